// Round 1
// baseline (1412.243 us; speedup 1.0000x reference)
//
#include <hip/hip_runtime.h>
#include <hip/hip_bf16.h>

#define BB 2
#define LL 4096
#define DD 1024
#define HH 4
#define DH 256
#define CH 32
#define NC (LL/CH)     // 128
#define BL (BB*LL)     // 8192
#define BLD ((size_t)BB*LL*DD) // 8388608

typedef __attribute__((ext_vector_type(8))) short short8;
typedef __attribute__((ext_vector_type(4))) float floatx4;

__device__ __forceinline__ float bf2f(unsigned short u) {
    union { float f; unsigned int i; } x; x.i = ((unsigned int)u) << 16; return x.f;
}
__device__ __forceinline__ float bflo(unsigned int u) {
    union { float f; unsigned int i; } x; x.i = u << 16; return x.f;
}
__device__ __forceinline__ float bfhi(unsigned int u) {
    union { float f; unsigned int i; } x; x.i = u & 0xFFFF0000u; return x.f;
}
__device__ __forceinline__ unsigned short f2bf(float f) {
    union { float f; unsigned int i; } x; x.f = f;
    unsigned int r = x.i + 0x7FFFu + ((x.i >> 16) & 1u);
    return (unsigned short)(r >> 16);
}
// pack two f32 -> (bf16(b)<<16)|bf16(a), round-half-up
__device__ __forceinline__ unsigned int pkbf(float a, float b) {
    unsigned int ua = __float_as_uint(a) + 0x8000u;
    unsigned int ub = __float_as_uint(b) + 0x8000u;
    return __builtin_amdgcn_perm(ub, ua, 0x07060302);
}

// ---------------------------------------------------------------- f32 -> bf16 bulk convert
__global__ __launch_bounds__(256) void cvt_bf_k(
    const float* __restrict__ x, unsigned short* __restrict__ y)
{
    size_t i = ((size_t)blockIdx.x * 256 + threadIdx.x) * 4;
    float4 v = *(const float4*)(x + i);
    ushort4 o;
    o.x = f2bf(v.x); o.y = f2bf(v.y); o.z = f2bf(v.z); o.w = f2bf(v.w);
    *(ushort4*)(y + i) = o;
}

// ---------------------------------------------------------------- pack w1[:,1024:1040] -> bf16 [1024][16]
__global__ __launch_bounds__(256) void w1s_prep_k(
    const float* __restrict__ w1, unsigned short* __restrict__ w1s)
{
    int idx = blockIdx.x * 256 + threadIdx.x;   // 16384
    int e = idx >> 4, s = idx & 15;
    w1s[idx] = f2bf(w1[(size_t)e * 1040 + 1024 + s]);
}

// ---------------------------------------------------------------- bf16 MFMA GEMM (NT), f32 A, f32 W
__global__ __launch_bounds__(256) void gemm_mfma(
    const float* __restrict__ A, int lda,
    const float* __restrict__ W, int ldw,
    const float* __restrict__ bias,
    float* __restrict__ C, int ldc, int K)
{
    __shared__ unsigned short Abuf[128][56];
    __shared__ unsigned short Bbuf[128][56];
    const int t = threadIdx.x;
    const int wave = t >> 6, lane = t & 63;
    const int wm = wave >> 1, wn = wave & 1;
    const int row0 = blockIdx.y * 128, col0 = blockIdx.x * 128;

    floatx4 acc[4][4];
#pragma unroll
    for (int i = 0; i < 4; ++i)
#pragma unroll
        for (int j = 0; j < 4; ++j) acc[i][j] = (floatx4){0.f, 0.f, 0.f, 0.f};

    const int fr = lane & 15, fk = (lane >> 4) * 8;

    for (int kt = 0; kt < K; kt += 32) {
        __syncthreads();
#pragma unroll
        for (int it = 0; it < 2; ++it) {
            int idx = t + it * 256;
            int r = idx >> 2, s = (idx & 3) * 8;
            const float* ap = A + (size_t)(row0 + r) * lda + kt + s;
            float4 a0 = *(const float4*)(ap);
            float4 a1 = *(const float4*)(ap + 4);
            ushort4 p0, p1;
            p0.x = f2bf(a0.x); p0.y = f2bf(a0.y); p0.z = f2bf(a0.z); p0.w = f2bf(a0.w);
            p1.x = f2bf(a1.x); p1.y = f2bf(a1.y); p1.z = f2bf(a1.z); p1.w = f2bf(a1.w);
            *(ushort4*)&Abuf[r][s]     = p0;
            *(ushort4*)&Abuf[r][s + 4] = p1;
            const float* wp = W + (size_t)(col0 + r) * ldw + kt + s;
            float4 b0 = *(const float4*)(wp);
            float4 b1 = *(const float4*)(wp + 4);
            ushort4 q0, q1;
            q0.x = f2bf(b0.x); q0.y = f2bf(b0.y); q0.z = f2bf(b0.z); q0.w = f2bf(b0.w);
            q1.x = f2bf(b1.x); q1.y = f2bf(b1.y); q1.z = f2bf(b1.z); q1.w = f2bf(b1.w);
            *(ushort4*)&Bbuf[r][s]     = q0;
            *(ushort4*)&Bbuf[r][s + 4] = q1;
        }
        __syncthreads();

        short8 afrag[4], bfrag[4];
#pragma unroll
        for (int i = 0; i < 4; ++i) {
            afrag[i] = *(const short8*)&Abuf[wm * 64 + i * 16 + fr][fk];
            bfrag[i] = *(const short8*)&Bbuf[wn * 64 + i * 16 + fr][fk];
        }
#pragma unroll
        for (int i = 0; i < 4; ++i)
#pragma unroll
            for (int j = 0; j < 4; ++j)
                acc[i][j] = __builtin_amdgcn_mfma_f32_16x16x32_bf16(
                    afrag[i], bfrag[j], acc[i][j], 0, 0, 0);
    }

    const int fc = lane & 15, frow = (lane >> 4) * 4;
#pragma unroll
    for (int j = 0; j < 4; ++j) {
        int col = col0 + wn * 64 + j * 16 + fc;
        float bv = bias ? bias[col] : 0.0f;
#pragma unroll
        for (int i = 0; i < 4; ++i) {
#pragma unroll
            for (int r = 0; r < 4; ++r) {
                int row = row0 + wm * 64 + i * 16 + frow + r;
                C[(size_t)row * ldc + col] = acc[i][j][r] + bv;
            }
        }
    }
}

// ---------------------------------------------------------------- bf16 MFMA GEMM (NT), bf16 A, bf16 B
__global__ __launch_bounds__(256) void gemm_bb(
    const unsigned short* __restrict__ A, int lda,
    const unsigned short* __restrict__ B, int ldb,
    float* __restrict__ C, int ldc, int K)
{
    __shared__ unsigned short Abuf[128][56];
    __shared__ unsigned short Bbuf[128][56];
    const int t = threadIdx.x;
    const int wave = t >> 6, lane = t & 63;
    const int wm = wave >> 1, wn = wave & 1;
    const int row0 = blockIdx.y * 128, col0 = blockIdx.x * 128;

    floatx4 acc[4][4];
#pragma unroll
    for (int i = 0; i < 4; ++i)
#pragma unroll
        for (int j = 0; j < 4; ++j) acc[i][j] = (floatx4){0.f, 0.f, 0.f, 0.f};

    const int fr = lane & 15, fk = (lane >> 4) * 8;

    for (int kt = 0; kt < K; kt += 32) {
        __syncthreads();
#pragma unroll
        for (int it = 0; it < 2; ++it) {
            int idx = t + it * 256;
            int r = idx >> 2, s = (idx & 3) * 8;
            uint4 av = *(const uint4*)(A + (size_t)(row0 + r) * lda + kt + s);
            *(uint4*)&Abuf[r][s] = av;
            uint4 bv = *(const uint4*)(B + (size_t)(col0 + r) * ldb + kt + s);
            *(uint4*)&Bbuf[r][s] = bv;
        }
        __syncthreads();

        short8 afrag[4], bfrag[4];
#pragma unroll
        for (int i = 0; i < 4; ++i) {
            afrag[i] = *(const short8*)&Abuf[wm * 64 + i * 16 + fr][fk];
            bfrag[i] = *(const short8*)&Bbuf[wn * 64 + i * 16 + fr][fk];
        }
#pragma unroll
        for (int i = 0; i < 4; ++i)
#pragma unroll
            for (int j = 0; j < 4; ++j)
                acc[i][j] = __builtin_amdgcn_mfma_f32_16x16x32_bf16(
                    afrag[i], bfrag[j], acc[i][j], 0, 0, 0);
    }

    const int fc = lane & 15, frow = (lane >> 4) * 4;
#pragma unroll
    for (int j = 0; j < 4; ++j) {
        int col = col0 + wn * 64 + j * 16 + fc;
#pragma unroll
        for (int i = 0; i < 4; ++i) {
#pragma unroll
            for (int r = 0; r < 4; ++r) {
                int row = row0 + wm * 64 + i * 16 + frow + r;
                C[(size_t)row * ldc + col] = acc[i][j][r];
            }
        }
    }
}

// --------------------------------------- causal dwconv K=4 + silu + head-l2norm -> bf16
__global__ __launch_bounds__(256) void convnorm_qk_k(
    const float* __restrict__ x, const float* __restrict__ w,
    unsigned short* __restrict__ y)
{
    int bl = blockIdx.x >> 2;
    int h  = blockIdx.x & 3;
    int l  = bl & (LL - 1);
    int d  = threadIdx.x;
    int c  = h * DH + d;
    const float* wp = w + (size_t)c * 4;
    const float* xp = x + (size_t)bl * DD + c;
    float acc = wp[3] * xp[0];
    if (l >= 1) acc += wp[2] * xp[-(int)DD];
    if (l >= 2) acc += wp[1] * xp[-2*(int)DD];
    if (l >= 3) acc += wp[0] * xp[-3*(int)DD];
    acc = acc / (1.0f + expf(-acc));
    float s = acc * acc;
#pragma unroll
    for (int off = 32; off > 0; off >>= 1) s += __shfl_down(s, off);
    __shared__ float red[4];
    int wv = threadIdx.x >> 6, ln = threadIdx.x & 63;
    if (ln == 0) red[wv] = s;
    __syncthreads();
    float tot = red[0] + red[1] + red[2] + red[3];
    y[(size_t)bl * DD + c] = f2bf(acc * rsqrtf(tot));
}

// ------------------------------------------------- causal depthwise conv K=4 + silu (f32)
__global__ __launch_bounds__(256) void conv_silu_k(
    const float* __restrict__ x, const float* __restrict__ w, float* __restrict__ y)
{
    size_t idx = (size_t)blockIdx.x * 256 + threadIdx.x;
    int c = (int)(idx & (DD - 1));
    int bl = (int)(idx >> 10);
    int l = bl & (LL - 1);
    const float* wp = w + (size_t)c * 4;
    const float* xp = x + (size_t)bl * DD + c;
    float acc = wp[3] * xp[0];
    if (l >= 1) acc += wp[2] * xp[-(int)DD];
    if (l >= 2) acc += wp[1] * xp[-2*(int)DD];
    if (l >= 3) acc += wp[0] * xp[-3*(int)DD];
    y[idx] = acc / (1.0f + expf(-acc));
}

// ------------------------------------------------- FIR causal depthwise conv, LDS-tiled
template<int K>
__global__ __launch_bounds__(256) void fir2_k(
    const float* __restrict__ x, const float* __restrict__ filt, float* __restrict__ y)
{
    const int ctile = blockIdx.x & 15;
    const int ltile = (blockIdx.x >> 4) & 63;
    const int b = blockIdx.x >> 10;
    const int RT = 64 + K - 1;
    __shared__ float xs[RT][64];
    __shared__ float fs[64][K + 1];
    const int t = threadIdx.x;
    const int l0 = ltile * 64;

    for (int i = t; i < RT * 16; i += 256) {
        int li = i >> 4, c4 = (i & 15) * 4;
        int l = l0 - (K - 1) + li;
        float4 v = make_float4(0.f, 0.f, 0.f, 0.f);
        if (l >= 0)
            v = *(const float4*)(x + ((size_t)b * LL + l) * DD + ctile * 64 + c4);
        *(float4*)&xs[li][c4] = v;
    }
    for (int i = t; i < 64 * K; i += 256) {
        fs[i / K][i % K] = filt[(size_t)ctile * 64 * K + i];
    }
    __syncthreads();

    const int c = t & 63, lg = t >> 6;
    float acc[16];
#pragma unroll
    for (int o = 0; o < 16; ++o) acc[o] = 0.f;
#pragma unroll
    for (int j = 0; j < 16 + K - 1; ++j) {
        float xv = xs[lg * 16 + j][c];
#pragma unroll
        for (int o = 0; o < 16; ++o) {
            int tap = j - o;
            if (tap >= 0 && tap < K) acc[o] += fs[c][tap] * xv;
        }
    }
    size_t base = ((size_t)b * LL + l0 + lg * 16) * DD + ctile * 64 + c;
#pragma unroll
    for (int o = 0; o < 16; ++o)
        y[base + (size_t)o * DD] = acc[o];
}

// ------------------------------------------------- beta = sigmoid(hs @ b_proj^T)
__global__ __launch_bounds__(256) void beta_k(
    const float* __restrict__ hs, const float* __restrict__ bw, float* __restrict__ beta)
{
    int bl = blockIdx.x;
    const float* xr = hs + (size_t)bl * DD;
    float a0=0.f,a1=0.f,a2=0.f,a3=0.f;
    for (int k = threadIdx.x; k < DD; k += 256) {
        float xv = xr[k];
        a0 += xv * bw[k];
        a1 += xv * bw[DD + k];
        a2 += xv * bw[2*DD + k];
        a3 += xv * bw[3*DD + k];
    }
#pragma unroll
    for (int off = 32; off > 0; off >>= 1) {
        a0 += __shfl_down(a0, off); a1 += __shfl_down(a1, off);
        a2 += __shfl_down(a2, off); a3 += __shfl_down(a3, off);
    }
    __shared__ float red[4][4];
    int wv = threadIdx.x >> 6, ln = threadIdx.x & 63;
    if (ln == 0) { red[wv][0]=a0; red[wv][1]=a1; red[wv][2]=a2; red[wv][3]=a3; }
    __syncthreads();
    if (threadIdx.x < 4) {
        int h = threadIdx.x;
        float s = red[0][h] + red[1][h] + red[2][h] + red[3][h];
        beta[(size_t)bl * HH + h] = 1.0f / (1.0f + expf(-s));
    }
}

// ------------------------------------------------- k transpose: k[b,l,h*DH+e] -> kT[bh,e,l]
__global__ __launch_bounds__(256) void tr_k(
    const unsigned short* __restrict__ k, unsigned short* __restrict__ kT)
{
    int et = blockIdx.x & 3;
    int lt = (blockIdx.x >> 2) & 63;
    int bh = blockIdx.x >> 8;
    int h = bh & 3, b = bh >> 2;
    __shared__ unsigned short tile[64][72];
    int t = threadIdx.x;
    int tr = t >> 4;
    int tc = (t & 15) * 4;
#pragma unroll
    for (int i = 0; i < 4; ++i) {
        int l = tr + i * 16;
        ushort4 v = *(const ushort4*)(k + ((size_t)b * LL + lt*64 + l) * DD + h * DH + et*64 + tc);
        *(ushort4*)&tile[l][tc] = v;
    }
    __syncthreads();
#pragma unroll
    for (int i = 0; i < 4; ++i) {
        int e = tr + i * 16;
        ushort4 v;
        v.x = tile[tc+0][e]; v.y = tile[tc+1][e];
        v.z = tile[tc+2][e]; v.w = tile[tc+3][e];
        *(ushort4*)(kT + ((size_t)bh * DH + et*64 + e) * LL + (size_t)lt*64 + tc) = v;
    }
}

// ------------------------------------------------- u transpose: u[bh,l,d] -> uT[bh,d,l]
__global__ __launch_bounds__(256) void tru_k(
    const unsigned short* __restrict__ u, unsigned short* __restrict__ uT)
{
    int et = blockIdx.x & 3;
    int lt = (blockIdx.x >> 2) & 63;
    int bh = blockIdx.x >> 8;
    __shared__ unsigned short tile[64][72];
    int t = threadIdx.x;
    int tr = t >> 4;
    int tc = (t & 15) * 4;
#pragma unroll
    for (int i = 0; i < 4; ++i) {
        int l = tr + i * 16;
        ushort4 v = *(const ushort4*)(u + ((size_t)bh * LL + lt*64 + l) * DH + et*64 + tc);
        *(ushort4*)&tile[l][tc] = v;
    }
    __syncthreads();
#pragma unroll
    for (int i = 0; i < 4; ++i) {
        int e = tr + i * 16;
        ushort4 v;
        v.x = tile[tc+0][e]; v.y = tile[tc+1][e];
        v.z = tile[tc+2][e]; v.w = tile[tc+3][e];
        *(ushort4*)(uT + ((size_t)bh * DH + et*64 + e) * LL + (size_t)lt*64 + tc) = v;
    }
}

// ------------------------------------------------- per-chunk prep (attn out bf16)
__global__ __launch_bounds__(256) void chunk_prep_k(
    const unsigned short* __restrict__ q, const unsigned short* __restrict__ k,
    const float* __restrict__ v, const float* __restrict__ beta,
    unsigned short* __restrict__ u_out, unsigned short* __restrict__ w_out,
    unsigned short* __restrict__ attn_out)
{
    int ci = blockIdx.x & (NC - 1);
    int bh = blockIdx.x >> 7;
    int h = bh & (HH - 1), b = bh >> 2;
    __shared__ float kt[CH][DH + 4];
    __shared__ float Am[CH][CH + 1];
    __shared__ float Ab[CH][CH + 1];
    __shared__ float bet[CH];
    int t = threadIdx.x;
    size_t qgbase = (size_t)b * LL + (size_t)ci * CH;

    for (int i = t; i < CH * (DH / 4); i += 256) {
        int r = i >> 6;
        int c4 = (i & 63) * 4;
        ushort4 kv = *(const ushort4*)(k + (qgbase + r) * DD + h * DH + c4);
        kt[r][c4+0] = bf2f(kv.x); kt[r][c4+1] = bf2f(kv.y);
        kt[r][c4+2] = bf2f(kv.z); kt[r][c4+3] = bf2f(kv.w);
    }
    if (t < CH) bet[t] = beta[(qgbase + t) * HH + h];
    __syncthreads();

    int c = t >> 3, e0 = (t & 7) * 4;
    {
        float accA[4] = {0,0,0,0}, accT[4] = {0,0,0,0};
        const unsigned short* qrow = q + (qgbase + c) * DD + h * DH;
        for (int d0 = 0; d0 < DH; d0 += 4) {
            float4 kc = *(const float4*)&kt[c][d0];
            ushort4 qv = *(const ushort4*)(qrow + d0);
            float qx = bf2f(qv.x), qy = bf2f(qv.y), qz = bf2f(qv.z), qw = bf2f(qv.w);
#pragma unroll
            for (int e = 0; e < 4; ++e) {
                float4 ke = *(const float4*)&kt[e0 + e][d0];
                accA[e] += kc.x*ke.x + kc.y*ke.y + kc.z*ke.z + kc.w*ke.w;
                accT[e] += qx*ke.x + qy*ke.y + qz*ke.z + qw*ke.w;
            }
        }
        float bc = bet[c];
        size_t abase = (size_t)blockIdx.x * (CH * CH) + (size_t)c * CH;
#pragma unroll
        for (int e = 0; e < 4; ++e) {
            int ee = e0 + e;
            Am[c][ee] = (ee < c) ? (-bc * accA[e]) : 0.0f;
            attn_out[abase + ee] = (ee <= c) ? f2bf(accT[e]) : (unsigned short)0;
        }
    }
    __syncthreads();

    for (int i = 1; i < CH; ++i) {
        float upd = 0.0f;
        if (t < i) {
#pragma unroll
            for (int kk = 0; kk < CH; ++kk) upd += Am[i][kk] * Am[kk][t];
        }
        __syncthreads();
        if (t < i) Am[i][t] += upd;
        __syncthreads();
    }

    for (int i = t; i < CH * CH; i += 256) {
        int cc = i >> 5, ee = i & 31;
        float val = Am[cc][ee] + (cc == ee ? 1.0f : 0.0f);
        Ab[cc][ee] = val * bet[ee];
    }
    __syncthreads();

    int c2 = t >> 3, dd0 = (t & 7) * 32;
    float accu[32];
#pragma unroll
    for (int j = 0; j < 32; ++j) accu[j] = 0.0f;
    for (int e = 0; e < CH; ++e) {
        float ab = Ab[c2][e];
        const float* vrow = v + (qgbase + e) * DD + h * DH + dd0;
#pragma unroll
        for (int j4 = 0; j4 < 8; ++j4) {
            float4 v4 = *(const float4*)(vrow + j4 * 4);
            accu[j4*4+0] += ab * v4.x; accu[j4*4+1] += ab * v4.y;
            accu[j4*4+2] += ab * v4.z; accu[j4*4+3] += ab * v4.w;
        }
    }
    size_t obase = ((size_t)bh * LL + (size_t)ci * CH + c2) * DH + dd0;
#pragma unroll
    for (int j4 = 0; j4 < 8; ++j4) {
        ushort4 o;
        o.x = f2bf(accu[j4*4+0]); o.y = f2bf(accu[j4*4+1]);
        o.z = f2bf(accu[j4*4+2]); o.w = f2bf(accu[j4*4+3]);
        *(ushort4*)(u_out + obase + j4*4) = o;
    }

#pragma unroll
    for (int j = 0; j < 32; ++j) accu[j] = 0.0f;
    for (int e = 0; e < CH; ++e) {
        float ab = Ab[c2][e];
#pragma unroll
        for (int j4 = 0; j4 < 8; ++j4) {
            float4 v4 = *(const float4*)&kt[e][dd0 + j4*4];
            accu[j4*4+0] += ab * v4.x; accu[j4*4+1] += ab * v4.y;
            accu[j4*4+2] += ab * v4.z; accu[j4*4+3] += ab * v4.w;
        }
    }
#pragma unroll
    for (int j4 = 0; j4 < 8; ++j4) {
        ushort4 o;
        o.x = f2bf(accu[j4*4+0]); o.y = f2bf(accu[j4*4+1]);
        o.z = f2bf(accu[j4*4+2]); o.w = f2bf(accu[j4*4+3]);
        *(ushort4*)(w_out + obase + j4*4) = o;
    }
}

// ------------------------------------------------- chunk scan v7: ONE WAVE per (bh,jb),
// full 256x16 S state in VGPRs (64 regs), ZERO barriers. The two data-layout changes
// (S C-layout -> B-frag, uadj C-layout -> B-frag) are intra-wave LDS round-trips with
// 16B-granule XOR swizzle (conflict-minimal b128 reads). 50 MFMA/chunk on one SIMD.
// Global frag loads issued at chunk top (~300cy before first use) hide XCD-L2 latency;
// bh in low 3 bits of blockIdx keeps same-bh blocks on one XCD L2.
__global__ __launch_bounds__(64, 1) void scan7_k(
    const unsigned short* __restrict__ q, const unsigned short* __restrict__ kT,
    const unsigned short* __restrict__ uT, const unsigned short* __restrict__ w,
    const unsigned short* __restrict__ attn, float* __restrict__ dout)
{
    const int bh = blockIdx.x & 7;     // low bits -> 16 same-bh blocks share one XCD
    const int jb = blockIdx.x >> 3;
    const int h = bh & (HH - 1), b = bh >> 2;
    const int jcol = jb * 16;
    const int lane = threadIdx.x & 63;
    const int c = lane & 15, g = lane >> 4;

    __shared__ unsigned char Sl[16 * 512];   // [col c][e] bf16, 16B-granule swizzle ^(c&7)
    __shared__ unsigned char Ul[16 * 64];    // [col c][k] bf16, 16B-granule swizzle ^(c&3)

    floatx4 Sacc[16];   // tile m: S[e=16m+4g+r][jcol+c]
#pragma unroll
    for (int m = 0; m < 16; ++m) Sacc[m] = (floatx4){0.f, 0.f, 0.f, 0.f};

    const unsigned short* qb  = q  + (size_t)b * LL * DD + h * DH;
    const unsigned short* wb  = w  + (size_t)bh * LL * DH;
    const unsigned short* kTb = kT + (size_t)bh * DH * LL;
    const unsigned short* uTb = uT + ((size_t)bh * DH + jcol + c) * LL;
    const unsigned short* atb = attn + (size_t)bh * NC * (CH * CH);
    float* db = dout + (size_t)bh * LL * DH;

    // precomputed LDS byte offsets
    int sw[16], sr[8], uw[2];
#pragma unroll
    for (int m = 0; m < 16; ++m)
        sw[m] = c * 512 + ((((2*m + (g >> 1)) ^ (c & 7)) << 4) | ((g & 1) << 3));
#pragma unroll
    for (int kt = 0; kt < 8; ++kt)
        sr[kt] = c * 512 + (((4*kt + g) ^ (c & 7)) << 4);
#pragma unroll
    for (int t = 0; t < 2; ++t)
        uw[t] = c * 64 + ((((2*t + (g >> 1)) ^ (c & 3)) << 4) | ((g & 1) << 3));
    const int ur = c * 64 + ((g ^ (c & 3)) << 4);

    for (int ci = 0; ci < NC; ++ci) {
        const int l0 = ci * CH;

        // ---- issue this chunk's global loads up front (flight hidden under S-pack/LDS)
        short8 wf[2][8], qf[2][8], kf[16], af[2];
        ushort4 uv[2];
#pragma unroll
        for (int t = 0; t < 2; ++t) {
            const unsigned short* wr = wb + (size_t)(l0 + 16*t + c) * DH + 8*g;
            const unsigned short* qr = qb + (size_t)(l0 + 16*t + c) * DD + 8*g;
#pragma unroll
            for (int kt = 0; kt < 8; ++kt) {
                wf[t][kt] = *(const short8*)(wr + 32*kt);
                qf[t][kt] = *(const short8*)(qr + 32*kt);
            }
            uv[t] = *(const ushort4*)(uTb + l0 + 16*t + 4*g);
            af[t] = *(const short8*)(atb + (size_t)ci * (CH*CH) + (16*t + c) * CH + 8*g);
        }
#pragma unroll
        for (int m = 0; m < 16; ++m)
            kf[m] = *(const short8*)(kTb + (size_t)(16*m + c) * LL + l0 + 8*g);

        // ---- pack S (f32 acc) -> Sl (bf16 B-frag layout)
#pragma unroll
        for (int m = 0; m < 16; ++m) {
            *(uint2*)&Sl[sw[m]] = make_uint2(pkbf(Sacc[m][0], Sacc[m][1]),
                                             pkbf(Sacc[m][2], Sacc[m][3]));
        }

        // ---- read S B-frags (compiler inserts lgkmcnt; same-wave, no barrier)
        short8 sf[8];
#pragma unroll
        for (int kt = 0; kt < 8; ++kt) sf[kt] = *(const short8*)&Sl[sr[kt]];

        // ---- Pw = w@S, Oq = q@S over K=256 (2 partial chains each for latency)
        floatx4 Pw[2], Oq[2];
#pragma unroll
        for (int t = 0; t < 2; ++t) {
            floatx4 pa = (floatx4){0.f,0.f,0.f,0.f}, pb = pa, oa = pa, oc = pa;
#pragma unroll
            for (int kt = 0; kt < 4; ++kt) {
                pa = __builtin_amdgcn_mfma_f32_16x16x32_bf16(wf[t][2*kt],   sf[2*kt],   pa, 0,0,0);
                pb = __builtin_amdgcn_mfma_f32_16x16x32_bf16(wf[t][2*kt+1], sf[2*kt+1], pb, 0,0,0);
                oa = __builtin_amdgcn_mfma_f32_16x16x32_bf16(qf[t][2*kt],   sf[2*kt],   oa, 0,0,0);
                oc = __builtin_amdgcn_mfma_f32_16x16x32_bf16(qf[t][2*kt+1], sf[2*kt+1], oc, 0,0,0);
            }
            Pw[t] = pa + pb;
            Oq[t] = oa + oc;
        }

        // ---- uadj = u - w@S -> Ul (bf16)
#pragma unroll
        for (int t = 0; t < 2; ++t) {
            float a0 = bf2f(uv[t].x) - Pw[t][0];
            float a1 = bf2f(uv[t].y) - Pw[t][1];
            float a2 = bf2f(uv[t].z) - Pw[t][2];
            float a3 = bf2f(uv[t].w) - Pw[t][3];
            *(uint2*)&Ul[uw[t]] = make_uint2(pkbf(a0, a1), pkbf(a2, a3));
        }
        short8 ub = *(const short8*)&Ul[ur];

        // ---- O = q@S + attn@uadj -> dout
#pragma unroll
        for (int t = 0; t < 2; ++t) {
            floatx4 Ot = __builtin_amdgcn_mfma_f32_16x16x32_bf16(af[t], ub, Oq[t], 0,0,0);
#pragma unroll
            for (int r = 0; r < 4; ++r)
                db[(size_t)(l0 + 16*t + 4*g + r) * DH + jcol + c] = Ot[r];
        }

        // ---- S += kT @ uadj (16 independent MFMAs)
#pragma unroll
        for (int m = 0; m < 16; ++m)
            Sacc[m] = __builtin_amdgcn_mfma_f32_16x16x32_bf16(kf[m], ub, Sacc[m], 0,0,0);
    }
}

// ------------------------------------------------- per-head stats
__global__ __launch_bounds__(256) void stats_k(
    const float* __restrict__ ls, const float* __restrict__ llb,
    const float* __restrict__ dox, const float* __restrict__ v,
    float* __restrict__ stats)
{
    int bl = blockIdx.x;
    int b = bl >> 12, l = bl & (LL - 1);
    int wv = threadIdx.x >> 6, ln = threadIdx.x & 63;
    size_t ibase = (size_t)bl * DD + wv * DH;
    size_t dbase = (((size_t)(b * HH + wv)) * LL + l) * DH;
#pragma unroll
    for (int tn = 0; tn < 4; ++tn) {
        const float* p; size_t base;
        if (tn == 0)      { p = ls;  base = ibase; }
        else if (tn == 1) { p = llb; base = ibase; }
        else if (tn == 2) { p = dox; base = dbase; }
        else              { p = v;   base = ibase; }
        float4 x = *(const float4*)(p + base + ln * 4);
        float sm = x.x + x.y + x.z + x.w;
        float sq = x.x*x.x + x.y*x.y + x.z*x.z + x.w*x.w;
        float sa = fabsf(x.x) + fabsf(x.y) + fabsf(x.z) + fabsf(x.w);
#pragma unroll
        for (int off = 32; off > 0; off >>= 1) {
            sm += __shfl_down(sm, off);
            sq += __shfl_down(sq, off);
            sa += __shfl_down(sa, off);
        }
        if (ln == 0) {
            float mean = sm * (1.0f / DH);
            float var = sq * (1.0f / DH) - mean * mean;
            float am = sa * (1.0f / DH);
            float l2 = sqrtf(sq);
            *(float4*)(stats + (size_t)bl * 64 + wv * 16 + tn * 4) =
                make_float4(mean, var, am, l2);
        }
    }
}

// ------------------------------------------------- gate finish v2
__global__ __launch_bounds__(256) void gate_fin2_k(
    const float* __restrict__ hpart, const float* __restrict__ stats,
    const unsigned short* __restrict__ w1s,
    const float* __restrict__ w2, const float* __restrict__ b2,
    const float* __restrict__ ltemp, float* __restrict__ fw)
{
    const int bl = blockIdx.x;
    const int t = threadIdx.x;
    const float temp = log1pf(expf(ltemp[0])) + 1e-4f;
    __shared__ float st[HH][16];
    __shared__ float red[4][16];
    __shared__ float fin[16];
    if (t < 64) st[t >> 4][t & 15] = stats[(size_t)bl * 64 + t];

    const int e0 = t * 4;
    float4 hp4 = *(const float4*)(hpart + (size_t)bl * DD + e0);
    float hp[4] = {hp4.x, hp4.y, hp4.z, hp4.w};
    float w2a[4][4];
#pragma unroll
    for (int j = 0; j < 4; ++j) {
        float4 wv = *(const float4*)(w2 + (size_t)j * 1024 + e0);
        w2a[j][0] = wv.x; w2a[j][1] = wv.y; w2a[j][2] = wv.z; w2a[j][3] = wv.w;
    }
    uint4 wpk[8];
    const uint4* wp = (const uint4*)(w1s + (size_t)e0 * 16);
#pragma unroll
    for (int i = 0; i < 8; ++i) wpk[i] = wp[i];
    __syncthreads();

    float lg[4][4];
#pragma unroll
    for (int h = 0; h < 4; ++h)
#pragma unroll
        for (int j = 0; j < 4; ++j) lg[h][j] = 0.0f;

#pragma unroll
    for (int ii = 0; ii < 4; ++ii) {
        float xh[4] = {hp[ii], hp[ii], hp[ii], hp[ii]};
        unsigned arr[8] = {wpk[ii*2].x, wpk[ii*2].y, wpk[ii*2].z, wpk[ii*2].w,
                           wpk[ii*2+1].x, wpk[ii*2+1].y, wpk[ii*2+1].z, wpk[ii*2+1].w};
#pragma unroll
        for (int p = 0; p < 8; ++p) {
            float wlo = bflo(arr[p]), whi = bfhi(arr[p]);
            int s = p * 2;
#pragma unroll
            for (int h = 0; h < 4; ++h)
                xh[h] += st[h][s] * wlo + st[h][s + 1] * whi;
        }
#pragma unroll
        for (int h = 0; h < 4; ++h) {
            float x = xh[h];
            float gct = 0.5f * x * (1.0f + erff(x * 0.70710678118654752f));
            lg[h][0] += gct * w2a[0][ii];
            lg[h][1] += gct * w2a[1][ii];
            lg[h][2] += gct * w2a[2][ii];
            lg[h][3] += gct * w2a[3][ii];
        }
    }

#pragma unroll
    for (int h = 0; h < 4; ++h)
#pragma unroll
        for (int j = 0; j < 4; ++j)
#pragma unroll
            for (int off = 32; off > 0; off >>= 1)
                lg[h][j] += __shfl_down(lg[h][j], off);

    const int wv = t >> 6, ln = t & 63;
    if (ln == 0) {
#pragma unroll
        for (int h = 0; h < 4; ++h)
#pragma unroll
            for (int j = 0; j < 4; ++j) red[wv][h * 4 + j] = lg[h][j];
    }
    __syncthreads();
    if (t < 16) {
        float s = red[0][t] + red[1][t] + red[2][t] + red[3][t] + b2[t & 3];
        fin[t] = s / temp;
    }
    __syncthreads();
    if (t < 4) {
        float l0 = fin[t*4], l1 = fin[t*4+1], l2 = fin[t*4+2], l3 = fin[t*4+3];
        float m = fmaxf(fmaxf(l0, l1), fmaxf(l2, l3));
        float e0x = expf(l0-m), e1 = expf(l1-m), e2 = expf(l2-m), e3 = expf(l3-m);
        float inv = 1.0f / (e0x + e1 + e2 + e3);
        *(float4*)(fw + (size_t)bl * 16 + t * 4) = make_float4(e0x*inv, e1*inv, e2*inv, e3*inv);
    }
}

// ------------------------------------------------- combine + rms norm
__global__ __launch_bounds__(256) void combine_k(
    const float* __restrict__ ls, const float* __restrict__ llb,
    const float* __restrict__ dox, const float* __restrict__ v,
    const float* __restrict__ fw, const float* __restrict__ rss,
    const float* __restrict__ rsl, const float* __restrict__ onw,
    float* __restrict__ opre)
{
    int h = blockIdx.x & (HH - 1);
    int bl = blockIdx.x >> 2;
    int b = bl >> 12, l = bl & (LL - 1);
    int d = threadIdx.x;
    size_t i1 = (size_t)blockIdx.x * DH + d;
    size_t i2 = (((size_t)(b * HH + h)) * LL + l) * DH + d;
    const float* fwp = fw + (size_t)blockIdx.x * 4;
    float f0 = fwp[0], f1 = fwp[1], f2 = fwp[2], f3 = fwp[3];
    float aS = rss[0], aL = rsl[0];
    float vls = ls[i1], vll = llb[i1], vd = dox[i2], vv = v[i1];
    float o = f0*vls + f1*vll + f2*vd + f3*vv + aS*vls + aL*vll;
    float s = o * o;
#pragma unroll
    for (int off = 32; off > 0; off >>= 1) s += __shfl_down(s, off);
    __shared__ float red[4];
    int wv = threadIdx.x >> 6, ln = threadIdx.x & 63;
    if (ln == 0) red[wv] = s;
    __syncthreads();
    float ms = (red[0] + red[1] + red[2] + red[3]) * (1.0f / DH);
    opre[(size_t)bl * DD + h * DH + d] = o * rsqrtf(ms + 1e-5f) * onw[d];
}

// ================================================================ launch
extern "C" void kernel_launch(void* const* d_in, const int* in_sizes, int n_in,
                              void* d_out, int out_size, void* d_ws, size_t ws_size,
                              hipStream_t stream)
{
    const float* hs  = (const float*)d_in[0];
    const float* qw  = (const float*)d_in[1];
    const float* kw  = (const float*)d_in[2];
    const float* vw  = (const float*)d_in[3];
    const float* bw  = (const float*)d_in[4];
    const float* qcw = (const float*)d_in[5];
    const float* kcw = (const float*)d_in[6];
    const float* vcw = (const float*)d_in[7];
    const float* fsw = (const float*)d_in[8];
    const float* flw = (const float*)d_in[9];
    const float* w1  = (const float*)d_in[10];
    const float* b1  = (const float*)d_in[11];
    const float* w2  = (const float*)d_in[12];
    const float* b2  = (const float*)d_in[13];
    const float* lt  = (const float*)d_in[14];
    const float* rss = (const float*)d_in[15];
    const float* rsl = (const float*)d_in[16];
    const float* onw = (const float*)d_in[17];
    const float* opw = (const float*)d_in[18];
    float* out = (float*)d_out;

    float* wsf = (float*)d_ws;
    float* tmp   = wsf;
    unsigned short* ktbuf = (unsigned short*)tmp;
    unsigned short* uTbuf = (unsigned short*)(wsf + BLD/2);
    float* vbuf  = wsf + BLD;
    float* dbuf  = wsf + 2*BLD;
    // hsb shares the dbuf region -> DEAD once scan7 writes dbuf. Only used in phase 1.
    unsigned short* hsb = (unsigned short*)(wsf + 2*BLD);
    // bf16 QKV weights live in the dead second half of the dbuf region during phase 1
    unsigned short* qwb = (unsigned short*)(wsf + 2*BLD + BLD/2);
    unsigned short* kwb = qwb + (size_t)DD*DD;
    unsigned short* vwb = kwb + (size_t)DD*DD;
    unsigned short* qbuf = (unsigned short*)(wsf + 3*BLD);
    unsigned short* kbuf = qbuf + BLD;
    float* hpart = wsf + 3*BLD;
    float* opre  = wsf + 3*BLD;
    unsigned short* ubuf = (unsigned short*)(wsf + 4*BLD);
    unsigned short* wbuf = ubuf + BLD;
    float* llbuf = wsf + 4*BLD;
    float* lsbuf = tmp;
    unsigned short* attnb = (unsigned short*)(wsf + 5*BLD);
    float* statsb = wsf + 5*BLD + 524288;
    float* fwbuf  = statsb + (size_t)BL*HH*16;
    float* betab  = fwbuf + (size_t)BL*HH*4;
    unsigned short* w1sp = (unsigned short*)(betab + (size_t)BL*HH);

    dim3 gg(8, 64);   // N/128, M/128

    cvt_bf_k<<<(int)(BLD/1024), 256, 0, stream>>>(hs, hsb);
    cvt_bf_k<<<1024, 256, 0, stream>>>(qw, qwb);
    cvt_bf_k<<<1024, 256, 0, stream>>>(kw, kwb);
    cvt_bf_k<<<1024, 256, 0, stream>>>(vw, vwb);
    w1s_prep_k<<<64, 256, 0, stream>>>(w1, w1sp);

    gemm_bb<<<gg, 256, 0, stream>>>(hsb, DD, qwb, DD, tmp, DD, DD);
    convnorm_qk_k<<<BL*HH, 256, 0, stream>>>(tmp, qcw, qbuf);
    gemm_bb<<<gg, 256, 0, stream>>>(hsb, DD, kwb, DD, tmp, DD, DD);
    convnorm_qk_k<<<BL*HH, 256, 0, stream>>>(tmp, kcw, kbuf);
    gemm_bb<<<gg, 256, 0, stream>>>(hsb, DD, vwb, DD, tmp, DD, DD);
    conv_silu_k<<<(int)(BLD/256), 256, 0, stream>>>(tmp, vcw, vbuf);

    beta_k<<<BL, 256, 0, stream>>>(hs, bw, betab);

    tr_k<<<8*64*4, 256, 0, stream>>>(kbuf, ktbuf);
    chunk_prep_k<<<BB*HH*NC, 256, 0, stream>>>(qbuf, kbuf, vbuf, betab, ubuf, wbuf, attnb);
    tru_k<<<8*64*4, 256, 0, stream>>>(ubuf, uTbuf);

    scan7_k<<<BB*HH*16, 64, 0, stream>>>(qbuf, ktbuf, uTbuf, wbuf, attnb, dbuf);

    fir2_k<5><<<BB*64*16, 256, 0, stream>>>(vbuf, fsw, lsbuf);
    fir2_k<64><<<BB*64*16, 256, 0, stream>>>(vbuf, flw, llbuf);

    stats_k<<<BL, 256, 0, stream>>>(lsbuf, llbuf, dbuf, vbuf, statsb);

    // hpart GEMM reads the pristine f32 input hs (hsb is dead: overwritten by dbuf)
    gemm_mfma<<<gg, 256, 0, stream>>>(hs, DD, w1, 1040, b1, hpart, DD, DD);
    gate_fin2_k<<<BL, 256, 0, stream>>>(hpart, statsb, w1sp, w2, b2, lt, fwbuf);

    combine_k<<<BL*HH, 256, 0, stream>>>(lsbuf, llbuf, dbuf, vbuf, fwbuf, rss, rsl, onw, opre);

    gemm_mfma<<<gg, 256, 0, stream>>>(opre, DD, opw, DD, nullptr, out, DD, DD);
}

// Round 2
// 1181.502 us; speedup vs baseline: 1.1953x; 1.1953x over previous
//
#include <hip/hip_runtime.h>
#include <hip/hip_bf16.h>

#define BB 2
#define LL 4096
#define DD 1024
#define HH 4
#define DH 256
#define CH 32
#define NC (LL/CH)     // 128
#define BL (BB*LL)     // 8192
#define BLD ((size_t)BB*LL*DD) // 8388608

typedef __attribute__((ext_vector_type(8))) short short8;
typedef __attribute__((ext_vector_type(4))) float floatx4;

__device__ __forceinline__ float bf2f(unsigned short u) {
    union { float f; unsigned int i; } x; x.i = ((unsigned int)u) << 16; return x.f;
}
__device__ __forceinline__ float bflo(unsigned int u) {
    union { float f; unsigned int i; } x; x.i = u << 16; return x.f;
}
__device__ __forceinline__ float bfhi(unsigned int u) {
    union { float f; unsigned int i; } x; x.i = u & 0xFFFF0000u; return x.f;
}
__device__ __forceinline__ unsigned short f2bf(float f) {
    union { float f; unsigned int i; } x; x.f = f;
    unsigned int r = x.i + 0x7FFFu + ((x.i >> 16) & 1u);
    return (unsigned short)(r >> 16);
}
// pack two f32 -> (bf16(b)<<16)|bf16(a), round-half-up
__device__ __forceinline__ unsigned int pkbf(float a, float b) {
    unsigned int ua = __float_as_uint(a) + 0x8000u;
    unsigned int ub = __float_as_uint(b) + 0x8000u;
    return __builtin_amdgcn_perm(ub, ua, 0x07060302);
}
// barrier with LDS-only drain (no vmcnt drain -> prefetch loads stay in flight)
__device__ __forceinline__ void lds_barrier() {
    __builtin_amdgcn_s_waitcnt(0xC07F);
    __builtin_amdgcn_s_barrier();
}

// ---------------------------------------------------------------- f32 -> bf16 bulk convert
__global__ __launch_bounds__(256) void cvt_bf_k(
    const float* __restrict__ x, unsigned short* __restrict__ y)
{
    size_t i = ((size_t)blockIdx.x * 256 + threadIdx.x) * 4;
    float4 v = *(const float4*)(x + i);
    ushort4 o;
    o.x = f2bf(v.x); o.y = f2bf(v.y); o.z = f2bf(v.z); o.w = f2bf(v.w);
    *(ushort4*)(y + i) = o;
}

// ---------------------------------------------------------------- pack w1[:,1024:1040] -> bf16 [1024][16]
__global__ __launch_bounds__(256) void w1s_prep_k(
    const float* __restrict__ w1, unsigned short* __restrict__ w1s)
{
    int idx = blockIdx.x * 256 + threadIdx.x;   // 16384
    int e = idx >> 4, s = idx & 15;
    w1s[idx] = f2bf(w1[(size_t)e * 1040 + 1024 + s]);
}

// ---------------------------------------------------------------- bf16 MFMA GEMM (NT), f32 A, f32 W
__global__ __launch_bounds__(256) void gemm_mfma(
    const float* __restrict__ A, int lda,
    const float* __restrict__ W, int ldw,
    const float* __restrict__ bias,
    float* __restrict__ C, int ldc, int K)
{
    __shared__ unsigned short Abuf[128][56];
    __shared__ unsigned short Bbuf[128][56];
    const int t = threadIdx.x;
    const int wave = t >> 6, lane = t & 63;
    const int wm = wave >> 1, wn = wave & 1;
    const int row0 = blockIdx.y * 128, col0 = blockIdx.x * 128;

    floatx4 acc[4][4];
#pragma unroll
    for (int i = 0; i < 4; ++i)
#pragma unroll
        for (int j = 0; j < 4; ++j) acc[i][j] = (floatx4){0.f, 0.f, 0.f, 0.f};

    const int fr = lane & 15, fk = (lane >> 4) * 8;

    for (int kt = 0; kt < K; kt += 32) {
        __syncthreads();
#pragma unroll
        for (int it = 0; it < 2; ++it) {
            int idx = t + it * 256;
            int r = idx >> 2, s = (idx & 3) * 8;
            const float* ap = A + (size_t)(row0 + r) * lda + kt + s;
            float4 a0 = *(const float4*)(ap);
            float4 a1 = *(const float4*)(ap + 4);
            ushort4 p0, p1;
            p0.x = f2bf(a0.x); p0.y = f2bf(a0.y); p0.z = f2bf(a0.z); p0.w = f2bf(a0.w);
            p1.x = f2bf(a1.x); p1.y = f2bf(a1.y); p1.z = f2bf(a1.z); p1.w = f2bf(a1.w);
            *(ushort4*)&Abuf[r][s]     = p0;
            *(ushort4*)&Abuf[r][s + 4] = p1;
            const float* wp = W + (size_t)(col0 + r) * ldw + kt + s;
            float4 b0 = *(const float4*)(wp);
            float4 b1 = *(const float4*)(wp + 4);
            ushort4 q0, q1;
            q0.x = f2bf(b0.x); q0.y = f2bf(b0.y); q0.z = f2bf(b0.z); q0.w = f2bf(b0.w);
            q1.x = f2bf(b1.x); q1.y = f2bf(b1.y); q1.z = f2bf(b1.z); q1.w = f2bf(b1.w);
            *(ushort4*)&Bbuf[r][s]     = q0;
            *(ushort4*)&Bbuf[r][s + 4] = q1;
        }
        __syncthreads();

        short8 afrag[4], bfrag[4];
#pragma unroll
        for (int i = 0; i < 4; ++i) {
            afrag[i] = *(const short8*)&Abuf[wm * 64 + i * 16 + fr][fk];
            bfrag[i] = *(const short8*)&Bbuf[wn * 64 + i * 16 + fr][fk];
        }
#pragma unroll
        for (int i = 0; i < 4; ++i)
#pragma unroll
            for (int j = 0; j < 4; ++j)
                acc[i][j] = __builtin_amdgcn_mfma_f32_16x16x32_bf16(
                    afrag[i], bfrag[j], acc[i][j], 0, 0, 0);
    }

    const int fc = lane & 15, frow = (lane >> 4) * 4;
#pragma unroll
    for (int j = 0; j < 4; ++j) {
        int col = col0 + wn * 64 + j * 16 + fc;
        float bv = bias ? bias[col] : 0.0f;
#pragma unroll
        for (int i = 0; i < 4; ++i) {
#pragma unroll
            for (int r = 0; r < 4; ++r) {
                int row = row0 + wm * 64 + i * 16 + frow + r;
                C[(size_t)row * ldc + col] = acc[i][j][r] + bv;
            }
        }
    }
}

// ---------------------------------------------------------------- bf16 MFMA GEMM (NT), bf16 A, bf16 B
__global__ __launch_bounds__(256) void gemm_bb(
    const unsigned short* __restrict__ A, int lda,
    const unsigned short* __restrict__ B, int ldb,
    float* __restrict__ C, int ldc, int K)
{
    __shared__ unsigned short Abuf[128][56];
    __shared__ unsigned short Bbuf[128][56];
    const int t = threadIdx.x;
    const int wave = t >> 6, lane = t & 63;
    const int wm = wave >> 1, wn = wave & 1;
    const int row0 = blockIdx.y * 128, col0 = blockIdx.x * 128;

    floatx4 acc[4][4];
#pragma unroll
    for (int i = 0; i < 4; ++i)
#pragma unroll
        for (int j = 0; j < 4; ++j) acc[i][j] = (floatx4){0.f, 0.f, 0.f, 0.f};

    const int fr = lane & 15, fk = (lane >> 4) * 8;

    for (int kt = 0; kt < K; kt += 32) {
        __syncthreads();
#pragma unroll
        for (int it = 0; it < 2; ++it) {
            int idx = t + it * 256;
            int r = idx >> 2, s = (idx & 3) * 8;
            uint4 av = *(const uint4*)(A + (size_t)(row0 + r) * lda + kt + s);
            *(uint4*)&Abuf[r][s] = av;
            uint4 bv = *(const uint4*)(B + (size_t)(col0 + r) * ldb + kt + s);
            *(uint4*)&Bbuf[r][s] = bv;
        }
        __syncthreads();

        short8 afrag[4], bfrag[4];
#pragma unroll
        for (int i = 0; i < 4; ++i) {
            afrag[i] = *(const short8*)&Abuf[wm * 64 + i * 16 + fr][fk];
            bfrag[i] = *(const short8*)&Bbuf[wn * 64 + i * 16 + fr][fk];
        }
#pragma unroll
        for (int i = 0; i < 4; ++i)
#pragma unroll
            for (int j = 0; j < 4; ++j)
                acc[i][j] = __builtin_amdgcn_mfma_f32_16x16x32_bf16(
                    afrag[i], bfrag[j], acc[i][j], 0, 0, 0);
    }

    const int fc = lane & 15, frow = (lane >> 4) * 4;
#pragma unroll
    for (int j = 0; j < 4; ++j) {
        int col = col0 + wn * 64 + j * 16 + fc;
#pragma unroll
        for (int i = 0; i < 4; ++i) {
#pragma unroll
            for (int r = 0; r < 4; ++r) {
                int row = row0 + wm * 64 + i * 16 + frow + r;
                C[(size_t)row * ldc + col] = acc[i][j][r];
            }
        }
    }
}

// --------------------------------------- causal dwconv K=4 + silu + head-l2norm -> bf16
__global__ __launch_bounds__(256) void convnorm_qk_k(
    const float* __restrict__ x, const float* __restrict__ w,
    unsigned short* __restrict__ y)
{
    int bl = blockIdx.x >> 2;
    int h  = blockIdx.x & 3;
    int l  = bl & (LL - 1);
    int d  = threadIdx.x;
    int c  = h * DH + d;
    const float* wp = w + (size_t)c * 4;
    const float* xp = x + (size_t)bl * DD + c;
    float acc = wp[3] * xp[0];
    if (l >= 1) acc += wp[2] * xp[-(int)DD];
    if (l >= 2) acc += wp[1] * xp[-2*(int)DD];
    if (l >= 3) acc += wp[0] * xp[-3*(int)DD];
    acc = acc / (1.0f + expf(-acc));
    float s = acc * acc;
#pragma unroll
    for (int off = 32; off > 0; off >>= 1) s += __shfl_down(s, off);
    __shared__ float red[4];
    int wv = threadIdx.x >> 6, ln = threadIdx.x & 63;
    if (ln == 0) red[wv] = s;
    __syncthreads();
    float tot = red[0] + red[1] + red[2] + red[3];
    y[(size_t)bl * DD + c] = f2bf(acc * rsqrtf(tot));
}

// ------------------------------------------------- causal depthwise conv K=4 + silu (f32)
__global__ __launch_bounds__(256) void conv_silu_k(
    const float* __restrict__ x, const float* __restrict__ w, float* __restrict__ y)
{
    size_t idx = (size_t)blockIdx.x * 256 + threadIdx.x;
    int c = (int)(idx & (DD - 1));
    int bl = (int)(idx >> 10);
    int l = bl & (LL - 1);
    const float* wp = w + (size_t)c * 4;
    const float* xp = x + (size_t)bl * DD + c;
    float acc = wp[3] * xp[0];
    if (l >= 1) acc += wp[2] * xp[-(int)DD];
    if (l >= 2) acc += wp[1] * xp[-2*(int)DD];
    if (l >= 3) acc += wp[0] * xp[-3*(int)DD];
    y[idx] = acc / (1.0f + expf(-acc));
}

// ------------------------------------------------- FIR causal depthwise conv, LDS-tiled
template<int K>
__global__ __launch_bounds__(256) void fir2_k(
    const float* __restrict__ x, const float* __restrict__ filt, float* __restrict__ y)
{
    const int ctile = blockIdx.x & 15;
    const int ltile = (blockIdx.x >> 4) & 63;
    const int b = blockIdx.x >> 10;
    const int RT = 64 + K - 1;
    __shared__ float xs[RT][64];
    __shared__ float fs[64][K + 1];
    const int t = threadIdx.x;
    const int l0 = ltile * 64;

    for (int i = t; i < RT * 16; i += 256) {
        int li = i >> 4, c4 = (i & 15) * 4;
        int l = l0 - (K - 1) + li;
        float4 v = make_float4(0.f, 0.f, 0.f, 0.f);
        if (l >= 0)
            v = *(const float4*)(x + ((size_t)b * LL + l) * DD + ctile * 64 + c4);
        *(float4*)&xs[li][c4] = v;
    }
    for (int i = t; i < 64 * K; i += 256) {
        fs[i / K][i % K] = filt[(size_t)ctile * 64 * K + i];
    }
    __syncthreads();

    const int c = t & 63, lg = t >> 6;
    float acc[16];
#pragma unroll
    for (int o = 0; o < 16; ++o) acc[o] = 0.f;
#pragma unroll
    for (int j = 0; j < 16 + K - 1; ++j) {
        float xv = xs[lg * 16 + j][c];
#pragma unroll
        for (int o = 0; o < 16; ++o) {
            int tap = j - o;
            if (tap >= 0 && tap < K) acc[o] += fs[c][tap] * xv;
        }
    }
    size_t base = ((size_t)b * LL + l0 + lg * 16) * DD + ctile * 64 + c;
#pragma unroll
    for (int o = 0; o < 16; ++o)
        y[base + (size_t)o * DD] = acc[o];
}

// ------------------------------------------------- beta = sigmoid(hs @ b_proj^T)
__global__ __launch_bounds__(256) void beta_k(
    const float* __restrict__ hs, const float* __restrict__ bw, float* __restrict__ beta)
{
    int bl = blockIdx.x;
    const float* xr = hs + (size_t)bl * DD;
    float a0=0.f,a1=0.f,a2=0.f,a3=0.f;
    for (int k = threadIdx.x; k < DD; k += 256) {
        float xv = xr[k];
        a0 += xv * bw[k];
        a1 += xv * bw[DD + k];
        a2 += xv * bw[2*DD + k];
        a3 += xv * bw[3*DD + k];
    }
#pragma unroll
    for (int off = 32; off > 0; off >>= 1) {
        a0 += __shfl_down(a0, off); a1 += __shfl_down(a1, off);
        a2 += __shfl_down(a2, off); a3 += __shfl_down(a3, off);
    }
    __shared__ float red[4][4];
    int wv = threadIdx.x >> 6, ln = threadIdx.x & 63;
    if (ln == 0) { red[wv][0]=a0; red[wv][1]=a1; red[wv][2]=a2; red[wv][3]=a3; }
    __syncthreads();
    if (threadIdx.x < 4) {
        int h = threadIdx.x;
        float s = red[0][h] + red[1][h] + red[2][h] + red[3][h];
        beta[(size_t)bl * HH + h] = 1.0f / (1.0f + expf(-s));
    }
}

// ------------------------------------------------- k transpose: k[b,l,h*DH+e] -> kT[bh,e,l]
__global__ __launch_bounds__(256) void tr_k(
    const unsigned short* __restrict__ k, unsigned short* __restrict__ kT)
{
    int et = blockIdx.x & 3;
    int lt = (blockIdx.x >> 2) & 63;
    int bh = blockIdx.x >> 8;
    int h = bh & 3, b = bh >> 2;
    __shared__ unsigned short tile[64][72];
    int t = threadIdx.x;
    int tr = t >> 4;
    int tc = (t & 15) * 4;
#pragma unroll
    for (int i = 0; i < 4; ++i) {
        int l = tr + i * 16;
        ushort4 v = *(const ushort4*)(k + ((size_t)b * LL + lt*64 + l) * DD + h * DH + et*64 + tc);
        *(ushort4*)&tile[l][tc] = v;
    }
    __syncthreads();
#pragma unroll
    for (int i = 0; i < 4; ++i) {
        int e = tr + i * 16;
        ushort4 v;
        v.x = tile[tc+0][e]; v.y = tile[tc+1][e];
        v.z = tile[tc+2][e]; v.w = tile[tc+3][e];
        *(ushort4*)(kT + ((size_t)bh * DH + et*64 + e) * LL + (size_t)lt*64 + tc) = v;
    }
}

// ------------------------------------------------- u transpose: u[bh,l,d] -> uT[bh,d,l]
__global__ __launch_bounds__(256) void tru_k(
    const unsigned short* __restrict__ u, unsigned short* __restrict__ uT)
{
    int et = blockIdx.x & 3;
    int lt = (blockIdx.x >> 2) & 63;
    int bh = blockIdx.x >> 8;
    __shared__ unsigned short tile[64][72];
    int t = threadIdx.x;
    int tr = t >> 4;
    int tc = (t & 15) * 4;
#pragma unroll
    for (int i = 0; i < 4; ++i) {
        int l = tr + i * 16;
        ushort4 v = *(const ushort4*)(u + ((size_t)bh * LL + lt*64 + l) * DH + et*64 + tc);
        *(ushort4*)&tile[l][tc] = v;
    }
    __syncthreads();
#pragma unroll
    for (int i = 0; i < 4; ++i) {
        int e = tr + i * 16;
        ushort4 v;
        v.x = tile[tc+0][e]; v.y = tile[tc+1][e];
        v.z = tile[tc+2][e]; v.w = tile[tc+3][e];
        *(ushort4*)(uT + ((size_t)bh * DH + et*64 + e) * LL + (size_t)lt*64 + tc) = v;
    }
}

// ------------------------------------------------- per-chunk prep (attn out bf16)
__global__ __launch_bounds__(256) void chunk_prep_k(
    const unsigned short* __restrict__ q, const unsigned short* __restrict__ k,
    const float* __restrict__ v, const float* __restrict__ beta,
    unsigned short* __restrict__ u_out, unsigned short* __restrict__ w_out,
    unsigned short* __restrict__ attn_out)
{
    int ci = blockIdx.x & (NC - 1);
    int bh = blockIdx.x >> 7;
    int h = bh & (HH - 1), b = bh >> 2;
    __shared__ float kt[CH][DH + 4];
    __shared__ float Am[CH][CH + 1];
    __shared__ float Ab[CH][CH + 1];
    __shared__ float bet[CH];
    int t = threadIdx.x;
    size_t qgbase = (size_t)b * LL + (size_t)ci * CH;

    for (int i = t; i < CH * (DH / 4); i += 256) {
        int r = i >> 6;
        int c4 = (i & 63) * 4;
        ushort4 kv = *(const ushort4*)(k + (qgbase + r) * DD + h * DH + c4);
        kt[r][c4+0] = bf2f(kv.x); kt[r][c4+1] = bf2f(kv.y);
        kt[r][c4+2] = bf2f(kv.z); kt[r][c4+3] = bf2f(kv.w);
    }
    if (t < CH) bet[t] = beta[(qgbase + t) * HH + h];
    __syncthreads();

    int c = t >> 3, e0 = (t & 7) * 4;
    {
        float accA[4] = {0,0,0,0}, accT[4] = {0,0,0,0};
        const unsigned short* qrow = q + (qgbase + c) * DD + h * DH;
        for (int d0 = 0; d0 < DH; d0 += 4) {
            float4 kc = *(const float4*)&kt[c][d0];
            ushort4 qv = *(const ushort4*)(qrow + d0);
            float qx = bf2f(qv.x), qy = bf2f(qv.y), qz = bf2f(qv.z), qw = bf2f(qv.w);
#pragma unroll
            for (int e = 0; e < 4; ++e) {
                float4 ke = *(const float4*)&kt[e0 + e][d0];
                accA[e] += kc.x*ke.x + kc.y*ke.y + kc.z*ke.z + kc.w*ke.w;
                accT[e] += qx*ke.x + qy*ke.y + qz*ke.z + qw*ke.w;
            }
        }
        float bc = bet[c];
        size_t abase = (size_t)blockIdx.x * (CH * CH) + (size_t)c * CH;
#pragma unroll
        for (int e = 0; e < 4; ++e) {
            int ee = e0 + e;
            Am[c][ee] = (ee < c) ? (-bc * accA[e]) : 0.0f;
            attn_out[abase + ee] = (ee <= c) ? f2bf(accT[e]) : (unsigned short)0;
        }
    }
    __syncthreads();

    for (int i = 1; i < CH; ++i) {
        float upd = 0.0f;
        if (t < i) {
#pragma unroll
            for (int kk = 0; kk < CH; ++kk) upd += Am[i][kk] * Am[kk][t];
        }
        __syncthreads();
        if (t < i) Am[i][t] += upd;
        __syncthreads();
    }

    for (int i = t; i < CH * CH; i += 256) {
        int cc = i >> 5, ee = i & 31;
        float val = Am[cc][ee] + (cc == ee ? 1.0f : 0.0f);
        Ab[cc][ee] = val * bet[ee];
    }
    __syncthreads();

    int c2 = t >> 3, dd0 = (t & 7) * 32;
    float accu[32];
#pragma unroll
    for (int j = 0; j < 32; ++j) accu[j] = 0.0f;
    for (int e = 0; e < CH; ++e) {
        float ab = Ab[c2][e];
        const float* vrow = v + (qgbase + e) * DD + h * DH + dd0;
#pragma unroll
        for (int j4 = 0; j4 < 8; ++j4) {
            float4 v4 = *(const float4*)(vrow + j4 * 4);
            accu[j4*4+0] += ab * v4.x; accu[j4*4+1] += ab * v4.y;
            accu[j4*4+2] += ab * v4.z; accu[j4*4+3] += ab * v4.w;
        }
    }
    size_t obase = ((size_t)bh * LL + (size_t)ci * CH + c2) * DH + dd0;
#pragma unroll
    for (int j4 = 0; j4 < 8; ++j4) {
        ushort4 o;
        o.x = f2bf(accu[j4*4+0]); o.y = f2bf(accu[j4*4+1]);
        o.z = f2bf(accu[j4*4+2]); o.w = f2bf(accu[j4*4+3]);
        *(ushort4*)(u_out + obase + j4*4) = o;
    }

#pragma unroll
    for (int j = 0; j < 32; ++j) accu[j] = 0.0f;
    for (int e = 0; e < CH; ++e) {
        float ab = Ab[c2][e];
#pragma unroll
        for (int j4 = 0; j4 < 8; ++j4) {
            float4 v4 = *(const float4*)&kt[e][dd0 + j4*4];
            accu[j4*4+0] += ab * v4.x; accu[j4*4+1] += ab * v4.y;
            accu[j4*4+2] += ab * v4.z; accu[j4*4+3] += ab * v4.w;
        }
    }
#pragma unroll
    for (int j4 = 0; j4 < 8; ++j4) {
        ushort4 o;
        o.x = f2bf(accu[j4*4+0]); o.y = f2bf(accu[j4*4+1]);
        o.z = f2bf(accu[j4*4+2]); o.w = f2bf(accu[j4*4+3]);
        *(ushort4*)(w_out + obase + j4*4) = o;
    }
}

// ------------------------------------------------- chunk scan v8: scan6 structure
// (full-K wave roles, prefetch dbuf, 2 LDS-only barriers/chunk) with TWO independent
// (bh,jb) tasks per 512-thread block -> 2 waves/SIMD for latency hiding.
// waves 0-3: task 0 (jb = jp*2), waves 4-7: task 1 (jb = jp*2+1).
// Within a task: wave0: w rows[0:16); wave1: w rows[16:32); wave2: q rows[0:16);
// wave3: q rows[16:32). Each wave owns S e-slice [64w,64w+64).
__global__ __launch_bounds__(512, 1) void scan8_k(
    const unsigned short* __restrict__ q, const unsigned short* __restrict__ kT,
    const unsigned short* __restrict__ uT, const unsigned short* __restrict__ w,
    const unsigned short* __restrict__ attn, float* __restrict__ dout)
{
    const int bh = blockIdx.x & 7;     // low bits -> same-bh blocks share one XCD
    const int jp = blockIdx.x >> 3;    // 0..7
    const int h = bh & (HH - 1), b = bh >> 2;
    const int task = threadIdx.x >> 8;          // 0,1
    const int jcol = (jp * 2 + task) * 16;
    const int wave = (threadIdx.x >> 6) & 3, lane = threadIdx.x & 63;
    const int lr = lane & 15, lg = lane >> 4;
    const int half = wave & 1;
    const bool isQ = wave >= 2;

    __shared__ unsigned short SbT[2][2][16][264];   // [task][par][col][e] bf16
    __shared__ unsigned short uadjT[2][2][16][40];  // [task][par][col][cc] bf16

    floatx4 Sacc[4];
#pragma unroll
    for (int mt = 0; mt < 4; ++mt) Sacc[mt] = (floatx4){0.f,0.f,0.f,0.f};

    const unsigned short* qb  = q + (size_t)b * LL * DD + h * DH;
    const unsigned short* wb  = w + (size_t)bh * LL * DH;
    const unsigned short* ob  = isQ ? qb : wb;
    const size_t ost          = isQ ? (size_t)DD : (size_t)DH;
    const unsigned short* uTb = uT + (size_t)bh * DH * LL
                                + (size_t)(jcol + lr) * LL + half * 16 + lg * 4;
    const unsigned short* kTb = kT + (size_t)bh * DH * LL;
    const unsigned short* atb = attn + (size_t)bh * NC * (CH * CH)
                                + (size_t)(half * 16 + lr) * CH + lg * 8;
    float* db = dout + (size_t)bh * LL * DH;

    short8 po[2][8];     // this wave's A rows, K=256
    short8 pk[2][4];     // kT A-frags for S-update
    short8 pa[2];        // attn frag (waves 2,3)
    ushort4 pu[2];       // u elems (waves 0,1)

    {   // preload chunk 0 -> slot 0
        const unsigned short* orow = ob + (size_t)(half * 16 + lr) * ost;
#pragma unroll
        for (int kt = 0; kt < 8; ++kt)
            po[0][kt] = *(const short8*)(orow + kt * 32 + lg * 8);
#pragma unroll
        for (int mt = 0; mt < 4; ++mt)
            pk[0][mt] = *(const short8*)(kTb + (size_t)(64 * wave + 16 * mt + lr) * LL + lg * 8);
        if (!isQ) pu[0] = *(const ushort4*)(uTb);
        else      pa[0] = *(const short8*)(atb);
    }

#pragma unroll 2
    for (int ci = 0; ci < NC; ++ci) {
        const int p = ci & 1;
        const int l0 = ci * CH;

        // 1) pack wave's S e-slice -> SbT[task][p][col][e]
#pragma unroll
        for (int mt = 0; mt < 4; ++mt) {
            int e0 = 64 * wave + 16 * mt + lg * 4;
            *(unsigned int*)&SbT[task][p][lr][e0]     = pkbf(Sacc[mt][0], Sacc[mt][1]);
            *(unsigned int*)&SbT[task][p][lr][e0 + 2] = pkbf(Sacc[mt][2], Sacc[mt][3]);
        }

        // prefetch chunk ci+1 (clamped) into slot p^1
        {
            const int cn = (ci + 1 < NC) ? (ci + 1) : ci;
            const int ln = cn * CH;
            const unsigned short* orow = ob + (size_t)(ln + half * 16 + lr) * ost;
#pragma unroll
            for (int kt = 0; kt < 8; ++kt)
                po[p^1][kt] = *(const short8*)(orow + kt * 32 + lg * 8);
#pragma unroll
            for (int mt = 0; mt < 4; ++mt)
                pk[p^1][mt] = *(const short8*)(kTb + (size_t)(64 * wave + 16 * mt + lr) * LL + ln + lg * 8);
            if (!isQ) pu[p^1] = *(const ushort4*)(uTb + ln);
            else      pa[p^1] = *(const short8*)(atb + (size_t)cn * (CH * CH));
        }
        lds_barrier();   // (a) SbT[task][p] visible

        // 2) P = A @ S over full K=256 (two independent chains for ILP)
        floatx4 Pa = (floatx4){0.f,0.f,0.f,0.f}, Pb = Pa;
#pragma unroll
        for (int kt = 0; kt < 4; ++kt) {
            short8 s0 = *(const short8*)&SbT[task][p][lr][(2*kt)   * 32 + lg * 8];
            short8 s1 = *(const short8*)&SbT[task][p][lr][(2*kt+1) * 32 + lg * 8];
            Pa = __builtin_amdgcn_mfma_f32_16x16x32_bf16(po[p][2*kt],   s0, Pa, 0,0,0);
            Pb = __builtin_amdgcn_mfma_f32_16x16x32_bf16(po[p][2*kt+1], s1, Pb, 0,0,0);
        }
        floatx4 P = Pa + Pb;

        // 3) waves 0,1: uadj = u - w@S -> uadjT[task][p]
        if (!isQ) {
            ushort4 u4 = pu[p];
            float ua0 = bf2f(u4.x) - P[0];
            float ua1 = bf2f(u4.y) - P[1];
            float ua2 = bf2f(u4.z) - P[2];
            float ua3 = bf2f(u4.w) - P[3];
            int cc0 = half * 16 + lg * 4;
            *(unsigned int*)&uadjT[task][p][lr][cc0]     = pkbf(ua0, ua1);
            *(unsigned int*)&uadjT[task][p][lr][cc0 + 2] = pkbf(ua2, ua3);
        }
        lds_barrier();   // (b) uadjT[task][p] visible

        short8 ub = *(const short8*)&uadjT[task][p][lr][lg * 8];

        // 4) waves 2,3: O = q@S + attn@uadj -> dout
        if (isQ) {
            floatx4 Ot = __builtin_amdgcn_mfma_f32_16x16x32_bf16(pa[p], ub, P, 0,0,0);
#pragma unroll
            for (int r = 0; r < 4; ++r)
                db[(size_t)(l0 + half * 16 + lg * 4 + r) * DH + jcol + lr] = Ot[r];
        }

        // 5) S e-slice += kT @ uadj
#pragma unroll
        for (int mt = 0; mt < 4; ++mt)
            Sacc[mt] = __builtin_amdgcn_mfma_f32_16x16x32_bf16(pk[p][mt], ub, Sacc[mt], 0,0,0);
        // no trailing barrier: parity p untouched until ci+2, guarded by (a),(b) of ci+1
    }
}

// ------------------------------------------------- per-head stats
__global__ __launch_bounds__(256) void stats_k(
    const float* __restrict__ ls, const float* __restrict__ llb,
    const float* __restrict__ dox, const float* __restrict__ v,
    float* __restrict__ stats)
{
    int bl = blockIdx.x;
    int b = bl >> 12, l = bl & (LL - 1);
    int wv = threadIdx.x >> 6, ln = threadIdx.x & 63;
    size_t ibase = (size_t)bl * DD + wv * DH;
    size_t dbase = (((size_t)(b * HH + wv)) * LL + l) * DH;
#pragma unroll
    for (int tn = 0; tn < 4; ++tn) {
        const float* p; size_t base;
        if (tn == 0)      { p = ls;  base = ibase; }
        else if (tn == 1) { p = llb; base = ibase; }
        else if (tn == 2) { p = dox; base = dbase; }
        else              { p = v;   base = ibase; }
        float4 x = *(const float4*)(p + base + ln * 4);
        float sm = x.x + x.y + x.z + x.w;
        float sq = x.x*x.x + x.y*x.y + x.z*x.z + x.w*x.w;
        float sa = fabsf(x.x) + fabsf(x.y) + fabsf(x.z) + fabsf(x.w);
#pragma unroll
        for (int off = 32; off > 0; off >>= 1) {
            sm += __shfl_down(sm, off);
            sq += __shfl_down(sq, off);
            sa += __shfl_down(sa, off);
        }
        if (ln == 0) {
            float mean = sm * (1.0f / DH);
            float var = sq * (1.0f / DH) - mean * mean;
            float am = sa * (1.0f / DH);
            float l2 = sqrtf(sq);
            *(float4*)(stats + (size_t)bl * 64 + wv * 16 + tn * 4) =
                make_float4(mean, var, am, l2);
        }
    }
}

// ------------------------------------------------- gate finish v2
__global__ __launch_bounds__(256) void gate_fin2_k(
    const float* __restrict__ hpart, const float* __restrict__ stats,
    const unsigned short* __restrict__ w1s,
    const float* __restrict__ w2, const float* __restrict__ b2,
    const float* __restrict__ ltemp, float* __restrict__ fw)
{
    const int bl = blockIdx.x;
    const int t = threadIdx.x;
    const float temp = log1pf(expf(ltemp[0])) + 1e-4f;
    __shared__ float st[HH][16];
    __shared__ float red[4][16];
    __shared__ float fin[16];
    if (t < 64) st[t >> 4][t & 15] = stats[(size_t)bl * 64 + t];

    const int e0 = t * 4;
    float4 hp4 = *(const float4*)(hpart + (size_t)bl * DD + e0);
    float hp[4] = {hp4.x, hp4.y, hp4.z, hp4.w};
    float w2a[4][4];
#pragma unroll
    for (int j = 0; j < 4; ++j) {
        float4 wv = *(const float4*)(w2 + (size_t)j * 1024 + e0);
        w2a[j][0] = wv.x; w2a[j][1] = wv.y; w2a[j][2] = wv.z; w2a[j][3] = wv.w;
    }
    uint4 wpk[8];
    const uint4* wp = (const uint4*)(w1s + (size_t)e0 * 16);
#pragma unroll
    for (int i = 0; i < 8; ++i) wpk[i] = wp[i];
    __syncthreads();

    float lg[4][4];
#pragma unroll
    for (int h = 0; h < 4; ++h)
#pragma unroll
        for (int j = 0; j < 4; ++j) lg[h][j] = 0.0f;

#pragma unroll
    for (int ii = 0; ii < 4; ++ii) {
        float xh[4] = {hp[ii], hp[ii], hp[ii], hp[ii]};
        unsigned arr[8] = {wpk[ii*2].x, wpk[ii*2].y, wpk[ii*2].z, wpk[ii*2].w,
                           wpk[ii*2+1].x, wpk[ii*2+1].y, wpk[ii*2+1].z, wpk[ii*2+1].w};
#pragma unroll
        for (int p = 0; p < 8; ++p) {
            float wlo = bflo(arr[p]), whi = bfhi(arr[p]);
            int s = p * 2;
#pragma unroll
            for (int h = 0; h < 4; ++h)
                xh[h] += st[h][s] * wlo + st[h][s + 1] * whi;
        }
#pragma unroll
        for (int h = 0; h < 4; ++h) {
            float x = xh[h];
            float gct = 0.5f * x * (1.0f + erff(x * 0.70710678118654752f));
            lg[h][0] += gct * w2a[0][ii];
            lg[h][1] += gct * w2a[1][ii];
            lg[h][2] += gct * w2a[2][ii];
            lg[h][3] += gct * w2a[3][ii];
        }
    }

#pragma unroll
    for (int h = 0; h < 4; ++h)
#pragma unroll
        for (int j = 0; j < 4; ++j)
#pragma unroll
            for (int off = 32; off > 0; off >>= 1)
                lg[h][j] += __shfl_down(lg[h][j], off);

    const int wv = t >> 6, ln = t & 63;
    if (ln == 0) {
#pragma unroll
        for (int h = 0; h < 4; ++h)
#pragma unroll
            for (int j = 0; j < 4; ++j) red[wv][h * 4 + j] = lg[h][j];
    }
    __syncthreads();
    if (t < 16) {
        float s = red[0][t] + red[1][t] + red[2][t] + red[3][t] + b2[t & 3];
        fin[t] = s / temp;
    }
    __syncthreads();
    if (t < 4) {
        float l0 = fin[t*4], l1 = fin[t*4+1], l2 = fin[t*4+2], l3 = fin[t*4+3];
        float m = fmaxf(fmaxf(l0, l1), fmaxf(l2, l3));
        float e0x = expf(l0-m), e1 = expf(l1-m), e2 = expf(l2-m), e3 = expf(l3-m);
        float inv = 1.0f / (e0x + e1 + e2 + e3);
        *(float4*)(fw + (size_t)bl * 16 + t * 4) = make_float4(e0x*inv, e1*inv, e2*inv, e3*inv);
    }
}

// ------------------------------------------------- combine + rms norm
__global__ __launch_bounds__(256) void combine_k(
    const float* __restrict__ ls, const float* __restrict__ llb,
    const float* __restrict__ dox, const float* __restrict__ v,
    const float* __restrict__ fw, const float* __restrict__ rss,
    const float* __restrict__ rsl, const float* __restrict__ onw,
    float* __restrict__ opre)
{
    int h = blockIdx.x & (HH - 1);
    int bl = blockIdx.x >> 2;
    int b = bl >> 12, l = bl & (LL - 1);
    int d = threadIdx.x;
    size_t i1 = (size_t)blockIdx.x * DH + d;
    size_t i2 = (((size_t)(b * HH + h)) * LL + l) * DH + d;
    const float* fwp = fw + (size_t)blockIdx.x * 4;
    float f0 = fwp[0], f1 = fwp[1], f2 = fwp[2], f3 = fwp[3];
    float aS = rss[0], aL = rsl[0];
    float vls = ls[i1], vll = llb[i1], vd = dox[i2], vv = v[i1];
    float o = f0*vls + f1*vll + f2*vd + f3*vv + aS*vls + aL*vll;
    float s = o * o;
#pragma unroll
    for (int off = 32; off > 0; off >>= 1) s += __shfl_down(s, off);
    __shared__ float red[4];
    int wv = threadIdx.x >> 6, ln = threadIdx.x & 63;
    if (ln == 0) red[wv] = s;
    __syncthreads();
    float ms = (red[0] + red[1] + red[2] + red[3]) * (1.0f / DH);
    opre[(size_t)bl * DD + h * DH + d] = o * rsqrtf(ms + 1e-5f) * onw[d];
}

// ================================================================ launch
extern "C" void kernel_launch(void* const* d_in, const int* in_sizes, int n_in,
                              void* d_out, int out_size, void* d_ws, size_t ws_size,
                              hipStream_t stream)
{
    const float* hs  = (const float*)d_in[0];
    const float* qw  = (const float*)d_in[1];
    const float* kw  = (const float*)d_in[2];
    const float* vw  = (const float*)d_in[3];
    const float* bw  = (const float*)d_in[4];
    const float* qcw = (const float*)d_in[5];
    const float* kcw = (const float*)d_in[6];
    const float* vcw = (const float*)d_in[7];
    const float* fsw = (const float*)d_in[8];
    const float* flw = (const float*)d_in[9];
    const float* w1  = (const float*)d_in[10];
    const float* b1  = (const float*)d_in[11];
    const float* w2  = (const float*)d_in[12];
    const float* b2  = (const float*)d_in[13];
    const float* lt  = (const float*)d_in[14];
    const float* rss = (const float*)d_in[15];
    const float* rsl = (const float*)d_in[16];
    const float* onw = (const float*)d_in[17];
    const float* opw = (const float*)d_in[18];
    float* out = (float*)d_out;

    float* wsf = (float*)d_ws;
    float* tmp   = wsf;
    unsigned short* ktbuf = (unsigned short*)tmp;
    unsigned short* uTbuf = (unsigned short*)(wsf + BLD/2);
    float* vbuf  = wsf + BLD;
    float* dbuf  = wsf + 2*BLD;
    // hsb shares the dbuf region -> DEAD once scan8 writes dbuf. Only used in phase 1.
    unsigned short* hsb = (unsigned short*)(wsf + 2*BLD);
    // bf16 QKV weights live in the dead second half of the dbuf region during phase 1
    unsigned short* qwb = (unsigned short*)(wsf + 2*BLD + BLD/2);
    unsigned short* kwb = qwb + (size_t)DD*DD;
    unsigned short* vwb = kwb + (size_t)DD*DD;
    unsigned short* qbuf = (unsigned short*)(wsf + 3*BLD);
    unsigned short* kbuf = qbuf + BLD;
    float* hpart = wsf + 3*BLD;
    float* opre  = wsf + 3*BLD;
    unsigned short* ubuf = (unsigned short*)(wsf + 4*BLD);
    unsigned short* wbuf = ubuf + BLD;
    float* llbuf = wsf + 4*BLD;
    float* lsbuf = tmp;
    unsigned short* attnb = (unsigned short*)(wsf + 5*BLD);
    float* statsb = wsf + 5*BLD + 524288;
    float* fwbuf  = statsb + (size_t)BL*HH*16;
    float* betab  = fwbuf + (size_t)BL*HH*4;
    unsigned short* w1sp = (unsigned short*)(betab + (size_t)BL*HH);

    dim3 gg(8, 64);   // N/128, M/128

    cvt_bf_k<<<(int)(BLD/1024), 256, 0, stream>>>(hs, hsb);
    cvt_bf_k<<<1024, 256, 0, stream>>>(qw, qwb);
    cvt_bf_k<<<1024, 256, 0, stream>>>(kw, kwb);
    cvt_bf_k<<<1024, 256, 0, stream>>>(vw, vwb);
    w1s_prep_k<<<64, 256, 0, stream>>>(w1, w1sp);

    gemm_bb<<<gg, 256, 0, stream>>>(hsb, DD, qwb, DD, tmp, DD, DD);
    convnorm_qk_k<<<BL*HH, 256, 0, stream>>>(tmp, qcw, qbuf);
    gemm_bb<<<gg, 256, 0, stream>>>(hsb, DD, kwb, DD, tmp, DD, DD);
    convnorm_qk_k<<<BL*HH, 256, 0, stream>>>(tmp, kcw, kbuf);
    gemm_bb<<<gg, 256, 0, stream>>>(hsb, DD, vwb, DD, tmp, DD, DD);
    conv_silu_k<<<(int)(BLD/256), 256, 0, stream>>>(tmp, vcw, vbuf);

    beta_k<<<BL, 256, 0, stream>>>(hs, bw, betab);

    tr_k<<<8*64*4, 256, 0, stream>>>(kbuf, ktbuf);
    chunk_prep_k<<<BB*HH*NC, 256, 0, stream>>>(qbuf, kbuf, vbuf, betab, ubuf, wbuf, attnb);
    tru_k<<<8*64*4, 256, 0, stream>>>(ubuf, uTbuf);

    scan8_k<<<BB*HH*8, 512, 0, stream>>>(qbuf, ktbuf, uTbuf, wbuf, attnb, dbuf);

    fir2_k<5><<<BB*64*16, 256, 0, stream>>>(vbuf, fsw, lsbuf);
    fir2_k<64><<<BB*64*16, 256, 0, stream>>>(vbuf, flw, llbuf);

    stats_k<<<BL, 256, 0, stream>>>(lsbuf, llbuf, dbuf, vbuf, statsb);

    // hpart GEMM reads the pristine f32 input hs (hsb is dead: overwritten by dbuf)
    gemm_mfma<<<gg, 256, 0, stream>>>(hs, DD, w1, 1040, b1, hpart, DD, DD);
    gate_fin2_k<<<BL, 256, 0, stream>>>(hpart, statsb, w1sp, w2, b2, lt, fwbuf);

    combine_k<<<BL*HH, 256, 0, stream>>>(lsbuf, llbuf, dbuf, vbuf, fwbuf, rss, rsl, onw, opre);

    gemm_mfma<<<gg, 256, 0, stream>>>(opre, DD, opw, DD, nullptr, out, DD, DD);
}

// Round 3
// 1003.952 us; speedup vs baseline: 1.4067x; 1.1769x over previous
//
#include <hip/hip_runtime.h>
#include <hip/hip_bf16.h>

#define BB 2
#define LL 4096
#define DD 1024
#define HH 4
#define DH 256
#define CH 32
#define NC (LL/CH)     // 128
#define BL (BB*LL)     // 8192
#define BLD ((size_t)BB*LL*DD) // 8388608

typedef __attribute__((ext_vector_type(8))) short short8;
typedef __attribute__((ext_vector_type(4))) float floatx4;

__device__ __forceinline__ float bf2f(unsigned short u) {
    union { float f; unsigned int i; } x; x.i = ((unsigned int)u) << 16; return x.f;
}
__device__ __forceinline__ float bflo(unsigned int u) {
    union { float f; unsigned int i; } x; x.i = u << 16; return x.f;
}
__device__ __forceinline__ float bfhi(unsigned int u) {
    union { float f; unsigned int i; } x; x.i = u & 0xFFFF0000u; return x.f;
}
__device__ __forceinline__ unsigned short f2bf(float f) {
    union { float f; unsigned int i; } x; x.f = f;
    unsigned int r = x.i + 0x7FFFu + ((x.i >> 16) & 1u);
    return (unsigned short)(r >> 16);
}
// pack two f32 -> (bf16(b)<<16)|bf16(a), round-half-up
__device__ __forceinline__ unsigned int pkbf(float a, float b) {
    unsigned int ua = __float_as_uint(a) + 0x8000u;
    unsigned int ub = __float_as_uint(b) + 0x8000u;
    return __builtin_amdgcn_perm(ub, ua, 0x07060302);
}
// barrier with LDS-only drain (no vmcnt drain -> prefetch loads stay in flight)
__device__ __forceinline__ void lds_barrier() {
    __builtin_amdgcn_s_waitcnt(0xC07F);
    __builtin_amdgcn_s_barrier();
}

// ---------------------------------------------------------------- f32 -> bf16 bulk convert
__global__ __launch_bounds__(256) void cvt_bf_k(
    const float* __restrict__ x, unsigned short* __restrict__ y)
{
    size_t i = ((size_t)blockIdx.x * 256 + threadIdx.x) * 4;
    float4 v = *(const float4*)(x + i);
    ushort4 o;
    o.x = f2bf(v.x); o.y = f2bf(v.y); o.z = f2bf(v.z); o.w = f2bf(v.w);
    *(ushort4*)(y + i) = o;
}

// ---------------------------------------------------------------- pack w1[:,1024:1040] -> bf16 [1024][16]
__global__ __launch_bounds__(256) void w1s_prep_k(
    const float* __restrict__ w1, unsigned short* __restrict__ w1s)
{
    int idx = blockIdx.x * 256 + threadIdx.x;   // 16384
    int e = idx >> 4, s = idx & 15;
    w1s[idx] = f2bf(w1[(size_t)e * 1040 + 1024 + s]);
}

// ---------------------------------------------------------------- bf16 MFMA GEMM (NT), f32 A, f32 W
__global__ __launch_bounds__(256) void gemm_mfma(
    const float* __restrict__ A, int lda,
    const float* __restrict__ W, int ldw,
    const float* __restrict__ bias,
    float* __restrict__ C, int ldc, int K)
{
    __shared__ unsigned short Abuf[128][56];
    __shared__ unsigned short Bbuf[128][56];
    const int t = threadIdx.x;
    const int wave = t >> 6, lane = t & 63;
    const int wm = wave >> 1, wn = wave & 1;
    const int row0 = blockIdx.y * 128, col0 = blockIdx.x * 128;

    floatx4 acc[4][4];
#pragma unroll
    for (int i = 0; i < 4; ++i)
#pragma unroll
        for (int j = 0; j < 4; ++j) acc[i][j] = (floatx4){0.f, 0.f, 0.f, 0.f};

    const int fr = lane & 15, fk = (lane >> 4) * 8;

    for (int kt = 0; kt < K; kt += 32) {
        __syncthreads();
#pragma unroll
        for (int it = 0; it < 2; ++it) {
            int idx = t + it * 256;
            int r = idx >> 2, s = (idx & 3) * 8;
            const float* ap = A + (size_t)(row0 + r) * lda + kt + s;
            float4 a0 = *(const float4*)(ap);
            float4 a1 = *(const float4*)(ap + 4);
            ushort4 p0, p1;
            p0.x = f2bf(a0.x); p0.y = f2bf(a0.y); p0.z = f2bf(a0.z); p0.w = f2bf(a0.w);
            p1.x = f2bf(a1.x); p1.y = f2bf(a1.y); p1.z = f2bf(a1.z); p1.w = f2bf(a1.w);
            *(ushort4*)&Abuf[r][s]     = p0;
            *(ushort4*)&Abuf[r][s + 4] = p1;
            const float* wp = W + (size_t)(col0 + r) * ldw + kt + s;
            float4 b0 = *(const float4*)(wp);
            float4 b1 = *(const float4*)(wp + 4);
            ushort4 q0, q1;
            q0.x = f2bf(b0.x); q0.y = f2bf(b0.y); q0.z = f2bf(b0.z); q0.w = f2bf(b0.w);
            q1.x = f2bf(b1.x); q1.y = f2bf(b1.y); q1.z = f2bf(b1.z); q1.w = f2bf(b1.w);
            *(ushort4*)&Bbuf[r][s]     = q0;
            *(ushort4*)&Bbuf[r][s + 4] = q1;
        }
        __syncthreads();

        short8 afrag[4], bfrag[4];
#pragma unroll
        for (int i = 0; i < 4; ++i) {
            afrag[i] = *(const short8*)&Abuf[wm * 64 + i * 16 + fr][fk];
            bfrag[i] = *(const short8*)&Bbuf[wn * 64 + i * 16 + fr][fk];
        }
#pragma unroll
        for (int i = 0; i < 4; ++i)
#pragma unroll
            for (int j = 0; j < 4; ++j)
                acc[i][j] = __builtin_amdgcn_mfma_f32_16x16x32_bf16(
                    afrag[i], bfrag[j], acc[i][j], 0, 0, 0);
    }

    const int fc = lane & 15, frow = (lane >> 4) * 4;
#pragma unroll
    for (int j = 0; j < 4; ++j) {
        int col = col0 + wn * 64 + j * 16 + fc;
        float bv = bias ? bias[col] : 0.0f;
#pragma unroll
        for (int i = 0; i < 4; ++i) {
#pragma unroll
            for (int r = 0; r < 4; ++r) {
                int row = row0 + wm * 64 + i * 16 + frow + r;
                C[(size_t)row * ldc + col] = acc[i][j][r] + bv;
            }
        }
    }
}

// ---------------------------------------------------------------- bf16 MFMA GEMM (NT), bf16 A, bf16 B
__global__ __launch_bounds__(256) void gemm_bb(
    const unsigned short* __restrict__ A, int lda,
    const unsigned short* __restrict__ B, int ldb,
    float* __restrict__ C, int ldc, int K)
{
    __shared__ unsigned short Abuf[128][56];
    __shared__ unsigned short Bbuf[128][56];
    const int t = threadIdx.x;
    const int wave = t >> 6, lane = t & 63;
    const int wm = wave >> 1, wn = wave & 1;
    const int row0 = blockIdx.y * 128, col0 = blockIdx.x * 128;

    floatx4 acc[4][4];
#pragma unroll
    for (int i = 0; i < 4; ++i)
#pragma unroll
        for (int j = 0; j < 4; ++j) acc[i][j] = (floatx4){0.f, 0.f, 0.f, 0.f};

    const int fr = lane & 15, fk = (lane >> 4) * 8;

    for (int kt = 0; kt < K; kt += 32) {
        __syncthreads();
#pragma unroll
        for (int it = 0; it < 2; ++it) {
            int idx = t + it * 256;
            int r = idx >> 2, s = (idx & 3) * 8;
            uint4 av = *(const uint4*)(A + (size_t)(row0 + r) * lda + kt + s);
            *(uint4*)&Abuf[r][s] = av;
            uint4 bv = *(const uint4*)(B + (size_t)(col0 + r) * ldb + kt + s);
            *(uint4*)&Bbuf[r][s] = bv;
        }
        __syncthreads();

        short8 afrag[4], bfrag[4];
#pragma unroll
        for (int i = 0; i < 4; ++i) {
            afrag[i] = *(const short8*)&Abuf[wm * 64 + i * 16 + fr][fk];
            bfrag[i] = *(const short8*)&Bbuf[wn * 64 + i * 16 + fr][fk];
        }
#pragma unroll
        for (int i = 0; i < 4; ++i)
#pragma unroll
            for (int j = 0; j < 4; ++j)
                acc[i][j] = __builtin_amdgcn_mfma_f32_16x16x32_bf16(
                    afrag[i], bfrag[j], acc[i][j], 0, 0, 0);
    }

    const int fc = lane & 15, frow = (lane >> 4) * 4;
#pragma unroll
    for (int j = 0; j < 4; ++j) {
        int col = col0 + wn * 64 + j * 16 + fc;
#pragma unroll
        for (int i = 0; i < 4; ++i) {
#pragma unroll
            for (int r = 0; r < 4; ++r) {
                int row = row0 + wm * 64 + i * 16 + frow + r;
                C[(size_t)row * ldc + col] = acc[i][j][r];
            }
        }
    }
}

// --------------------------------------- causal dwconv K=4 + silu + head-l2norm -> bf16
__global__ __launch_bounds__(256) void convnorm_qk_k(
    const float* __restrict__ x, const float* __restrict__ w,
    unsigned short* __restrict__ y)
{
    int bl = blockIdx.x >> 2;
    int h  = blockIdx.x & 3;
    int l  = bl & (LL - 1);
    int d  = threadIdx.x;
    int c  = h * DH + d;
    const float* wp = w + (size_t)c * 4;
    const float* xp = x + (size_t)bl * DD + c;
    float acc = wp[3] * xp[0];
    if (l >= 1) acc += wp[2] * xp[-(int)DD];
    if (l >= 2) acc += wp[1] * xp[-2*(int)DD];
    if (l >= 3) acc += wp[0] * xp[-3*(int)DD];
    acc = acc / (1.0f + expf(-acc));
    float s = acc * acc;
#pragma unroll
    for (int off = 32; off > 0; off >>= 1) s += __shfl_down(s, off);
    __shared__ float red[4];
    int wv = threadIdx.x >> 6, ln = threadIdx.x & 63;
    if (ln == 0) red[wv] = s;
    __syncthreads();
    float tot = red[0] + red[1] + red[2] + red[3];
    y[(size_t)bl * DD + c] = f2bf(acc * rsqrtf(tot));
}

// ------------------------------------------------- causal depthwise conv K=4 + silu (f32)
__global__ __launch_bounds__(256) void conv_silu_k(
    const float* __restrict__ x, const float* __restrict__ w, float* __restrict__ y)
{
    size_t idx = (size_t)blockIdx.x * 256 + threadIdx.x;
    int c = (int)(idx & (DD - 1));
    int bl = (int)(idx >> 10);
    int l = bl & (LL - 1);
    const float* wp = w + (size_t)c * 4;
    const float* xp = x + (size_t)bl * DD + c;
    float acc = wp[3] * xp[0];
    if (l >= 1) acc += wp[2] * xp[-(int)DD];
    if (l >= 2) acc += wp[1] * xp[-2*(int)DD];
    if (l >= 3) acc += wp[0] * xp[-3*(int)DD];
    y[idx] = acc / (1.0f + expf(-acc));
}

// ------------------------------------------------- FIR causal depthwise conv, LDS-tiled
template<int K>
__global__ __launch_bounds__(256) void fir2_k(
    const float* __restrict__ x, const float* __restrict__ filt, float* __restrict__ y)
{
    const int ctile = blockIdx.x & 15;
    const int ltile = (blockIdx.x >> 4) & 63;
    const int b = blockIdx.x >> 10;
    const int RT = 64 + K - 1;
    __shared__ float xs[RT][64];
    __shared__ float fs[64][K + 1];
    const int t = threadIdx.x;
    const int l0 = ltile * 64;

    for (int i = t; i < RT * 16; i += 256) {
        int li = i >> 4, c4 = (i & 15) * 4;
        int l = l0 - (K - 1) + li;
        float4 v = make_float4(0.f, 0.f, 0.f, 0.f);
        if (l >= 0)
            v = *(const float4*)(x + ((size_t)b * LL + l) * DD + ctile * 64 + c4);
        *(float4*)&xs[li][c4] = v;
    }
    for (int i = t; i < 64 * K; i += 256) {
        fs[i / K][i % K] = filt[(size_t)ctile * 64 * K + i];
    }
    __syncthreads();

    const int c = t & 63, lg = t >> 6;
    float acc[16];
#pragma unroll
    for (int o = 0; o < 16; ++o) acc[o] = 0.f;
#pragma unroll
    for (int j = 0; j < 16 + K - 1; ++j) {
        float xv = xs[lg * 16 + j][c];
#pragma unroll
        for (int o = 0; o < 16; ++o) {
            int tap = j - o;
            if (tap >= 0 && tap < K) acc[o] += fs[c][tap] * xv;
        }
    }
    size_t base = ((size_t)b * LL + l0 + lg * 16) * DD + ctile * 64 + c;
#pragma unroll
    for (int o = 0; o < 16; ++o)
        y[base + (size_t)o * DD] = acc[o];
}

// ------------------------------------------------- beta = sigmoid(hs @ b_proj^T)
__global__ __launch_bounds__(256) void beta_k(
    const float* __restrict__ hs, const float* __restrict__ bw, float* __restrict__ beta)
{
    int bl = blockIdx.x;
    const float* xr = hs + (size_t)bl * DD;
    float a0=0.f,a1=0.f,a2=0.f,a3=0.f;
    for (int k = threadIdx.x; k < DD; k += 256) {
        float xv = xr[k];
        a0 += xv * bw[k];
        a1 += xv * bw[DD + k];
        a2 += xv * bw[2*DD + k];
        a3 += xv * bw[3*DD + k];
    }
#pragma unroll
    for (int off = 32; off > 0; off >>= 1) {
        a0 += __shfl_down(a0, off); a1 += __shfl_down(a1, off);
        a2 += __shfl_down(a2, off); a3 += __shfl_down(a3, off);
    }
    __shared__ float red[4][4];
    int wv = threadIdx.x >> 6, ln = threadIdx.x & 63;
    if (ln == 0) { red[wv][0]=a0; red[wv][1]=a1; red[wv][2]=a2; red[wv][3]=a3; }
    __syncthreads();
    if (threadIdx.x < 4) {
        int h = threadIdx.x;
        float s = red[0][h] + red[1][h] + red[2][h] + red[3][h];
        beta[(size_t)bl * HH + h] = 1.0f / (1.0f + expf(-s));
    }
}

// ------------------------------------------------- k transpose: k[b,l,h*DH+e] -> kT[bh,e,l]
__global__ __launch_bounds__(256) void tr_k(
    const unsigned short* __restrict__ k, unsigned short* __restrict__ kT)
{
    int et = blockIdx.x & 3;
    int lt = (blockIdx.x >> 2) & 63;
    int bh = blockIdx.x >> 8;
    int h = bh & 3, b = bh >> 2;
    __shared__ unsigned short tile[64][72];
    int t = threadIdx.x;
    int tr = t >> 4;
    int tc = (t & 15) * 4;
#pragma unroll
    for (int i = 0; i < 4; ++i) {
        int l = tr + i * 16;
        ushort4 v = *(const ushort4*)(k + ((size_t)b * LL + lt*64 + l) * DD + h * DH + et*64 + tc);
        *(ushort4*)&tile[l][tc] = v;
    }
    __syncthreads();
#pragma unroll
    for (int i = 0; i < 4; ++i) {
        int e = tr + i * 16;
        ushort4 v;
        v.x = tile[tc+0][e]; v.y = tile[tc+1][e];
        v.z = tile[tc+2][e]; v.w = tile[tc+3][e];
        *(ushort4*)(kT + ((size_t)bh * DH + et*64 + e) * LL + (size_t)lt*64 + tc) = v;
    }
}

// ------------------------------------------------- u transpose: u[bh,l,d] -> uT[bh,d,l]
__global__ __launch_bounds__(256) void tru_k(
    const unsigned short* __restrict__ u, unsigned short* __restrict__ uT)
{
    int et = blockIdx.x & 3;
    int lt = (blockIdx.x >> 2) & 63;
    int bh = blockIdx.x >> 8;
    __shared__ unsigned short tile[64][72];
    int t = threadIdx.x;
    int tr = t >> 4;
    int tc = (t & 15) * 4;
#pragma unroll
    for (int i = 0; i < 4; ++i) {
        int l = tr + i * 16;
        ushort4 v = *(const ushort4*)(u + ((size_t)bh * LL + lt*64 + l) * DH + et*64 + tc);
        *(ushort4*)&tile[l][tc] = v;
    }
    __syncthreads();
#pragma unroll
    for (int i = 0; i < 4; ++i) {
        int e = tr + i * 16;
        ushort4 v;
        v.x = tile[tc+0][e]; v.y = tile[tc+1][e];
        v.z = tile[tc+2][e]; v.w = tile[tc+3][e];
        *(ushort4*)(uT + ((size_t)bh * DH + et*64 + e) * LL + (size_t)lt*64 + tc) = v;
    }
}

// ------------------------------------------------- per-chunk prep (attn out bf16)
__global__ __launch_bounds__(256) void chunk_prep_k(
    const unsigned short* __restrict__ q, const unsigned short* __restrict__ k,
    const float* __restrict__ v, const float* __restrict__ beta,
    unsigned short* __restrict__ u_out, unsigned short* __restrict__ w_out,
    unsigned short* __restrict__ attn_out)
{
    int ci = blockIdx.x & (NC - 1);
    int bh = blockIdx.x >> 7;
    int h = bh & (HH - 1), b = bh >> 2;
    __shared__ float kt[CH][DH + 4];
    __shared__ float Am[CH][CH + 1];
    __shared__ float Ab[CH][CH + 1];
    __shared__ float bet[CH];
    int t = threadIdx.x;
    size_t qgbase = (size_t)b * LL + (size_t)ci * CH;

    for (int i = t; i < CH * (DH / 4); i += 256) {
        int r = i >> 6;
        int c4 = (i & 63) * 4;
        ushort4 kv = *(const ushort4*)(k + (qgbase + r) * DD + h * DH + c4);
        kt[r][c4+0] = bf2f(kv.x); kt[r][c4+1] = bf2f(kv.y);
        kt[r][c4+2] = bf2f(kv.z); kt[r][c4+3] = bf2f(kv.w);
    }
    if (t < CH) bet[t] = beta[(qgbase + t) * HH + h];
    __syncthreads();

    int c = t >> 3, e0 = (t & 7) * 4;
    {
        float accA[4] = {0,0,0,0}, accT[4] = {0,0,0,0};
        const unsigned short* qrow = q + (qgbase + c) * DD + h * DH;
        for (int d0 = 0; d0 < DH; d0 += 4) {
            float4 kc = *(const float4*)&kt[c][d0];
            ushort4 qv = *(const ushort4*)(qrow + d0);
            float qx = bf2f(qv.x), qy = bf2f(qv.y), qz = bf2f(qv.z), qw = bf2f(qv.w);
#pragma unroll
            for (int e = 0; e < 4; ++e) {
                float4 ke = *(const float4*)&kt[e0 + e][d0];
                accA[e] += kc.x*ke.x + kc.y*ke.y + kc.z*ke.z + kc.w*ke.w;
                accT[e] += qx*ke.x + qy*ke.y + qz*ke.z + qw*ke.w;
            }
        }
        float bc = bet[c];
        size_t abase = (size_t)blockIdx.x * (CH * CH) + (size_t)c * CH;
#pragma unroll
        for (int e = 0; e < 4; ++e) {
            int ee = e0 + e;
            Am[c][ee] = (ee < c) ? (-bc * accA[e]) : 0.0f;
            attn_out[abase + ee] = (ee <= c) ? f2bf(accT[e]) : (unsigned short)0;
        }
    }
    __syncthreads();

    for (int i = 1; i < CH; ++i) {
        float upd = 0.0f;
        if (t < i) {
#pragma unroll
            for (int kk = 0; kk < CH; ++kk) upd += Am[i][kk] * Am[kk][t];
        }
        __syncthreads();
        if (t < i) Am[i][t] += upd;
        __syncthreads();
    }

    for (int i = t; i < CH * CH; i += 256) {
        int cc = i >> 5, ee = i & 31;
        float val = Am[cc][ee] + (cc == ee ? 1.0f : 0.0f);
        Ab[cc][ee] = val * bet[ee];
    }
    __syncthreads();

    int c2 = t >> 3, dd0 = (t & 7) * 32;
    float accu[32];
#pragma unroll
    for (int j = 0; j < 32; ++j) accu[j] = 0.0f;
    for (int e = 0; e < CH; ++e) {
        float ab = Ab[c2][e];
        const float* vrow = v + (qgbase + e) * DD + h * DH + dd0;
#pragma unroll
        for (int j4 = 0; j4 < 8; ++j4) {
            float4 v4 = *(const float4*)(vrow + j4 * 4);
            accu[j4*4+0] += ab * v4.x; accu[j4*4+1] += ab * v4.y;
            accu[j4*4+2] += ab * v4.z; accu[j4*4+3] += ab * v4.w;
        }
    }
    size_t obase = ((size_t)bh * LL + (size_t)ci * CH + c2) * DH + dd0;
#pragma unroll
    for (int j4 = 0; j4 < 8; ++j4) {
        ushort4 o;
        o.x = f2bf(accu[j4*4+0]); o.y = f2bf(accu[j4*4+1]);
        o.z = f2bf(accu[j4*4+2]); o.w = f2bf(accu[j4*4+3]);
        *(ushort4*)(u_out + obase + j4*4) = o;
    }

#pragma unroll
    for (int j = 0; j < 32; ++j) accu[j] = 0.0f;
    for (int e = 0; e < CH; ++e) {
        float ab = Ab[c2][e];
#pragma unroll
        for (int j4 = 0; j4 < 8; ++j4) {
            float4 v4 = *(const float4*)&kt[e][dd0 + j4*4];
            accu[j4*4+0] += ab * v4.x; accu[j4*4+1] += ab * v4.y;
            accu[j4*4+2] += ab * v4.z; accu[j4*4+3] += ab * v4.w;
        }
    }
#pragma unroll
    for (int j4 = 0; j4 < 8; ++j4) {
        ushort4 o;
        o.x = f2bf(accu[j4*4+0]); o.y = f2bf(accu[j4*4+1]);
        o.z = f2bf(accu[j4*4+2]); o.w = f2bf(accu[j4*4+3]);
        *(ushort4*)(w_out + obase + j4*4) = o;
    }
}

// ------------------------------------------------- chunk scan v9: scan6 structure
// (full-K wave roles, 2 LDS-only barriers/chunk, XCD swizzle, register dbuf prefetch)
// + __launch_bounds__(256,1): at 1 block/CU the full 512-VGPR file is available, so
// the po/pk/pa/pu double-buffer (~110 VGPR) actually stays register-resident and the
// prefetch loads remain in flight a full chunk ahead (they were being sunk to
// just-before-use at the default 104-VGPR budget -> ~13 x 210cy serial L2 latency).
__global__ __launch_bounds__(256, 1) void scan9_k(
    const unsigned short* __restrict__ q, const unsigned short* __restrict__ kT,
    const unsigned short* __restrict__ uT, const unsigned short* __restrict__ w,
    const unsigned short* __restrict__ attn, float* __restrict__ dout)
{
    const int bh = blockIdx.x & 7;     // low bits -> 16 same-bh blocks share one XCD
    const int jb = blockIdx.x >> 3;
    const int h = bh & (HH - 1), b = bh >> 2;
    const int jcol = jb * 16;
    const int wave = threadIdx.x >> 6, lane = threadIdx.x & 63;
    const int lr = lane & 15, lg = lane >> 4;
    const int half = wave & 1;
    const bool isQ = wave >= 2;

    __shared__ unsigned short SbT[2][16][264];   // [par][col][e] bf16
    __shared__ unsigned short uadjT[2][16][40];  // [par][col][cc] bf16

    floatx4 Sacc[4];
#pragma unroll
    for (int mt = 0; mt < 4; ++mt) Sacc[mt] = (floatx4){0.f,0.f,0.f,0.f};

    const unsigned short* qb  = q + (size_t)b * LL * DD + h * DH;
    const unsigned short* wb  = w + (size_t)bh * LL * DH;
    const unsigned short* ob  = isQ ? qb : wb;
    const size_t ost          = isQ ? (size_t)DD : (size_t)DH;
    const unsigned short* uTb = uT + (size_t)bh * DH * LL
                                + (size_t)(jcol + lr) * LL + half * 16 + lg * 4;
    const unsigned short* kTb = kT + (size_t)bh * DH * LL;
    const unsigned short* atb = attn + (size_t)bh * NC * (CH * CH)
                                + (size_t)(half * 16 + lr) * CH + lg * 8;
    float* db = dout + (size_t)bh * LL * DH;

    short8 po[2][8];     // this wave's A rows, K=256
    short8 pk[2][4];     // kT A-frags for S-update
    short8 pa[2];        // attn frag (waves 2,3)
    ushort4 pu[2];       // u elems (waves 0,1)

    {   // preload chunk 0 -> slot 0
        const unsigned short* orow = ob + (size_t)(half * 16 + lr) * ost;
#pragma unroll
        for (int kt = 0; kt < 8; ++kt)
            po[0][kt] = *(const short8*)(orow + kt * 32 + lg * 8);
#pragma unroll
        for (int mt = 0; mt < 4; ++mt)
            pk[0][mt] = *(const short8*)(kTb + (size_t)(64 * wave + 16 * mt + lr) * LL + lg * 8);
        if (!isQ) pu[0] = *(const ushort4*)(uTb);
        else      pa[0] = *(const short8*)(atb);
    }

#pragma unroll 2
    for (int ci = 0; ci < NC; ++ci) {
        const int p = ci & 1;
        const int l0 = ci * CH;

        // 1) pack wave's S e-slice -> SbT[p][col][e]
#pragma unroll
        for (int mt = 0; mt < 4; ++mt) {
            int e0 = 64 * wave + 16 * mt + lg * 4;
            *(unsigned int*)&SbT[p][lr][e0]     = pkbf(Sacc[mt][0], Sacc[mt][1]);
            *(unsigned int*)&SbT[p][lr][e0 + 2] = pkbf(Sacc[mt][2], Sacc[mt][3]);
        }

        // prefetch chunk ci+1 (clamped) into slot p^1
        {
            const int cn = (ci + 1 < NC) ? (ci + 1) : ci;
            const int ln = cn * CH;
            const unsigned short* orow = ob + (size_t)(ln + half * 16 + lr) * ost;
#pragma unroll
            for (int kt = 0; kt < 8; ++kt)
                po[p^1][kt] = *(const short8*)(orow + kt * 32 + lg * 8);
#pragma unroll
            for (int mt = 0; mt < 4; ++mt)
                pk[p^1][mt] = *(const short8*)(kTb + (size_t)(64 * wave + 16 * mt + lr) * LL + ln + lg * 8);
            if (!isQ) pu[p^1] = *(const ushort4*)(uTb + ln);
            else      pa[p^1] = *(const short8*)(atb + (size_t)cn * (CH * CH));
        }
        lds_barrier();   // (a) SbT[p] visible

        // 2) P = A @ S over full K=256 (two independent chains for ILP)
        floatx4 Pa = (floatx4){0.f,0.f,0.f,0.f}, Pb = Pa;
#pragma unroll
        for (int kt = 0; kt < 4; ++kt) {
            short8 s0 = *(const short8*)&SbT[p][lr][(2*kt)   * 32 + lg * 8];
            short8 s1 = *(const short8*)&SbT[p][lr][(2*kt+1) * 32 + lg * 8];
            Pa = __builtin_amdgcn_mfma_f32_16x16x32_bf16(po[p][2*kt],   s0, Pa, 0,0,0);
            Pb = __builtin_amdgcn_mfma_f32_16x16x32_bf16(po[p][2*kt+1], s1, Pb, 0,0,0);
        }
        floatx4 P = Pa + Pb;

        // 3) waves 0,1: uadj = u - w@S -> uadjT[p]
        if (!isQ) {
            ushort4 u4 = pu[p];
            float ua0 = bf2f(u4.x) - P[0];
            float ua1 = bf2f(u4.y) - P[1];
            float ua2 = bf2f(u4.z) - P[2];
            float ua3 = bf2f(u4.w) - P[3];
            int cc0 = half * 16 + lg * 4;
            *(unsigned int*)&uadjT[p][lr][cc0]     = pkbf(ua0, ua1);
            *(unsigned int*)&uadjT[p][lr][cc0 + 2] = pkbf(ua2, ua3);
        }
        lds_barrier();   // (b) uadjT[p] visible

        short8 ub = *(const short8*)&uadjT[p][lr][lg * 8];

        // 4) waves 2,3: O = q@S + attn@uadj -> dout
        if (isQ) {
            floatx4 Ot = __builtin_amdgcn_mfma_f32_16x16x32_bf16(pa[p], ub, P, 0,0,0);
#pragma unroll
            for (int r = 0; r < 4; ++r)
                db[(size_t)(l0 + half * 16 + lg * 4 + r) * DH + jcol + lr] = Ot[r];
        }

        // 5) S e-slice += kT @ uadj
#pragma unroll
        for (int mt = 0; mt < 4; ++mt)
            Sacc[mt] = __builtin_amdgcn_mfma_f32_16x16x32_bf16(pk[p][mt], ub, Sacc[mt], 0,0,0);
        // no trailing barrier: parity p untouched until ci+2, guarded by (a),(b) of ci+1
    }
}

// ------------------------------------------------- per-head stats
__global__ __launch_bounds__(256) void stats_k(
    const float* __restrict__ ls, const float* __restrict__ llb,
    const float* __restrict__ dox, const float* __restrict__ v,
    float* __restrict__ stats)
{
    int bl = blockIdx.x;
    int b = bl >> 12, l = bl & (LL - 1);
    int wv = threadIdx.x >> 6, ln = threadIdx.x & 63;
    size_t ibase = (size_t)bl * DD + wv * DH;
    size_t dbase = (((size_t)(b * HH + wv)) * LL + l) * DH;
#pragma unroll
    for (int tn = 0; tn < 4; ++tn) {
        const float* p; size_t base;
        if (tn == 0)      { p = ls;  base = ibase; }
        else if (tn == 1) { p = llb; base = ibase; }
        else if (tn == 2) { p = dox; base = dbase; }
        else              { p = v;   base = ibase; }
        float4 x = *(const float4*)(p + base + ln * 4);
        float sm = x.x + x.y + x.z + x.w;
        float sq = x.x*x.x + x.y*x.y + x.z*x.z + x.w*x.w;
        float sa = fabsf(x.x) + fabsf(x.y) + fabsf(x.z) + fabsf(x.w);
#pragma unroll
        for (int off = 32; off > 0; off >>= 1) {
            sm += __shfl_down(sm, off);
            sq += __shfl_down(sq, off);
            sa += __shfl_down(sa, off);
        }
        if (ln == 0) {
            float mean = sm * (1.0f / DH);
            float var = sq * (1.0f / DH) - mean * mean;
            float am = sa * (1.0f / DH);
            float l2 = sqrtf(sq);
            *(float4*)(stats + (size_t)bl * 64 + wv * 16 + tn * 4) =
                make_float4(mean, var, am, l2);
        }
    }
}

// ------------------------------------------------- gate finish v2
__global__ __launch_bounds__(256) void gate_fin2_k(
    const float* __restrict__ hpart, const float* __restrict__ stats,
    const unsigned short* __restrict__ w1s,
    const float* __restrict__ w2, const float* __restrict__ b2,
    const float* __restrict__ ltemp, float* __restrict__ fw)
{
    const int bl = blockIdx.x;
    const int t = threadIdx.x;
    const float temp = log1pf(expf(ltemp[0])) + 1e-4f;
    __shared__ float st[HH][16];
    __shared__ float red[4][16];
    __shared__ float fin[16];
    if (t < 64) st[t >> 4][t & 15] = stats[(size_t)bl * 64 + t];

    const int e0 = t * 4;
    float4 hp4 = *(const float4*)(hpart + (size_t)bl * DD + e0);
    float hp[4] = {hp4.x, hp4.y, hp4.z, hp4.w};
    float w2a[4][4];
#pragma unroll
    for (int j = 0; j < 4; ++j) {
        float4 wv = *(const float4*)(w2 + (size_t)j * 1024 + e0);
        w2a[j][0] = wv.x; w2a[j][1] = wv.y; w2a[j][2] = wv.z; w2a[j][3] = wv.w;
    }
    uint4 wpk[8];
    const uint4* wp = (const uint4*)(w1s + (size_t)e0 * 16);
#pragma unroll
    for (int i = 0; i < 8; ++i) wpk[i] = wp[i];
    __syncthreads();

    float lg[4][4];
#pragma unroll
    for (int h = 0; h < 4; ++h)
#pragma unroll
        for (int j = 0; j < 4; ++j) lg[h][j] = 0.0f;

#pragma unroll
    for (int ii = 0; ii < 4; ++ii) {
        float xh[4] = {hp[ii], hp[ii], hp[ii], hp[ii]};
        unsigned arr[8] = {wpk[ii*2].x, wpk[ii*2].y, wpk[ii*2].z, wpk[ii*2].w,
                           wpk[ii*2+1].x, wpk[ii*2+1].y, wpk[ii*2+1].z, wpk[ii*2+1].w};
#pragma unroll
        for (int p = 0; p < 8; ++p) {
            float wlo = bflo(arr[p]), whi = bfhi(arr[p]);
            int s = p * 2;
#pragma unroll
            for (int h = 0; h < 4; ++h)
                xh[h] += st[h][s] * wlo + st[h][s + 1] * whi;
        }
#pragma unroll
        for (int h = 0; h < 4; ++h) {
            float x = xh[h];
            float gct = 0.5f * x * (1.0f + erff(x * 0.70710678118654752f));
            lg[h][0] += gct * w2a[0][ii];
            lg[h][1] += gct * w2a[1][ii];
            lg[h][2] += gct * w2a[2][ii];
            lg[h][3] += gct * w2a[3][ii];
        }
    }

#pragma unroll
    for (int h = 0; h < 4; ++h)
#pragma unroll
        for (int j = 0; j < 4; ++j)
#pragma unroll
            for (int off = 32; off > 0; off >>= 1)
                lg[h][j] += __shfl_down(lg[h][j], off);

    const int wv = t >> 6, ln = t & 63;
    if (ln == 0) {
#pragma unroll
        for (int h = 0; h < 4; ++h)
#pragma unroll
            for (int j = 0; j < 4; ++j) red[wv][h * 4 + j] = lg[h][j];
    }
    __syncthreads();
    if (t < 16) {
        float s = red[0][t] + red[1][t] + red[2][t] + red[3][t] + b2[t & 3];
        fin[t] = s / temp;
    }
    __syncthreads();
    if (t < 4) {
        float l0 = fin[t*4], l1 = fin[t*4+1], l2 = fin[t*4+2], l3 = fin[t*4+3];
        float m = fmaxf(fmaxf(l0, l1), fmaxf(l2, l3));
        float e0x = expf(l0-m), e1 = expf(l1-m), e2 = expf(l2-m), e3 = expf(l3-m);
        float inv = 1.0f / (e0x + e1 + e2 + e3);
        *(float4*)(fw + (size_t)bl * 16 + t * 4) = make_float4(e0x*inv, e1*inv, e2*inv, e3*inv);
    }
}

// ------------------------------------------------- combine + rms norm
__global__ __launch_bounds__(256) void combine_k(
    const float* __restrict__ ls, const float* __restrict__ llb,
    const float* __restrict__ dox, const float* __restrict__ v,
    const float* __restrict__ fw, const float* __restrict__ rss,
    const float* __restrict__ rsl, const float* __restrict__ onw,
    float* __restrict__ opre)
{
    int h = blockIdx.x & (HH - 1);
    int bl = blockIdx.x >> 2;
    int b = bl >> 12, l = bl & (LL - 1);
    int d = threadIdx.x;
    size_t i1 = (size_t)blockIdx.x * DH + d;
    size_t i2 = (((size_t)(b * HH + h)) * LL + l) * DH + d;
    const float* fwp = fw + (size_t)blockIdx.x * 4;
    float f0 = fwp[0], f1 = fwp[1], f2 = fwp[2], f3 = fwp[3];
    float aS = rss[0], aL = rsl[0];
    float vls = ls[i1], vll = llb[i1], vd = dox[i2], vv = v[i1];
    float o = f0*vls + f1*vll + f2*vd + f3*vv + aS*vls + aL*vll;
    float s = o * o;
#pragma unroll
    for (int off = 32; off > 0; off >>= 1) s += __shfl_down(s, off);
    __shared__ float red[4];
    int wv = threadIdx.x >> 6, ln = threadIdx.x & 63;
    if (ln == 0) red[wv] = s;
    __syncthreads();
    float ms = (red[0] + red[1] + red[2] + red[3]) * (1.0f / DH);
    opre[(size_t)bl * DD + h * DH + d] = o * rsqrtf(ms + 1e-5f) * onw[d];
}

// ================================================================ launch
extern "C" void kernel_launch(void* const* d_in, const int* in_sizes, int n_in,
                              void* d_out, int out_size, void* d_ws, size_t ws_size,
                              hipStream_t stream)
{
    const float* hs  = (const float*)d_in[0];
    const float* qw  = (const float*)d_in[1];
    const float* kw  = (const float*)d_in[2];
    const float* vw  = (const float*)d_in[3];
    const float* bw  = (const float*)d_in[4];
    const float* qcw = (const float*)d_in[5];
    const float* kcw = (const float*)d_in[6];
    const float* vcw = (const float*)d_in[7];
    const float* fsw = (const float*)d_in[8];
    const float* flw = (const float*)d_in[9];
    const float* w1  = (const float*)d_in[10];
    const float* b1  = (const float*)d_in[11];
    const float* w2  = (const float*)d_in[12];
    const float* b2  = (const float*)d_in[13];
    const float* lt  = (const float*)d_in[14];
    const float* rss = (const float*)d_in[15];
    const float* rsl = (const float*)d_in[16];
    const float* onw = (const float*)d_in[17];
    const float* opw = (const float*)d_in[18];
    float* out = (float*)d_out;

    float* wsf = (float*)d_ws;
    float* tmp   = wsf;
    unsigned short* ktbuf = (unsigned short*)tmp;
    unsigned short* uTbuf = (unsigned short*)(wsf + BLD/2);
    float* vbuf  = wsf + BLD;
    float* dbuf  = wsf + 2*BLD;
    // hsb shares the dbuf region -> DEAD once scan9 writes dbuf. Only used in phase 1.
    unsigned short* hsb = (unsigned short*)(wsf + 2*BLD);
    // bf16 QKV weights live in the dead second half of the dbuf region during phase 1
    unsigned short* qwb = (unsigned short*)(wsf + 2*BLD + BLD/2);
    unsigned short* kwb = qwb + (size_t)DD*DD;
    unsigned short* vwb = kwb + (size_t)DD*DD;
    unsigned short* qbuf = (unsigned short*)(wsf + 3*BLD);
    unsigned short* kbuf = qbuf + BLD;
    float* hpart = wsf + 3*BLD;
    float* opre  = wsf + 3*BLD;
    unsigned short* ubuf = (unsigned short*)(wsf + 4*BLD);
    unsigned short* wbuf = ubuf + BLD;
    float* llbuf = wsf + 4*BLD;
    float* lsbuf = tmp;
    unsigned short* attnb = (unsigned short*)(wsf + 5*BLD);
    float* statsb = wsf + 5*BLD + 524288;
    float* fwbuf  = statsb + (size_t)BL*HH*16;
    float* betab  = fwbuf + (size_t)BL*HH*4;
    unsigned short* w1sp = (unsigned short*)(betab + (size_t)BL*HH);

    dim3 gg(8, 64);   // N/128, M/128

    cvt_bf_k<<<(int)(BLD/1024), 256, 0, stream>>>(hs, hsb);
    cvt_bf_k<<<1024, 256, 0, stream>>>(qw, qwb);
    cvt_bf_k<<<1024, 256, 0, stream>>>(kw, kwb);
    cvt_bf_k<<<1024, 256, 0, stream>>>(vw, vwb);
    w1s_prep_k<<<64, 256, 0, stream>>>(w1, w1sp);

    gemm_bb<<<gg, 256, 0, stream>>>(hsb, DD, qwb, DD, tmp, DD, DD);
    convnorm_qk_k<<<BL*HH, 256, 0, stream>>>(tmp, qcw, qbuf);
    gemm_bb<<<gg, 256, 0, stream>>>(hsb, DD, kwb, DD, tmp, DD, DD);
    convnorm_qk_k<<<BL*HH, 256, 0, stream>>>(tmp, kcw, kbuf);
    gemm_bb<<<gg, 256, 0, stream>>>(hsb, DD, vwb, DD, tmp, DD, DD);
    conv_silu_k<<<(int)(BLD/256), 256, 0, stream>>>(tmp, vcw, vbuf);

    beta_k<<<BL, 256, 0, stream>>>(hs, bw, betab);

    tr_k<<<8*64*4, 256, 0, stream>>>(kbuf, ktbuf);
    chunk_prep_k<<<BB*HH*NC, 256, 0, stream>>>(qbuf, kbuf, vbuf, betab, ubuf, wbuf, attnb);
    tru_k<<<8*64*4, 256, 0, stream>>>(ubuf, uTbuf);

    scan9_k<<<BB*HH*16, 256, 0, stream>>>(qbuf, ktbuf, uTbuf, wbuf, attnb, dbuf);

    fir2_k<5><<<BB*64*16, 256, 0, stream>>>(vbuf, fsw, lsbuf);
    fir2_k<64><<<BB*64*16, 256, 0, stream>>>(vbuf, flw, llbuf);

    stats_k<<<BL, 256, 0, stream>>>(lsbuf, llbuf, dbuf, vbuf, statsb);

    // hpart GEMM reads the pristine f32 input hs (hsb is dead: overwritten by dbuf)
    gemm_mfma<<<gg, 256, 0, stream>>>(hs, DD, w1, 1040, b1, hpart, DD, DD);
    gate_fin2_k<<<BL, 256, 0, stream>>>(hpart, statsb, w1sp, w2, b2, lt, fwbuf);

    combine_k<<<BL*HH, 256, 0, stream>>>(lsbuf, llbuf, dbuf, vbuf, fwbuf, rss, rsl, onw, opre);

    gemm_mfma<<<gg, 256, 0, stream>>>(opre, DD, opw, DD, nullptr, out, DD, DD);
}

// Round 4
// 990.496 us; speedup vs baseline: 1.4258x; 1.0136x over previous
//
#include <hip/hip_runtime.h>
#include <hip/hip_bf16.h>

#define BB 2
#define LL 4096
#define DD 1024
#define HH 4
#define DH 256
#define CH 32
#define NC (LL/CH)     // 128
#define BL (BB*LL)     // 8192
#define BLD ((size_t)BB*LL*DD) // 8388608

typedef __attribute__((ext_vector_type(8))) short short8;
typedef __attribute__((ext_vector_type(4))) float floatx4;

__device__ __forceinline__ float bf2f(unsigned short u) {
    union { float f; unsigned int i; } x; x.i = ((unsigned int)u) << 16; return x.f;
}
__device__ __forceinline__ float bflo(unsigned int u) {
    union { float f; unsigned int i; } x; x.i = u << 16; return x.f;
}
__device__ __forceinline__ float bfhi(unsigned int u) {
    union { float f; unsigned int i; } x; x.i = u & 0xFFFF0000u; return x.f;
}
__device__ __forceinline__ unsigned short f2bf(float f) {
    union { float f; unsigned int i; } x; x.f = f;
    unsigned int r = x.i + 0x7FFFu + ((x.i >> 16) & 1u);
    return (unsigned short)(r >> 16);
}
// pack two f32 -> (bf16(b)<<16)|bf16(a), round-half-up
__device__ __forceinline__ unsigned int pkbf(float a, float b) {
    unsigned int ua = __float_as_uint(a) + 0x8000u;
    unsigned int ub = __float_as_uint(b) + 0x8000u;
    return __builtin_amdgcn_perm(ub, ua, 0x07060302);
}
// barrier with LDS-only drain (no vmcnt drain -> prefetch loads stay in flight)
__device__ __forceinline__ void lds_barrier() {
    __builtin_amdgcn_s_waitcnt(0xC07F);
    __builtin_amdgcn_s_barrier();
}

typedef __attribute__((address_space(1))) const unsigned int as1_uint;
typedef __attribute__((address_space(3))) unsigned int as3_uint;
// async 1KB DMA: 64 lanes x 16B from per-lane global src to wave-uniform LDS base
__device__ __forceinline__ void dma16(const void* g, void* l) {
    __builtin_amdgcn_global_load_lds((as1_uint*)g, (as3_uint*)l, 16, 0, 0);
}

// ---------------------------------------------------------------- f32 -> bf16 bulk convert
__global__ __launch_bounds__(256) void cvt_bf_k(
    const float* __restrict__ x, unsigned short* __restrict__ y)
{
    size_t i = ((size_t)blockIdx.x * 256 + threadIdx.x) * 4;
    float4 v = *(const float4*)(x + i);
    ushort4 o;
    o.x = f2bf(v.x); o.y = f2bf(v.y); o.z = f2bf(v.z); o.w = f2bf(v.w);
    *(ushort4*)(y + i) = o;
}

// ---------------------------------------------------------------- pack w1[:,1024:1040] -> bf16 [1024][16]
__global__ __launch_bounds__(256) void w1s_prep_k(
    const float* __restrict__ w1, unsigned short* __restrict__ w1s)
{
    int idx = blockIdx.x * 256 + threadIdx.x;   // 16384
    int e = idx >> 4, s = idx & 15;
    w1s[idx] = f2bf(w1[(size_t)e * 1040 + 1024 + s]);
}

// ---------------------------------------------------------------- bf16 MFMA GEMM (NT), f32 A, f32 W
__global__ __launch_bounds__(256) void gemm_mfma(
    const float* __restrict__ A, int lda,
    const float* __restrict__ W, int ldw,
    const float* __restrict__ bias,
    float* __restrict__ C, int ldc, int K)
{
    __shared__ unsigned short Abuf[128][56];
    __shared__ unsigned short Bbuf[128][56];
    const int t = threadIdx.x;
    const int wave = t >> 6, lane = t & 63;
    const int wm = wave >> 1, wn = wave & 1;
    const int row0 = blockIdx.y * 128, col0 = blockIdx.x * 128;

    floatx4 acc[4][4];
#pragma unroll
    for (int i = 0; i < 4; ++i)
#pragma unroll
        for (int j = 0; j < 4; ++j) acc[i][j] = (floatx4){0.f, 0.f, 0.f, 0.f};

    const int fr = lane & 15, fk = (lane >> 4) * 8;

    for (int kt = 0; kt < K; kt += 32) {
        __syncthreads();
#pragma unroll
        for (int it = 0; it < 2; ++it) {
            int idx = t + it * 256;
            int r = idx >> 2, s = (idx & 3) * 8;
            const float* ap = A + (size_t)(row0 + r) * lda + kt + s;
            float4 a0 = *(const float4*)(ap);
            float4 a1 = *(const float4*)(ap + 4);
            ushort4 p0, p1;
            p0.x = f2bf(a0.x); p0.y = f2bf(a0.y); p0.z = f2bf(a0.z); p0.w = f2bf(a0.w);
            p1.x = f2bf(a1.x); p1.y = f2bf(a1.y); p1.z = f2bf(a1.z); p1.w = f2bf(a1.w);
            *(ushort4*)&Abuf[r][s]     = p0;
            *(ushort4*)&Abuf[r][s + 4] = p1;
            const float* wp = W + (size_t)(col0 + r) * ldw + kt + s;
            float4 b0 = *(const float4*)(wp);
            float4 b1 = *(const float4*)(wp + 4);
            ushort4 q0, q1;
            q0.x = f2bf(b0.x); q0.y = f2bf(b0.y); q0.z = f2bf(b0.z); q0.w = f2bf(b0.w);
            q1.x = f2bf(b1.x); q1.y = f2bf(b1.y); q1.z = f2bf(b1.z); q1.w = f2bf(b1.w);
            *(ushort4*)&Bbuf[r][s]     = q0;
            *(ushort4*)&Bbuf[r][s + 4] = q1;
        }
        __syncthreads();

        short8 afrag[4], bfrag[4];
#pragma unroll
        for (int i = 0; i < 4; ++i) {
            afrag[i] = *(const short8*)&Abuf[wm * 64 + i * 16 + fr][fk];
            bfrag[i] = *(const short8*)&Bbuf[wn * 64 + i * 16 + fr][fk];
        }
#pragma unroll
        for (int i = 0; i < 4; ++i)
#pragma unroll
            for (int j = 0; j < 4; ++j)
                acc[i][j] = __builtin_amdgcn_mfma_f32_16x16x32_bf16(
                    afrag[i], bfrag[j], acc[i][j], 0, 0, 0);
    }

    const int fc = lane & 15, frow = (lane >> 4) * 4;
#pragma unroll
    for (int j = 0; j < 4; ++j) {
        int col = col0 + wn * 64 + j * 16 + fc;
        float bv = bias ? bias[col] : 0.0f;
#pragma unroll
        for (int i = 0; i < 4; ++i) {
#pragma unroll
            for (int r = 0; r < 4; ++r) {
                int row = row0 + wm * 64 + i * 16 + frow + r;
                C[(size_t)row * ldc + col] = acc[i][j][r] + bv;
            }
        }
    }
}

// ---------------------------------------------------------------- bf16 MFMA GEMM (NT), bf16 A, bf16 B
__global__ __launch_bounds__(256) void gemm_bb(
    const unsigned short* __restrict__ A, int lda,
    const unsigned short* __restrict__ B, int ldb,
    float* __restrict__ C, int ldc, int K)
{
    __shared__ unsigned short Abuf[128][56];
    __shared__ unsigned short Bbuf[128][56];
    const int t = threadIdx.x;
    const int wave = t >> 6, lane = t & 63;
    const int wm = wave >> 1, wn = wave & 1;
    const int row0 = blockIdx.y * 128, col0 = blockIdx.x * 128;

    floatx4 acc[4][4];
#pragma unroll
    for (int i = 0; i < 4; ++i)
#pragma unroll
        for (int j = 0; j < 4; ++j) acc[i][j] = (floatx4){0.f, 0.f, 0.f, 0.f};

    const int fr = lane & 15, fk = (lane >> 4) * 8;

    for (int kt = 0; kt < K; kt += 32) {
        __syncthreads();
#pragma unroll
        for (int it = 0; it < 2; ++it) {
            int idx = t + it * 256;
            int r = idx >> 2, s = (idx & 3) * 8;
            uint4 av = *(const uint4*)(A + (size_t)(row0 + r) * lda + kt + s);
            *(uint4*)&Abuf[r][s] = av;
            uint4 bv = *(const uint4*)(B + (size_t)(col0 + r) * ldb + kt + s);
            *(uint4*)&Bbuf[r][s] = bv;
        }
        __syncthreads();

        short8 afrag[4], bfrag[4];
#pragma unroll
        for (int i = 0; i < 4; ++i) {
            afrag[i] = *(const short8*)&Abuf[wm * 64 + i * 16 + fr][fk];
            bfrag[i] = *(const short8*)&Bbuf[wn * 64 + i * 16 + fr][fk];
        }
#pragma unroll
        for (int i = 0; i < 4; ++i)
#pragma unroll
            for (int j = 0; j < 4; ++j)
                acc[i][j] = __builtin_amdgcn_mfma_f32_16x16x32_bf16(
                    afrag[i], bfrag[j], acc[i][j], 0, 0, 0);
    }

    const int fc = lane & 15, frow = (lane >> 4) * 4;
#pragma unroll
    for (int j = 0; j < 4; ++j) {
        int col = col0 + wn * 64 + j * 16 + fc;
#pragma unroll
        for (int i = 0; i < 4; ++i) {
#pragma unroll
            for (int r = 0; r < 4; ++r) {
                int row = row0 + wm * 64 + i * 16 + frow + r;
                C[(size_t)row * ldc + col] = acc[i][j][r];
            }
        }
    }
}

// --------------------------------------- causal dwconv K=4 + silu + head-l2norm -> bf16
__global__ __launch_bounds__(256) void convnorm_qk_k(
    const float* __restrict__ x, const float* __restrict__ w,
    unsigned short* __restrict__ y)
{
    int bl = blockIdx.x >> 2;
    int h  = blockIdx.x & 3;
    int l  = bl & (LL - 1);
    int d  = threadIdx.x;
    int c  = h * DH + d;
    const float* wp = w + (size_t)c * 4;
    const float* xp = x + (size_t)bl * DD + c;
    float acc = wp[3] * xp[0];
    if (l >= 1) acc += wp[2] * xp[-(int)DD];
    if (l >= 2) acc += wp[1] * xp[-2*(int)DD];
    if (l >= 3) acc += wp[0] * xp[-3*(int)DD];
    acc = acc / (1.0f + expf(-acc));
    float s = acc * acc;
#pragma unroll
    for (int off = 32; off > 0; off >>= 1) s += __shfl_down(s, off);
    __shared__ float red[4];
    int wv = threadIdx.x >> 6, ln = threadIdx.x & 63;
    if (ln == 0) red[wv] = s;
    __syncthreads();
    float tot = red[0] + red[1] + red[2] + red[3];
    y[(size_t)bl * DD + c] = f2bf(acc * rsqrtf(tot));
}

// ------------------------------------------------- causal depthwise conv K=4 + silu (f32)
__global__ __launch_bounds__(256) void conv_silu_k(
    const float* __restrict__ x, const float* __restrict__ w, float* __restrict__ y)
{
    size_t idx = (size_t)blockIdx.x * 256 + threadIdx.x;
    int c = (int)(idx & (DD - 1));
    int bl = (int)(idx >> 10);
    int l = bl & (LL - 1);
    const float* wp = w + (size_t)c * 4;
    const float* xp = x + (size_t)bl * DD + c;
    float acc = wp[3] * xp[0];
    if (l >= 1) acc += wp[2] * xp[-(int)DD];
    if (l >= 2) acc += wp[1] * xp[-2*(int)DD];
    if (l >= 3) acc += wp[0] * xp[-3*(int)DD];
    y[idx] = acc / (1.0f + expf(-acc));
}

// ------------------------------------------------- FIR causal depthwise conv, LDS-tiled
template<int K>
__global__ __launch_bounds__(256) void fir2_k(
    const float* __restrict__ x, const float* __restrict__ filt, float* __restrict__ y)
{
    const int ctile = blockIdx.x & 15;
    const int ltile = (blockIdx.x >> 4) & 63;
    const int b = blockIdx.x >> 10;
    const int RT = 64 + K - 1;
    __shared__ float xs[RT][64];
    __shared__ float fs[64][K + 1];
    const int t = threadIdx.x;
    const int l0 = ltile * 64;

    for (int i = t; i < RT * 16; i += 256) {
        int li = i >> 4, c4 = (i & 15) * 4;
        int l = l0 - (K - 1) + li;
        float4 v = make_float4(0.f, 0.f, 0.f, 0.f);
        if (l >= 0)
            v = *(const float4*)(x + ((size_t)b * LL + l) * DD + ctile * 64 + c4);
        *(float4*)&xs[li][c4] = v;
    }
    for (int i = t; i < 64 * K; i += 256) {
        fs[i / K][i % K] = filt[(size_t)ctile * 64 * K + i];
    }
    __syncthreads();

    const int c = t & 63, lg = t >> 6;
    float acc[16];
#pragma unroll
    for (int o = 0; o < 16; ++o) acc[o] = 0.f;
#pragma unroll
    for (int j = 0; j < 16 + K - 1; ++j) {
        float xv = xs[lg * 16 + j][c];
#pragma unroll
        for (int o = 0; o < 16; ++o) {
            int tap = j - o;
            if (tap >= 0 && tap < K) acc[o] += fs[c][tap] * xv;
        }
    }
    size_t base = ((size_t)b * LL + l0 + lg * 16) * DD + ctile * 64 + c;
#pragma unroll
    for (int o = 0; o < 16; ++o)
        y[base + (size_t)o * DD] = acc[o];
}

// ------------------------------------------------- beta = sigmoid(hs @ b_proj^T)
__global__ __launch_bounds__(256) void beta_k(
    const float* __restrict__ hs, const float* __restrict__ bw, float* __restrict__ beta)
{
    int bl = blockIdx.x;
    const float* xr = hs + (size_t)bl * DD;
    float a0=0.f,a1=0.f,a2=0.f,a3=0.f;
    for (int k = threadIdx.x; k < DD; k += 256) {
        float xv = xr[k];
        a0 += xv * bw[k];
        a1 += xv * bw[DD + k];
        a2 += xv * bw[2*DD + k];
        a3 += xv * bw[3*DD + k];
    }
#pragma unroll
    for (int off = 32; off > 0; off >>= 1) {
        a0 += __shfl_down(a0, off); a1 += __shfl_down(a1, off);
        a2 += __shfl_down(a2, off); a3 += __shfl_down(a3, off);
    }
    __shared__ float red[4][4];
    int wv = threadIdx.x >> 6, ln = threadIdx.x & 63;
    if (ln == 0) { red[wv][0]=a0; red[wv][1]=a1; red[wv][2]=a2; red[wv][3]=a3; }
    __syncthreads();
    if (threadIdx.x < 4) {
        int h = threadIdx.x;
        float s = red[0][h] + red[1][h] + red[2][h] + red[3][h];
        beta[(size_t)bl * HH + h] = 1.0f / (1.0f + expf(-s));
    }
}

// ------------------------------------------------- k transpose: k[b,l,h*DH+e] -> kT[bh,e,l]
__global__ __launch_bounds__(256) void tr_k(
    const unsigned short* __restrict__ k, unsigned short* __restrict__ kT)
{
    int et = blockIdx.x & 3;
    int lt = (blockIdx.x >> 2) & 63;
    int bh = blockIdx.x >> 8;
    int h = bh & 3, b = bh >> 2;
    __shared__ unsigned short tile[64][72];
    int t = threadIdx.x;
    int tr = t >> 4;
    int tc = (t & 15) * 4;
#pragma unroll
    for (int i = 0; i < 4; ++i) {
        int l = tr + i * 16;
        ushort4 v = *(const ushort4*)(k + ((size_t)b * LL + lt*64 + l) * DD + h * DH + et*64 + tc);
        *(ushort4*)&tile[l][tc] = v;
    }
    __syncthreads();
#pragma unroll
    for (int i = 0; i < 4; ++i) {
        int e = tr + i * 16;
        ushort4 v;
        v.x = tile[tc+0][e]; v.y = tile[tc+1][e];
        v.z = tile[tc+2][e]; v.w = tile[tc+3][e];
        *(ushort4*)(kT + ((size_t)bh * DH + et*64 + e) * LL + (size_t)lt*64 + tc) = v;
    }
}

// ------------------------------------------------- u transpose: u[bh,l,d] -> uT[bh,d,l]
__global__ __launch_bounds__(256) void tru_k(
    const unsigned short* __restrict__ u, unsigned short* __restrict__ uT)
{
    int et = blockIdx.x & 3;
    int lt = (blockIdx.x >> 2) & 63;
    int bh = blockIdx.x >> 8;
    __shared__ unsigned short tile[64][72];
    int t = threadIdx.x;
    int tr = t >> 4;
    int tc = (t & 15) * 4;
#pragma unroll
    for (int i = 0; i < 4; ++i) {
        int l = tr + i * 16;
        ushort4 v = *(const ushort4*)(u + ((size_t)bh * LL + lt*64 + l) * DH + et*64 + tc);
        *(ushort4*)&tile[l][tc] = v;
    }
    __syncthreads();
#pragma unroll
    for (int i = 0; i < 4; ++i) {
        int e = tr + i * 16;
        ushort4 v;
        v.x = tile[tc+0][e]; v.y = tile[tc+1][e];
        v.z = tile[tc+2][e]; v.w = tile[tc+3][e];
        *(ushort4*)(uT + ((size_t)bh * DH + et*64 + e) * LL + (size_t)lt*64 + tc) = v;
    }
}

// ------------------------------------------------- per-chunk prep (attn out bf16)
__global__ __launch_bounds__(256) void chunk_prep_k(
    const unsigned short* __restrict__ q, const unsigned short* __restrict__ k,
    const float* __restrict__ v, const float* __restrict__ beta,
    unsigned short* __restrict__ u_out, unsigned short* __restrict__ w_out,
    unsigned short* __restrict__ attn_out)
{
    int ci = blockIdx.x & (NC - 1);
    int bh = blockIdx.x >> 7;
    int h = bh & (HH - 1), b = bh >> 2;
    __shared__ float kt[CH][DH + 4];
    __shared__ float Am[CH][CH + 1];
    __shared__ float Ab[CH][CH + 1];
    __shared__ float bet[CH];
    int t = threadIdx.x;
    size_t qgbase = (size_t)b * LL + (size_t)ci * CH;

    for (int i = t; i < CH * (DH / 4); i += 256) {
        int r = i >> 6;
        int c4 = (i & 63) * 4;
        ushort4 kv = *(const ushort4*)(k + (qgbase + r) * DD + h * DH + c4);
        kt[r][c4+0] = bf2f(kv.x); kt[r][c4+1] = bf2f(kv.y);
        kt[r][c4+2] = bf2f(kv.z); kt[r][c4+3] = bf2f(kv.w);
    }
    if (t < CH) bet[t] = beta[(qgbase + t) * HH + h];
    __syncthreads();

    int c = t >> 3, e0 = (t & 7) * 4;
    {
        float accA[4] = {0,0,0,0}, accT[4] = {0,0,0,0};
        const unsigned short* qrow = q + (qgbase + c) * DD + h * DH;
        for (int d0 = 0; d0 < DH; d0 += 4) {
            float4 kc = *(const float4*)&kt[c][d0];
            ushort4 qv = *(const ushort4*)(qrow + d0);
            float qx = bf2f(qv.x), qy = bf2f(qv.y), qz = bf2f(qv.z), qw = bf2f(qv.w);
#pragma unroll
            for (int e = 0; e < 4; ++e) {
                float4 ke = *(const float4*)&kt[e0 + e][d0];
                accA[e] += kc.x*ke.x + kc.y*ke.y + kc.z*ke.z + kc.w*ke.w;
                accT[e] += qx*ke.x + qy*ke.y + qz*ke.z + qw*ke.w;
            }
        }
        float bc = bet[c];
        size_t abase = (size_t)blockIdx.x * (CH * CH) + (size_t)c * CH;
#pragma unroll
        for (int e = 0; e < 4; ++e) {
            int ee = e0 + e;
            Am[c][ee] = (ee < c) ? (-bc * accA[e]) : 0.0f;
            attn_out[abase + ee] = (ee <= c) ? f2bf(accT[e]) : (unsigned short)0;
        }
    }
    __syncthreads();

    for (int i = 1; i < CH; ++i) {
        float upd = 0.0f;
        if (t < i) {
#pragma unroll
            for (int kk = 0; kk < CH; ++kk) upd += Am[i][kk] * Am[kk][t];
        }
        __syncthreads();
        if (t < i) Am[i][t] += upd;
        __syncthreads();
    }

    for (int i = t; i < CH * CH; i += 256) {
        int cc = i >> 5, ee = i & 31;
        float val = Am[cc][ee] + (cc == ee ? 1.0f : 0.0f);
        Ab[cc][ee] = val * bet[ee];
    }
    __syncthreads();

    int c2 = t >> 3, dd0 = (t & 7) * 32;
    float accu[32];
#pragma unroll
    for (int j = 0; j < 32; ++j) accu[j] = 0.0f;
    for (int e = 0; e < CH; ++e) {
        float ab = Ab[c2][e];
        const float* vrow = v + (qgbase + e) * DD + h * DH + dd0;
#pragma unroll
        for (int j4 = 0; j4 < 8; ++j4) {
            float4 v4 = *(const float4*)(vrow + j4 * 4);
            accu[j4*4+0] += ab * v4.x; accu[j4*4+1] += ab * v4.y;
            accu[j4*4+2] += ab * v4.z; accu[j4*4+3] += ab * v4.w;
        }
    }
    size_t obase = ((size_t)bh * LL + (size_t)ci * CH + c2) * DH + dd0;
#pragma unroll
    for (int j4 = 0; j4 < 8; ++j4) {
        ushort4 o;
        o.x = f2bf(accu[j4*4+0]); o.y = f2bf(accu[j4*4+1]);
        o.z = f2bf(accu[j4*4+2]); o.w = f2bf(accu[j4*4+3]);
        *(ushort4*)(u_out + obase + j4*4) = o;
    }

#pragma unroll
    for (int j = 0; j < 32; ++j) accu[j] = 0.0f;
    for (int e = 0; e < CH; ++e) {
        float ab = Ab[c2][e];
#pragma unroll
        for (int j4 = 0; j4 < 8; ++j4) {
            float4 v4 = *(const float4*)&kt[e][dd0 + j4*4];
            accu[j4*4+0] += ab * v4.x; accu[j4*4+1] += ab * v4.y;
            accu[j4*4+2] += ab * v4.z; accu[j4*4+3] += ab * v4.w;
        }
    }
#pragma unroll
    for (int j4 = 0; j4 < 8; ++j4) {
        ushort4 o;
        o.x = f2bf(accu[j4*4+0]); o.y = f2bf(accu[j4*4+1]);
        o.z = f2bf(accu[j4*4+2]); o.w = f2bf(accu[j4*4+3]);
        *(ushort4*)(w_out + obase + j4*4) = o;
    }
}

// ------------------------------------------------- chunk scan v10: scan6 wave roles +
// LDS-staged operands via async global_load_lds (double-buffered slot, 51KB each).
// The DMA for chunk ci+1 is issued right after barrier (a) of chunk ci -> a full chunk
// in flight in the HW vmcnt queue; the compiler cannot sink it (unlike register
// prefetch, which r1-r3 proved gets sunk to just-before-use at any launch_bounds).
// One s_waitcnt vmcnt(0) at chunk top (before barrier a) publishes the slot.
// Bank-conflict fix: 16B-granule XOR swizzle applied on the GLOBAL source address
// (LDS dest stays linear, required by global_load_lds); reads apply the same XOR.
__global__ __launch_bounds__(256, 1) void scan10_k(
    const unsigned short* __restrict__ q, const unsigned short* __restrict__ kT,
    const unsigned short* __restrict__ uT, const unsigned short* __restrict__ w,
    const unsigned short* __restrict__ attn, float* __restrict__ dout)
{
    const int bh = blockIdx.x & 7;     // low bits -> 16 same-bh blocks share one XCD
    const int jb = blockIdx.x >> 3;
    const int h = bh & (HH - 1), b = bh >> 2;
    const int jcol = jb * 16;
    const int wave = threadIdx.x >> 6, lane = threadIdx.x & 63;
    const int lr = lane & 15, lg = lane >> 4;
    const int half = wave & 1;
    const bool isQ = wave >= 2;

    // staged slot: W 16K | Q 16K | K 16K | A 2K | U 1K  = 52224 B
    #define OW 0
    #define OQ 16384
    #define OK2 32768
    #define OA 49152
    #define OU 51200
    __shared__ char slotmem[2][52224];
    __shared__ unsigned short SbT[2][16][264];   // [par][col][e] bf16
    __shared__ unsigned short uadjT[2][16][40];  // [par][col][cc] bf16

    floatx4 Sacc[4];
#pragma unroll
    for (int mt = 0; mt < 4; ++mt) Sacc[mt] = (floatx4){0.f,0.f,0.f,0.f};

    const char* wbB  = (const char*)(w  + (size_t)bh * LL * DH);
    const char* qbB  = (const char*)(q  + (size_t)b * LL * DD + h * DH);
    const char* kbB  = (const char*)(kT + (size_t)bh * DH * LL);
    const char* uTbB = (const char*)(uT + (size_t)bh * DH * LL);
    const char* atB  = (const char*)(attn + (size_t)bh * NC * (CH * CH));
    float* db = dout + (size_t)bh * LL * DH;

    // ---- per-lane DMA source byte offsets (loop-invariant; add l0-scaled base per chunk)
    const int lane16 = lane * 16;
    int pw[4], pq[4], pkt[4];
#pragma unroll
    for (int j = 0; j < 4; ++j) {
        int i = wave + 4 * j;
        int L = i * 1024 + lane16;
        { int row = L >> 9, g = (L >> 4) & 31, gs = g ^ (row & 7);
          pw[j] = row * 512 + gs * 16; }          // W rows: 512B stride (DH bf16)
        { int row = L >> 9, g = (L >> 4) & 31, gs = g ^ (row & 7);
          pq[j] = row * 2048 + gs * 16; }         // Q rows: 2048B stride (DD bf16)
        { int row = L >> 6, g = (L >> 4) & 3, gs = g ^ (row & 3);
          pkt[j] = row * 8192 + gs * 16; }        // kT rows: 8192B stride (LL bf16)
    }
    int pat = 0, put = 0;
    if (wave < 2) { int L = wave * 1024 + lane16;
        int row = L >> 6, g = (L >> 4) & 3, gs = g ^ (row & 3);
        pat = row * 64 + gs * 16; }               // attn rows: 64B stride
    else if (wave == 2) { int L = lane16;
        int row = L >> 6, g = (L >> 4) & 3;
        put = (jcol + row) * 8192 + g * 16; }     // uT rows: 8192B stride, linear

    // ---- per-lane LDS read byte offsets (swizzled to match DMA source permutation)
    const int row_o = half * 16 + lr;
    int opo[8];
#pragma unroll
    for (int kt = 0; kt < 8; ++kt)
        opo[kt] = row_o * 512 + (((kt * 4 + lg) ^ (row_o & 7)) * 16);
    int opk[4];
#pragma unroll
    for (int mt = 0; mt < 4; ++mt) {
        int rk = 64 * wave + 16 * mt + lr;
        opk[mt] = rk * 64 + ((lg ^ (rk & 3)) * 16);
    }
    const int opa = row_o * 64 + ((lg ^ (row_o & 3)) * 16);
    const int opu = lr * 64 + half * 32 + lg * 8;

    // ---- prologue: stage chunk 0 -> slot 0
    {
        char* sb = &slotmem[0][0];
#pragma unroll
        for (int j = 0; j < 4; ++j) {
            int i = wave + 4 * j;
            dma16(wbB + pw[j],  sb + OW  + i * 1024);
            dma16(qbB + pq[j],  sb + OQ  + i * 1024);
            dma16(kbB + pkt[j], sb + OK2 + i * 1024);
        }
        if (wave < 2)       dma16(atB + pat,  sb + OA + wave * 1024);
        else if (wave == 2) dma16(uTbB + put, sb + OU);
    }

#pragma unroll 2
    for (int ci = 0; ci < NC; ++ci) {
        const int p = ci & 1;
        const int l0 = ci * CH;

        // 1) pack wave's S e-slice -> SbT[p][col][e]
#pragma unroll
        for (int mt = 0; mt < 4; ++mt) {
            int e0 = 64 * wave + 16 * mt + lg * 4;
            *(unsigned int*)&SbT[p][lr][e0]     = pkbf(Sacc[mt][0], Sacc[mt][1]);
            *(unsigned int*)&SbT[p][lr][e0 + 2] = pkbf(Sacc[mt][2], Sacc[mt][3]);
        }

        // 2) drain this chunk's staged DMAs, publish LDS (slot p + SbT[p])
        asm volatile("s_waitcnt vmcnt(0)" ::: "memory");
        lds_barrier();   // (a)

        // 3) issue async stage of chunk ci+1 -> slot p^1 (safe: all p^1 readers drained at (a))
        {
            const int cn = (ci + 1 < NC) ? (ci + 1) : ci;
            const size_t lnW = (size_t)(cn * CH) * 512;
            const size_t lnQ = (size_t)(cn * CH) * 2048;
            const size_t lnK = (size_t)(cn * CH) * 2;
            char* sb = &slotmem[p ^ 1][0];
#pragma unroll
            for (int j = 0; j < 4; ++j) {
                int i = wave + 4 * j;
                dma16(wbB + lnW + pw[j],  sb + OW  + i * 1024);
                dma16(qbB + lnQ + pq[j],  sb + OQ  + i * 1024);
                dma16(kbB + lnK + pkt[j], sb + OK2 + i * 1024);
            }
            if (wave < 2)       dma16(atB + (size_t)cn * 2048 + pat, sb + OA + wave * 1024);
            else if (wave == 2) dma16(uTbB + lnK + put, sb + OU);
        }

        const char* sp = &slotmem[p][0];
        const char* ab = sp + (isQ ? OQ : OW);

        // 4) P = A @ S over full K=256 (two independent chains for ILP)
        floatx4 Pa = (floatx4){0.f,0.f,0.f,0.f}, Pb = Pa;
#pragma unroll
        for (int kt = 0; kt < 4; ++kt) {
            short8 s0 = *(const short8*)&SbT[p][lr][(2*kt)   * 32 + lg * 8];
            short8 s1 = *(const short8*)&SbT[p][lr][(2*kt+1) * 32 + lg * 8];
            short8 a0 = *(const short8*)(ab + opo[2*kt]);
            short8 a1 = *(const short8*)(ab + opo[2*kt+1]);
            Pa = __builtin_amdgcn_mfma_f32_16x16x32_bf16(a0, s0, Pa, 0,0,0);
            Pb = __builtin_amdgcn_mfma_f32_16x16x32_bf16(a1, s1, Pb, 0,0,0);
        }
        floatx4 P = Pa + Pb;

        // 5) waves 0,1: uadj = u - w@S -> uadjT[p]
        if (!isQ) {
            ushort4 u4 = *(const ushort4*)(sp + OU + opu);
            float ua0 = bf2f(u4.x) - P[0];
            float ua1 = bf2f(u4.y) - P[1];
            float ua2 = bf2f(u4.z) - P[2];
            float ua3 = bf2f(u4.w) - P[3];
            int cc0 = half * 16 + lg * 4;
            *(unsigned int*)&uadjT[p][lr][cc0]     = pkbf(ua0, ua1);
            *(unsigned int*)&uadjT[p][lr][cc0 + 2] = pkbf(ua2, ua3);
        }
        lds_barrier();   // (b) uadjT[p] visible

        short8 ub = *(const short8*)&uadjT[p][lr][lg * 8];

        // 6) waves 2,3: O = q@S + attn@uadj -> dout
        if (isQ) {
            short8 paR = *(const short8*)(sp + OA + opa);
            floatx4 Ot = __builtin_amdgcn_mfma_f32_16x16x32_bf16(paR, ub, P, 0,0,0);
#pragma unroll
            for (int r = 0; r < 4; ++r)
                db[(size_t)(l0 + half * 16 + lg * 4 + r) * DH + jcol + lr] = Ot[r];
        }

        // 7) S e-slice += kT @ uadj
#pragma unroll
        for (int mt = 0; mt < 4; ++mt) {
            short8 pkR = *(const short8*)(sp + OK2 + opk[mt]);
            Sacc[mt] = __builtin_amdgcn_mfma_f32_16x16x32_bf16(pkR, ub, Sacc[mt], 0,0,0);
        }
        // no trailing barrier: slot p / SbT[p] / uadjT[p] untouched until ci+2,
        // guarded by the vmcnt drain + barriers (a),(b) of ci+1
    }
    #undef OW
    #undef OQ
    #undef OK2
    #undef OA
    #undef OU
}

// ------------------------------------------------- per-head stats
__global__ __launch_bounds__(256) void stats_k(
    const float* __restrict__ ls, const float* __restrict__ llb,
    const float* __restrict__ dox, const float* __restrict__ v,
    float* __restrict__ stats)
{
    int bl = blockIdx.x;
    int b = bl >> 12, l = bl & (LL - 1);
    int wv = threadIdx.x >> 6, ln = threadIdx.x & 63;
    size_t ibase = (size_t)bl * DD + wv * DH;
    size_t dbase = (((size_t)(b * HH + wv)) * LL + l) * DH;
#pragma unroll
    for (int tn = 0; tn < 4; ++tn) {
        const float* p; size_t base;
        if (tn == 0)      { p = ls;  base = ibase; }
        else if (tn == 1) { p = llb; base = ibase; }
        else if (tn == 2) { p = dox; base = dbase; }
        else              { p = v;   base = ibase; }
        float4 x = *(const float4*)(p + base + ln * 4);
        float sm = x.x + x.y + x.z + x.w;
        float sq = x.x*x.x + x.y*x.y + x.z*x.z + x.w*x.w;
        float sa = fabsf(x.x) + fabsf(x.y) + fabsf(x.z) + fabsf(x.w);
#pragma unroll
        for (int off = 32; off > 0; off >>= 1) {
            sm += __shfl_down(sm, off);
            sq += __shfl_down(sq, off);
            sa += __shfl_down(sa, off);
        }
        if (ln == 0) {
            float mean = sm * (1.0f / DH);
            float var = sq * (1.0f / DH) - mean * mean;
            float am = sa * (1.0f / DH);
            float l2 = sqrtf(sq);
            *(float4*)(stats + (size_t)bl * 64 + wv * 16 + tn * 4) =
                make_float4(mean, var, am, l2);
        }
    }
}

// ------------------------------------------------- gate finish v2
__global__ __launch_bounds__(256) void gate_fin2_k(
    const float* __restrict__ hpart, const float* __restrict__ stats,
    const unsigned short* __restrict__ w1s,
    const float* __restrict__ w2, const float* __restrict__ b2,
    const float* __restrict__ ltemp, float* __restrict__ fw)
{
    const int bl = blockIdx.x;
    const int t = threadIdx.x;
    const float temp = log1pf(expf(ltemp[0])) + 1e-4f;
    __shared__ float st[HH][16];
    __shared__ float red[4][16];
    __shared__ float fin[16];
    if (t < 64) st[t >> 4][t & 15] = stats[(size_t)bl * 64 + t];

    const int e0 = t * 4;
    float4 hp4 = *(const float4*)(hpart + (size_t)bl * DD + e0);
    float hp[4] = {hp4.x, hp4.y, hp4.z, hp4.w};
    float w2a[4][4];
#pragma unroll
    for (int j = 0; j < 4; ++j) {
        float4 wv = *(const float4*)(w2 + (size_t)j * 1024 + e0);
        w2a[j][0] = wv.x; w2a[j][1] = wv.y; w2a[j][2] = wv.z; w2a[j][3] = wv.w;
    }
    uint4 wpk[8];
    const uint4* wp = (const uint4*)(w1s + (size_t)e0 * 16);
#pragma unroll
    for (int i = 0; i < 8; ++i) wpk[i] = wp[i];
    __syncthreads();

    float lg[4][4];
#pragma unroll
    for (int h = 0; h < 4; ++h)
#pragma unroll
        for (int j = 0; j < 4; ++j) lg[h][j] = 0.0f;

#pragma unroll
    for (int ii = 0; ii < 4; ++ii) {
        float xh[4] = {hp[ii], hp[ii], hp[ii], hp[ii]};
        unsigned arr[8] = {wpk[ii*2].x, wpk[ii*2].y, wpk[ii*2].z, wpk[ii*2].w,
                           wpk[ii*2+1].x, wpk[ii*2+1].y, wpk[ii*2+1].z, wpk[ii*2+1].w};
#pragma unroll
        for (int p = 0; p < 8; ++p) {
            float wlo = bflo(arr[p]), whi = bfhi(arr[p]);
            int s = p * 2;
#pragma unroll
            for (int h = 0; h < 4; ++h)
                xh[h] += st[h][s] * wlo + st[h][s + 1] * whi;
        }
#pragma unroll
        for (int h = 0; h < 4; ++h) {
            float x = xh[h];
            float gct = 0.5f * x * (1.0f + erff(x * 0.70710678118654752f));
            lg[h][0] += gct * w2a[0][ii];
            lg[h][1] += gct * w2a[1][ii];
            lg[h][2] += gct * w2a[2][ii];
            lg[h][3] += gct * w2a[3][ii];
        }
    }

#pragma unroll
    for (int h = 0; h < 4; ++h)
#pragma unroll
        for (int j = 0; j < 4; ++j)
#pragma unroll
            for (int off = 32; off > 0; off >>= 1)
                lg[h][j] += __shfl_down(lg[h][j], off);

    const int wv = t >> 6, ln = t & 63;
    if (ln == 0) {
#pragma unroll
        for (int h = 0; h < 4; ++h)
#pragma unroll
            for (int j = 0; j < 4; ++j) red[wv][h * 4 + j] = lg[h][j];
    }
    __syncthreads();
    if (t < 16) {
        float s = red[0][t] + red[1][t] + red[2][t] + red[3][t] + b2[t & 3];
        fin[t] = s / temp;
    }
    __syncthreads();
    if (t < 4) {
        float l0 = fin[t*4], l1 = fin[t*4+1], l2 = fin[t*4+2], l3 = fin[t*4+3];
        float m = fmaxf(fmaxf(l0, l1), fmaxf(l2, l3));
        float e0x = expf(l0-m), e1 = expf(l1-m), e2 = expf(l2-m), e3 = expf(l3-m);
        float inv = 1.0f / (e0x + e1 + e2 + e3);
        *(float4*)(fw + (size_t)bl * 16 + t * 4) = make_float4(e0x*inv, e1*inv, e2*inv, e3*inv);
    }
}

// ------------------------------------------------- combine + rms norm
__global__ __launch_bounds__(256) void combine_k(
    const float* __restrict__ ls, const float* __restrict__ llb,
    const float* __restrict__ dox, const float* __restrict__ v,
    const float* __restrict__ fw, const float* __restrict__ rss,
    const float* __restrict__ rsl, const float* __restrict__ onw,
    float* __restrict__ opre)
{
    int h = blockIdx.x & (HH - 1);
    int bl = blockIdx.x >> 2;
    int b = bl >> 12, l = bl & (LL - 1);
    int d = threadIdx.x;
    size_t i1 = (size_t)blockIdx.x * DH + d;
    size_t i2 = (((size_t)(b * HH + h)) * LL + l) * DH + d;
    const float* fwp = fw + (size_t)blockIdx.x * 4;
    float f0 = fwp[0], f1 = fwp[1], f2 = fwp[2], f3 = fwp[3];
    float aS = rss[0], aL = rsl[0];
    float vls = ls[i1], vll = llb[i1], vd = dox[i2], vv = v[i1];
    float o = f0*vls + f1*vll + f2*vd + f3*vv + aS*vls + aL*vll;
    float s = o * o;
#pragma unroll
    for (int off = 32; off > 0; off >>= 1) s += __shfl_down(s, off);
    __shared__ float red[4];
    int wv = threadIdx.x >> 6, ln = threadIdx.x & 63;
    if (ln == 0) red[wv] = s;
    __syncthreads();
    float ms = (red[0] + red[1] + red[2] + red[3]) * (1.0f / DH);
    opre[(size_t)bl * DD + h * DH + d] = o * rsqrtf(ms + 1e-5f) * onw[d];
}

// ================================================================ launch
extern "C" void kernel_launch(void* const* d_in, const int* in_sizes, int n_in,
                              void* d_out, int out_size, void* d_ws, size_t ws_size,
                              hipStream_t stream)
{
    const float* hs  = (const float*)d_in[0];
    const float* qw  = (const float*)d_in[1];
    const float* kw  = (const float*)d_in[2];
    const float* vw  = (const float*)d_in[3];
    const float* bw  = (const float*)d_in[4];
    const float* qcw = (const float*)d_in[5];
    const float* kcw = (const float*)d_in[6];
    const float* vcw = (const float*)d_in[7];
    const float* fsw = (const float*)d_in[8];
    const float* flw = (const float*)d_in[9];
    const float* w1  = (const float*)d_in[10];
    const float* b1  = (const float*)d_in[11];
    const float* w2  = (const float*)d_in[12];
    const float* b2  = (const float*)d_in[13];
    const float* lt  = (const float*)d_in[14];
    const float* rss = (const float*)d_in[15];
    const float* rsl = (const float*)d_in[16];
    const float* onw = (const float*)d_in[17];
    const float* opw = (const float*)d_in[18];
    float* out = (float*)d_out;

    float* wsf = (float*)d_ws;
    float* tmp   = wsf;
    unsigned short* ktbuf = (unsigned short*)tmp;
    unsigned short* uTbuf = (unsigned short*)(wsf + BLD/2);
    float* vbuf  = wsf + BLD;
    float* dbuf  = wsf + 2*BLD;
    // hsb shares the dbuf region -> DEAD once scan10 writes dbuf. Only used in phase 1.
    unsigned short* hsb = (unsigned short*)(wsf + 2*BLD);
    // bf16 QKV weights live in the dead second half of the dbuf region during phase 1
    unsigned short* qwb = (unsigned short*)(wsf + 2*BLD + BLD/2);
    unsigned short* kwb = qwb + (size_t)DD*DD;
    unsigned short* vwb = kwb + (size_t)DD*DD;
    unsigned short* qbuf = (unsigned short*)(wsf + 3*BLD);
    unsigned short* kbuf = qbuf + BLD;
    float* hpart = wsf + 3*BLD;
    float* opre  = wsf + 3*BLD;
    unsigned short* ubuf = (unsigned short*)(wsf + 4*BLD);
    unsigned short* wbuf = ubuf + BLD;
    float* llbuf = wsf + 4*BLD;
    float* lsbuf = tmp;
    unsigned short* attnb = (unsigned short*)(wsf + 5*BLD);
    float* statsb = wsf + 5*BLD + 524288;
    float* fwbuf  = statsb + (size_t)BL*HH*16;
    float* betab  = fwbuf + (size_t)BL*HH*4;
    unsigned short* w1sp = (unsigned short*)(betab + (size_t)BL*HH);

    dim3 gg(8, 64);   // N/128, M/128

    cvt_bf_k<<<(int)(BLD/1024), 256, 0, stream>>>(hs, hsb);
    cvt_bf_k<<<1024, 256, 0, stream>>>(qw, qwb);
    cvt_bf_k<<<1024, 256, 0, stream>>>(kw, kwb);
    cvt_bf_k<<<1024, 256, 0, stream>>>(vw, vwb);
    w1s_prep_k<<<64, 256, 0, stream>>>(w1, w1sp);

    gemm_bb<<<gg, 256, 0, stream>>>(hsb, DD, qwb, DD, tmp, DD, DD);
    convnorm_qk_k<<<BL*HH, 256, 0, stream>>>(tmp, qcw, qbuf);
    gemm_bb<<<gg, 256, 0, stream>>>(hsb, DD, kwb, DD, tmp, DD, DD);
    convnorm_qk_k<<<BL*HH, 256, 0, stream>>>(tmp, kcw, kbuf);
    gemm_bb<<<gg, 256, 0, stream>>>(hsb, DD, vwb, DD, tmp, DD, DD);
    conv_silu_k<<<(int)(BLD/256), 256, 0, stream>>>(tmp, vcw, vbuf);

    beta_k<<<BL, 256, 0, stream>>>(hs, bw, betab);

    tr_k<<<8*64*4, 256, 0, stream>>>(kbuf, ktbuf);
    chunk_prep_k<<<BB*HH*NC, 256, 0, stream>>>(qbuf, kbuf, vbuf, betab, ubuf, wbuf, attnb);
    tru_k<<<8*64*4, 256, 0, stream>>>(ubuf, uTbuf);

    scan10_k<<<BB*HH*16, 256, 0, stream>>>(qbuf, ktbuf, uTbuf, wbuf, attnb, dbuf);

    fir2_k<5><<<BB*64*16, 256, 0, stream>>>(vbuf, fsw, lsbuf);
    fir2_k<64><<<BB*64*16, 256, 0, stream>>>(vbuf, flw, llbuf);

    stats_k<<<BL, 256, 0, stream>>>(lsbuf, llbuf, dbuf, vbuf, statsb);

    // hpart GEMM reads the pristine f32 input hs (hsb is dead: overwritten by dbuf)
    gemm_mfma<<<gg, 256, 0, stream>>>(hs, DD, w1, 1040, b1, hpart, DD, DD);
    gate_fin2_k<<<BL, 256, 0, stream>>>(hpart, statsb, w1sp, w2, b2, lt, fwbuf);

    combine_k<<<BL*HH, 256, 0, stream>>>(lsbuf, llbuf, dbuf, vbuf, fwbuf, rss, rsl, onw, opre);

    gemm_mfma<<<gg, 256, 0, stream>>>(opre, DD, opw, DD, nullptr, out, DD, DD);
}

// Round 5
// 876.437 us; speedup vs baseline: 1.6113x; 1.1301x over previous
//
#include <hip/hip_runtime.h>
#include <hip/hip_bf16.h>

#define BB 2
#define LL 4096
#define DD 1024
#define HH 4
#define DH 256
#define CH 32
#define NC (LL/CH)     // 128
#define BL (BB*LL)     // 8192
#define BLD ((size_t)BB*LL*DD) // 8388608

typedef __attribute__((ext_vector_type(8))) short short8;
typedef __attribute__((ext_vector_type(4))) float floatx4;

__device__ __forceinline__ float bf2f(unsigned short u) {
    union { float f; unsigned int i; } x; x.i = ((unsigned int)u) << 16; return x.f;
}
__device__ __forceinline__ float bflo(unsigned int u) {
    union { float f; unsigned int i; } x; x.i = u << 16; return x.f;
}
__device__ __forceinline__ float bfhi(unsigned int u) {
    union { float f; unsigned int i; } x; x.i = u & 0xFFFF0000u; return x.f;
}
__device__ __forceinline__ unsigned short f2bf(float f) {
    union { float f; unsigned int i; } x; x.f = f;
    unsigned int r = x.i + 0x7FFFu + ((x.i >> 16) & 1u);
    return (unsigned short)(r >> 16);
}
// pack two f32 -> (bf16(b)<<16)|bf16(a), round-half-up
__device__ __forceinline__ unsigned int pkbf(float a, float b) {
    unsigned int ua = __float_as_uint(a) + 0x8000u;
    unsigned int ub = __float_as_uint(b) + 0x8000u;
    return __builtin_amdgcn_perm(ub, ua, 0x07060302);
}
// barrier with LDS-only drain (no vmcnt drain -> prefetch loads stay in flight)
__device__ __forceinline__ void lds_barrier() {
    __builtin_amdgcn_s_waitcnt(0xC07F);
    __builtin_amdgcn_s_barrier();
}

typedef __attribute__((address_space(1))) const unsigned int as1_uint;
typedef __attribute__((address_space(3))) unsigned int as3_uint;
// async 1KB DMA: 64 lanes x 16B from per-lane global src to wave-uniform LDS base
__device__ __forceinline__ void dma16(const void* g, void* l) {
    __builtin_amdgcn_global_load_lds((as1_uint*)g, (as3_uint*)l, 16, 0, 0);
}

// ---------------------------------------------------------------- f32 -> bf16 bulk convert
__global__ __launch_bounds__(256) void cvt_bf_k(
    const float* __restrict__ x, unsigned short* __restrict__ y)
{
    size_t i = ((size_t)blockIdx.x * 256 + threadIdx.x) * 4;
    float4 v = *(const float4*)(x + i);
    ushort4 o;
    o.x = f2bf(v.x); o.y = f2bf(v.y); o.z = f2bf(v.z); o.w = f2bf(v.w);
    *(ushort4*)(y + i) = o;
}

// ---------------------------------------------------------------- pack w1[:,1024:1040] -> bf16 [1024][16]
__global__ __launch_bounds__(256) void w1s_prep_k(
    const float* __restrict__ w1, unsigned short* __restrict__ w1s)
{
    int idx = blockIdx.x * 256 + threadIdx.x;   // 16384
    int e = idx >> 4, s = idx & 15;
    w1s[idx] = f2bf(w1[(size_t)e * 1040 + 1024 + s]);
}

// ---------------------------------------------------------------- bf16 MFMA GEMM (NT), f32 A, f32 W
__global__ __launch_bounds__(256) void gemm_mfma(
    const float* __restrict__ A, int lda,
    const float* __restrict__ W, int ldw,
    const float* __restrict__ bias,
    float* __restrict__ C, int ldc, int K)
{
    __shared__ unsigned short Abuf[128][56];
    __shared__ unsigned short Bbuf[128][56];
    const int t = threadIdx.x;
    const int wave = t >> 6, lane = t & 63;
    const int wm = wave >> 1, wn = wave & 1;
    const int row0 = blockIdx.y * 128, col0 = blockIdx.x * 128;

    floatx4 acc[4][4];
#pragma unroll
    for (int i = 0; i < 4; ++i)
#pragma unroll
        for (int j = 0; j < 4; ++j) acc[i][j] = (floatx4){0.f, 0.f, 0.f, 0.f};

    const int fr = lane & 15, fk = (lane >> 4) * 8;

    for (int kt = 0; kt < K; kt += 32) {
        __syncthreads();
#pragma unroll
        for (int it = 0; it < 2; ++it) {
            int idx = t + it * 256;
            int r = idx >> 2, s = (idx & 3) * 8;
            const float* ap = A + (size_t)(row0 + r) * lda + kt + s;
            float4 a0 = *(const float4*)(ap);
            float4 a1 = *(const float4*)(ap + 4);
            ushort4 p0, p1;
            p0.x = f2bf(a0.x); p0.y = f2bf(a0.y); p0.z = f2bf(a0.z); p0.w = f2bf(a0.w);
            p1.x = f2bf(a1.x); p1.y = f2bf(a1.y); p1.z = f2bf(a1.z); p1.w = f2bf(a1.w);
            *(ushort4*)&Abuf[r][s]     = p0;
            *(ushort4*)&Abuf[r][s + 4] = p1;
            const float* wp = W + (size_t)(col0 + r) * ldw + kt + s;
            float4 b0 = *(const float4*)(wp);
            float4 b1 = *(const float4*)(wp + 4);
            ushort4 q0, q1;
            q0.x = f2bf(b0.x); q0.y = f2bf(b0.y); q0.z = f2bf(b0.z); q0.w = f2bf(b0.w);
            q1.x = f2bf(b1.x); q1.y = f2bf(b1.y); q1.z = f2bf(b1.z); q1.w = f2bf(b1.w);
            *(ushort4*)&Bbuf[r][s]     = q0;
            *(ushort4*)&Bbuf[r][s + 4] = q1;
        }
        __syncthreads();

        short8 afrag[4], bfrag[4];
#pragma unroll
        for (int i = 0; i < 4; ++i) {
            afrag[i] = *(const short8*)&Abuf[wm * 64 + i * 16 + fr][fk];
            bfrag[i] = *(const short8*)&Bbuf[wn * 64 + i * 16 + fr][fk];
        }
#pragma unroll
        for (int i = 0; i < 4; ++i)
#pragma unroll
            for (int j = 0; j < 4; ++j)
                acc[i][j] = __builtin_amdgcn_mfma_f32_16x16x32_bf16(
                    afrag[i], bfrag[j], acc[i][j], 0, 0, 0);
    }

    const int fc = lane & 15, frow = (lane >> 4) * 4;
#pragma unroll
    for (int j = 0; j < 4; ++j) {
        int col = col0 + wn * 64 + j * 16 + fc;
        float bv = bias ? bias[col] : 0.0f;
#pragma unroll
        for (int i = 0; i < 4; ++i) {
#pragma unroll
            for (int r = 0; r < 4; ++r) {
                int row = row0 + wm * 64 + i * 16 + frow + r;
                C[(size_t)row * ldc + col] = acc[i][j][r] + bv;
            }
        }
    }
}

// ---------------------------------------------------------------- bf16 MFMA GEMM (NT), bf16 A, bf16 B
__global__ __launch_bounds__(256) void gemm_bb(
    const unsigned short* __restrict__ A, int lda,
    const unsigned short* __restrict__ B, int ldb,
    float* __restrict__ C, int ldc, int K)
{
    __shared__ unsigned short Abuf[128][56];
    __shared__ unsigned short Bbuf[128][56];
    const int t = threadIdx.x;
    const int wave = t >> 6, lane = t & 63;
    const int wm = wave >> 1, wn = wave & 1;
    const int row0 = blockIdx.y * 128, col0 = blockIdx.x * 128;

    floatx4 acc[4][4];
#pragma unroll
    for (int i = 0; i < 4; ++i)
#pragma unroll
        for (int j = 0; j < 4; ++j) acc[i][j] = (floatx4){0.f, 0.f, 0.f, 0.f};

    const int fr = lane & 15, fk = (lane >> 4) * 8;

    for (int kt = 0; kt < K; kt += 32) {
        __syncthreads();
#pragma unroll
        for (int it = 0; it < 2; ++it) {
            int idx = t + it * 256;
            int r = idx >> 2, s = (idx & 3) * 8;
            uint4 av = *(const uint4*)(A + (size_t)(row0 + r) * lda + kt + s);
            *(uint4*)&Abuf[r][s] = av;
            uint4 bv = *(const uint4*)(B + (size_t)(col0 + r) * ldb + kt + s);
            *(uint4*)&Bbuf[r][s] = bv;
        }
        __syncthreads();

        short8 afrag[4], bfrag[4];
#pragma unroll
        for (int i = 0; i < 4; ++i) {
            afrag[i] = *(const short8*)&Abuf[wm * 64 + i * 16 + fr][fk];
            bfrag[i] = *(const short8*)&Bbuf[wn * 64 + i * 16 + fr][fk];
        }
#pragma unroll
        for (int i = 0; i < 4; ++i)
#pragma unroll
            for (int j = 0; j < 4; ++j)
                acc[i][j] = __builtin_amdgcn_mfma_f32_16x16x32_bf16(
                    afrag[i], bfrag[j], acc[i][j], 0, 0, 0);
    }

    const int fc = lane & 15, frow = (lane >> 4) * 4;
#pragma unroll
    for (int j = 0; j < 4; ++j) {
        int col = col0 + wn * 64 + j * 16 + fc;
#pragma unroll
        for (int i = 0; i < 4; ++i) {
#pragma unroll
            for (int r = 0; r < 4; ++r) {
                int row = row0 + wm * 64 + i * 16 + frow + r;
                C[(size_t)row * ldc + col] = acc[i][j][r];
            }
        }
    }
}

// --------------------------------------- causal dwconv K=4 + silu + head-l2norm -> bf16
__global__ __launch_bounds__(256) void convnorm_qk_k(
    const float* __restrict__ x, const float* __restrict__ w,
    unsigned short* __restrict__ y)
{
    int bl = blockIdx.x >> 2;
    int h  = blockIdx.x & 3;
    int l  = bl & (LL - 1);
    int d  = threadIdx.x;
    int c  = h * DH + d;
    const float* wp = w + (size_t)c * 4;
    const float* xp = x + (size_t)bl * DD + c;
    float acc = wp[3] * xp[0];
    if (l >= 1) acc += wp[2] * xp[-(int)DD];
    if (l >= 2) acc += wp[1] * xp[-2*(int)DD];
    if (l >= 3) acc += wp[0] * xp[-3*(int)DD];
    acc = acc / (1.0f + expf(-acc));
    float s = acc * acc;
#pragma unroll
    for (int off = 32; off > 0; off >>= 1) s += __shfl_down(s, off);
    __shared__ float red[4];
    int wv = threadIdx.x >> 6, ln = threadIdx.x & 63;
    if (ln == 0) red[wv] = s;
    __syncthreads();
    float tot = red[0] + red[1] + red[2] + red[3];
    y[(size_t)bl * DD + c] = f2bf(acc * rsqrtf(tot));
}

// ------------------------------------------------- causal depthwise conv K=4 + silu (f32)
__global__ __launch_bounds__(256) void conv_silu_k(
    const float* __restrict__ x, const float* __restrict__ w, float* __restrict__ y)
{
    size_t idx = (size_t)blockIdx.x * 256 + threadIdx.x;
    int c = (int)(idx & (DD - 1));
    int bl = (int)(idx >> 10);
    int l = bl & (LL - 1);
    const float* wp = w + (size_t)c * 4;
    const float* xp = x + (size_t)bl * DD + c;
    float acc = wp[3] * xp[0];
    if (l >= 1) acc += wp[2] * xp[-(int)DD];
    if (l >= 2) acc += wp[1] * xp[-2*(int)DD];
    if (l >= 3) acc += wp[0] * xp[-3*(int)DD];
    y[idx] = acc / (1.0f + expf(-acc));
}

// ------------------------------------------------- FIR causal depthwise conv, LDS-tiled
template<int K>
__global__ __launch_bounds__(256) void fir2_k(
    const float* __restrict__ x, const float* __restrict__ filt, float* __restrict__ y)
{
    const int ctile = blockIdx.x & 15;
    const int ltile = (blockIdx.x >> 4) & 63;
    const int b = blockIdx.x >> 10;
    const int RT = 64 + K - 1;
    __shared__ float xs[RT][64];
    __shared__ float fs[64][K + 1];
    const int t = threadIdx.x;
    const int l0 = ltile * 64;

    for (int i = t; i < RT * 16; i += 256) {
        int li = i >> 4, c4 = (i & 15) * 4;
        int l = l0 - (K - 1) + li;
        float4 v = make_float4(0.f, 0.f, 0.f, 0.f);
        if (l >= 0)
            v = *(const float4*)(x + ((size_t)b * LL + l) * DD + ctile * 64 + c4);
        *(float4*)&xs[li][c4] = v;
    }
    for (int i = t; i < 64 * K; i += 256) {
        fs[i / K][i % K] = filt[(size_t)ctile * 64 * K + i];
    }
    __syncthreads();

    const int c = t & 63, lg = t >> 6;
    float acc[16];
#pragma unroll
    for (int o = 0; o < 16; ++o) acc[o] = 0.f;
#pragma unroll
    for (int j = 0; j < 16 + K - 1; ++j) {
        float xv = xs[lg * 16 + j][c];
#pragma unroll
        for (int o = 0; o < 16; ++o) {
            int tap = j - o;
            if (tap >= 0 && tap < K) acc[o] += fs[c][tap] * xv;
        }
    }
    size_t base = ((size_t)b * LL + l0 + lg * 16) * DD + ctile * 64 + c;
#pragma unroll
    for (int o = 0; o < 16; ++o)
        y[base + (size_t)o * DD] = acc[o];
}

// ------------------------------------------------- beta = sigmoid(hs @ b_proj^T)
__global__ __launch_bounds__(256) void beta_k(
    const float* __restrict__ hs, const float* __restrict__ bw, float* __restrict__ beta)
{
    int bl = blockIdx.x;
    const float* xr = hs + (size_t)bl * DD;
    float a0=0.f,a1=0.f,a2=0.f,a3=0.f;
    for (int k = threadIdx.x; k < DD; k += 256) {
        float xv = xr[k];
        a0 += xv * bw[k];
        a1 += xv * bw[DD + k];
        a2 += xv * bw[2*DD + k];
        a3 += xv * bw[3*DD + k];
    }
#pragma unroll
    for (int off = 32; off > 0; off >>= 1) {
        a0 += __shfl_down(a0, off); a1 += __shfl_down(a1, off);
        a2 += __shfl_down(a2, off); a3 += __shfl_down(a3, off);
    }
    __shared__ float red[4][4];
    int wv = threadIdx.x >> 6, ln = threadIdx.x & 63;
    if (ln == 0) { red[wv][0]=a0; red[wv][1]=a1; red[wv][2]=a2; red[wv][3]=a3; }
    __syncthreads();
    if (threadIdx.x < 4) {
        int h = threadIdx.x;
        float s = red[0][h] + red[1][h] + red[2][h] + red[3][h];
        beta[(size_t)bl * HH + h] = 1.0f / (1.0f + expf(-s));
    }
}

// ------------------------------------------------- k transpose: k[b,l,h*DH+e] -> kT[bh,e,l]
__global__ __launch_bounds__(256) void tr_k(
    const unsigned short* __restrict__ k, unsigned short* __restrict__ kT)
{
    int et = blockIdx.x & 3;
    int lt = (blockIdx.x >> 2) & 63;
    int bh = blockIdx.x >> 8;
    int h = bh & 3, b = bh >> 2;
    __shared__ unsigned short tile[64][72];
    int t = threadIdx.x;
    int tr = t >> 4;
    int tc = (t & 15) * 4;
#pragma unroll
    for (int i = 0; i < 4; ++i) {
        int l = tr + i * 16;
        ushort4 v = *(const ushort4*)(k + ((size_t)b * LL + lt*64 + l) * DD + h * DH + et*64 + tc);
        *(ushort4*)&tile[l][tc] = v;
    }
    __syncthreads();
#pragma unroll
    for (int i = 0; i < 4; ++i) {
        int e = tr + i * 16;
        ushort4 v;
        v.x = tile[tc+0][e]; v.y = tile[tc+1][e];
        v.z = tile[tc+2][e]; v.w = tile[tc+3][e];
        *(ushort4*)(kT + ((size_t)bh * DH + et*64 + e) * LL + (size_t)lt*64 + tc) = v;
    }
}

// ------------------------------------------------- chunk prep v2: MFMA everywhere.
// Phase 2: Am = -beta_c*(k k^T) strict-lower and attn = masked q k^T via 32 MFMAs/wave
// (replaces 2x2048 scalar FMAs + conflicted kt reads). Phase 3: forward substitution
// fully register-resident in ONE wave (lane j owns column j; static-unrolled __shfl
// broadcasts) -> 62 barriers down to 4 total. Phase 4: u = Ab@v and w = Ab@k via MFMA
// with dual-bf16 Ab (hi+lo, f32-equivalent), w's B-operand straight from global kT,
// and u written TRANSPOSED directly to uT (eliminates the tru_k kernel).
__global__ __launch_bounds__(256) void chunk_prep2_k(
    const unsigned short* __restrict__ q, const unsigned short* __restrict__ k,
    const unsigned short* __restrict__ kT, const float* __restrict__ v,
    const float* __restrict__ beta,
    unsigned short* __restrict__ uT, unsigned short* __restrict__ w_out,
    unsigned short* __restrict__ attn_out)
{
    const int ci = blockIdx.x & (NC - 1);
    const int bh = blockIdx.x >> 7;
    const int h = bh & (HH - 1), b = bh >> 2;
    __shared__ unsigned short kL[32][264];
    __shared__ unsigned short qL[32][264];
    __shared__ float vL[32][260];
    __shared__ float AmL[32][33];
    __shared__ unsigned short AbH[32][40];
    __shared__ unsigned short AbL2[32][40];
    __shared__ float betL[32];
    const int t = threadIdx.x;
    const int wave = t >> 6, lane = t & 63;
    const int lr = lane & 15, lg = lane >> 4;
    const int l0 = ci * CH;
    const size_t rowbase = (size_t)b * LL + l0;

    // ---- phase 1: stage k,q (bf16, padded rows) + v (f32, padded) + beta
    for (int i = t; i < 1024; i += 256) {
        int r = i >> 5, s8 = (i & 31) * 8;
        *(uint4*)&kL[r][s8] = *(const uint4*)(k + (rowbase + r) * DD + h * DH + s8);
        *(uint4*)&qL[r][s8] = *(const uint4*)(q + (rowbase + r) * DD + h * DH + s8);
    }
    for (int i = t; i < 2048; i += 256) {
        int e = i >> 6, d4 = (i & 63) * 4;
        *(float4*)&vL[e][d4] = *(const float4*)(v + (rowbase + e) * DD + h * DH + d4);
    }
    if (t < 32) betL[t] = beta[(rowbase + t) * HH + h];
    __syncthreads();

    // ---- phase 2: per-wave 16x16 tile of Am (k k^T) and attn (q k^T), K=256
    const int mt = wave >> 1, nt = wave & 1;
    floatx4 accA = (floatx4){0.f,0.f,0.f,0.f}, accT = accA;
#pragma unroll
    for (int ks = 0; ks < 8; ++ks) {
        short8 bk = *(const short8*)&kL[nt * 16 + lr][ks * 32 + lg * 8];
        short8 ak = *(const short8*)&kL[mt * 16 + lr][ks * 32 + lg * 8];
        short8 aq = *(const short8*)&qL[mt * 16 + lr][ks * 32 + lg * 8];
        accA = __builtin_amdgcn_mfma_f32_16x16x32_bf16(ak, bk, accA, 0, 0, 0);
        accT = __builtin_amdgcn_mfma_f32_16x16x32_bf16(aq, bk, accT, 0, 0, 0);
    }
    {
        const size_t abase = (size_t)blockIdx.x * (CH * CH);
        const int ee = nt * 16 + lr;
#pragma unroll
        for (int r = 0; r < 4; ++r) {
            int c = mt * 16 + lg * 4 + r;
            float bc = betL[c];
            AmL[c][ee] = (ee < c) ? (-bc * accA[r]) : 0.0f;
            attn_out[abase + (size_t)c * CH + ee] =
                (ee <= c) ? f2bf(accT[r]) : (unsigned short)0;
        }
    }
    __syncthreads();

    // pre-issue w's B-frags from global kT (independent of Ab -> latency hides
    // under the substitution wave's work)
    const unsigned short* kTg = kT + (size_t)bh * DH * LL;
    short8 wB[4];
#pragma unroll
    for (int n = 0; n < 4; ++n)
        wB[n] = *(const short8*)(kTg + (size_t)(wave * 64 + n * 16 + lr) * LL + l0 + lg * 8);

    // ---- phase 3: wave 0 forward-substitution, column-per-lane in registers
    if (wave == 0) {
        const int j = lane & 31;
        float col[32];
#pragma unroll
        for (int c = 0; c < 32; ++c) col[c] = AmL[c][j];
#pragma unroll
        for (int i = 1; i < 32; ++i) {
            float u0 = 0.f, u1 = 0.f;
#pragma unroll
            for (int kk = 0; kk < 32; kk += 2) {
                if (kk < i)     u0 += __shfl(col[i], kk) * col[kk];
                if (kk + 1 < i) u1 += __shfl(col[i], kk + 1) * col[kk + 1];
            }
            if (j < i) col[i] += u0 + u1;
        }
        if (lane < 32) {
            const float bj = betL[j];
#pragma unroll
            for (int c = 0; c < 32; ++c) {
                float val = (col[c] + (c == j ? 1.0f : 0.0f)) * bj;
                unsigned short hi = f2bf(val);
                AbH[c][j] = hi;
                AbL2[c][j] = f2bf(val - bf2f(hi));
            }
        }
    }
    __syncthreads();

    // ---- phase 4: u^T = (Ab @ v)^T direct to uT; w = Ab @ k. Dual-bf16 Ab.
    short8 AH[2], ALo[2];
#pragma unroll
    for (int m = 0; m < 2; ++m) {
        AH[m]  = *(const short8*)&AbH[m * 16 + lr][lg * 8];
        ALo[m] = *(const short8*)&AbL2[m * 16 + lr][lg * 8];
    }
    const size_t uTbase = (size_t)bh * DH * LL;
    const size_t wbase  = (size_t)bh * LL * DH;
#pragma unroll
    for (int n = 0; n < 4; ++n) {
        const int d = wave * 64 + n * 16 + lr;
        union { short8 s8; unsigned int u[4]; } vf;
#pragma unroll
        for (int p2 = 0; p2 < 4; ++p2)
            vf.u[p2] = pkbf(vL[lg * 8 + p2 * 2][d], vL[lg * 8 + p2 * 2 + 1][d]);
#pragma unroll
        for (int m = 0; m < 2; ++m) {
            floatx4 au = (floatx4){0.f,0.f,0.f,0.f};
            au = __builtin_amdgcn_mfma_f32_16x16x32_bf16(AH[m],  vf.s8, au, 0, 0, 0);
            au = __builtin_amdgcn_mfma_f32_16x16x32_bf16(ALo[m], vf.s8, au, 0, 0, 0);
            ushort4 ou;
            ou.x = f2bf(au[0]); ou.y = f2bf(au[1]); ou.z = f2bf(au[2]); ou.w = f2bf(au[3]);
            *(ushort4*)(uT + uTbase + (size_t)d * LL + l0 + m * 16 + lg * 4) = ou;

            floatx4 aw = (floatx4){0.f,0.f,0.f,0.f};
            aw = __builtin_amdgcn_mfma_f32_16x16x32_bf16(AH[m],  wB[n], aw, 0, 0, 0);
            aw = __builtin_amdgcn_mfma_f32_16x16x32_bf16(ALo[m], wB[n], aw, 0, 0, 0);
#pragma unroll
            for (int r = 0; r < 4; ++r)
                w_out[wbase + (size_t)(l0 + m * 16 + lg * 4 + r) * DH + d] = f2bf(aw[r]);
        }
    }
}

// ------------------------------------------------- chunk scan v10: scan6 wave roles +
// LDS-staged operands via async global_load_lds (double-buffered slot, 51KB each).
__global__ __launch_bounds__(256, 1) void scan10_k(
    const unsigned short* __restrict__ q, const unsigned short* __restrict__ kT,
    const unsigned short* __restrict__ uT, const unsigned short* __restrict__ w,
    const unsigned short* __restrict__ attn, float* __restrict__ dout)
{
    const int bh = blockIdx.x & 7;     // low bits -> 16 same-bh blocks share one XCD
    const int jb = blockIdx.x >> 3;
    const int h = bh & (HH - 1), b = bh >> 2;
    const int jcol = jb * 16;
    const int wave = threadIdx.x >> 6, lane = threadIdx.x & 63;
    const int lr = lane & 15, lg = lane >> 4;
    const int half = wave & 1;
    const bool isQ = wave >= 2;

    // staged slot: W 16K | Q 16K | K 16K | A 2K | U 1K  = 52224 B
    #define OW 0
    #define OQ 16384
    #define OK2 32768
    #define OA 49152
    #define OU 51200
    __shared__ char slotmem[2][52224];
    __shared__ unsigned short SbT[2][16][264];   // [par][col][e] bf16
    __shared__ unsigned short uadjT[2][16][40];  // [par][col][cc] bf16

    floatx4 Sacc[4];
#pragma unroll
    for (int mt = 0; mt < 4; ++mt) Sacc[mt] = (floatx4){0.f,0.f,0.f,0.f};

    const char* wbB  = (const char*)(w  + (size_t)bh * LL * DH);
    const char* qbB  = (const char*)(q  + (size_t)b * LL * DD + h * DH);
    const char* kbB  = (const char*)(kT + (size_t)bh * DH * LL);
    const char* uTbB = (const char*)(uT + (size_t)bh * DH * LL);
    const char* atB  = (const char*)(attn + (size_t)bh * NC * (CH * CH));
    float* db = dout + (size_t)bh * LL * DH;

    // ---- per-lane DMA source byte offsets (loop-invariant; add l0-scaled base per chunk)
    const int lane16 = lane * 16;
    int pw[4], pq[4], pkt[4];
#pragma unroll
    for (int j = 0; j < 4; ++j) {
        int i = wave + 4 * j;
        int L = i * 1024 + lane16;
        { int row = L >> 9, g = (L >> 4) & 31, gs = g ^ (row & 7);
          pw[j] = row * 512 + gs * 16; }          // W rows: 512B stride (DH bf16)
        { int row = L >> 9, g = (L >> 4) & 31, gs = g ^ (row & 7);
          pq[j] = row * 2048 + gs * 16; }         // Q rows: 2048B stride (DD bf16)
        { int row = L >> 6, g = (L >> 4) & 3, gs = g ^ (row & 3);
          pkt[j] = row * 8192 + gs * 16; }        // kT rows: 8192B stride (LL bf16)
    }
    int pat = 0, put = 0;
    if (wave < 2) { int L = wave * 1024 + lane16;
        int row = L >> 6, g = (L >> 4) & 3, gs = g ^ (row & 3);
        pat = row * 64 + gs * 16; }               // attn rows: 64B stride
    else if (wave == 2) { int L = lane16;
        int row = L >> 6, g = (L >> 4) & 3;
        put = (jcol + row) * 8192 + g * 16; }     // uT rows: 8192B stride, linear

    // ---- per-lane LDS read byte offsets (swizzled to match DMA source permutation)
    const int row_o = half * 16 + lr;
    int opo[8];
#pragma unroll
    for (int kt = 0; kt < 8; ++kt)
        opo[kt] = row_o * 512 + (((kt * 4 + lg) ^ (row_o & 7)) * 16);
    int opk[4];
#pragma unroll
    for (int mt = 0; mt < 4; ++mt) {
        int rk = 64 * wave + 16 * mt + lr;
        opk[mt] = rk * 64 + ((lg ^ (rk & 3)) * 16);
    }
    const int opa = row_o * 64 + ((lg ^ (row_o & 3)) * 16);
    const int opu = lr * 64 + half * 32 + lg * 8;

    // ---- prologue: stage chunk 0 -> slot 0
    {
        char* sb = &slotmem[0][0];
#pragma unroll
        for (int j = 0; j < 4; ++j) {
            int i = wave + 4 * j;
            dma16(wbB + pw[j],  sb + OW  + i * 1024);
            dma16(qbB + pq[j],  sb + OQ  + i * 1024);
            dma16(kbB + pkt[j], sb + OK2 + i * 1024);
        }
        if (wave < 2)       dma16(atB + pat,  sb + OA + wave * 1024);
        else if (wave == 2) dma16(uTbB + put, sb + OU);
    }

#pragma unroll 2
    for (int ci = 0; ci < NC; ++ci) {
        const int p = ci & 1;
        const int l0 = ci * CH;

        // 1) pack wave's S e-slice -> SbT[p][col][e]
#pragma unroll
        for (int mt = 0; mt < 4; ++mt) {
            int e0 = 64 * wave + 16 * mt + lg * 4;
            *(unsigned int*)&SbT[p][lr][e0]     = pkbf(Sacc[mt][0], Sacc[mt][1]);
            *(unsigned int*)&SbT[p][lr][e0 + 2] = pkbf(Sacc[mt][2], Sacc[mt][3]);
        }

        // 2) drain this chunk's staged DMAs, publish LDS (slot p + SbT[p])
        asm volatile("s_waitcnt vmcnt(0)" ::: "memory");
        lds_barrier();   // (a)

        // 3) issue async stage of chunk ci+1 -> slot p^1 (safe: all p^1 readers drained at (a))
        {
            const int cn = (ci + 1 < NC) ? (ci + 1) : ci;
            const size_t lnW = (size_t)(cn * CH) * 512;
            const size_t lnQ = (size_t)(cn * CH) * 2048;
            const size_t lnK = (size_t)(cn * CH) * 2;
            char* sb = &slotmem[p ^ 1][0];
#pragma unroll
            for (int j = 0; j < 4; ++j) {
                int i = wave + 4 * j;
                dma16(wbB + lnW + pw[j],  sb + OW  + i * 1024);
                dma16(qbB + lnQ + pq[j],  sb + OQ  + i * 1024);
                dma16(kbB + lnK + pkt[j], sb + OK2 + i * 1024);
            }
            if (wave < 2)       dma16(atB + (size_t)cn * 2048 + pat, sb + OA + wave * 1024);
            else if (wave == 2) dma16(uTbB + lnK + put, sb + OU);
        }

        const char* sp = &slotmem[p][0];
        const char* ab = sp + (isQ ? OQ : OW);

        // 4) P = A @ S over full K=256 (two independent chains for ILP)
        floatx4 Pa = (floatx4){0.f,0.f,0.f,0.f}, Pb = Pa;
#pragma unroll
        for (int kt = 0; kt < 4; ++kt) {
            short8 s0 = *(const short8*)&SbT[p][lr][(2*kt)   * 32 + lg * 8];
            short8 s1 = *(const short8*)&SbT[p][lr][(2*kt+1) * 32 + lg * 8];
            short8 a0 = *(const short8*)(ab + opo[2*kt]);
            short8 a1 = *(const short8*)(ab + opo[2*kt+1]);
            Pa = __builtin_amdgcn_mfma_f32_16x16x32_bf16(a0, s0, Pa, 0,0,0);
            Pb = __builtin_amdgcn_mfma_f32_16x16x32_bf16(a1, s1, Pb, 0,0,0);
        }
        floatx4 P = Pa + Pb;

        // 5) waves 0,1: uadj = u - w@S -> uadjT[p]
        if (!isQ) {
            ushort4 u4 = *(const ushort4*)(sp + OU + opu);
            float ua0 = bf2f(u4.x) - P[0];
            float ua1 = bf2f(u4.y) - P[1];
            float ua2 = bf2f(u4.z) - P[2];
            float ua3 = bf2f(u4.w) - P[3];
            int cc0 = half * 16 + lg * 4;
            *(unsigned int*)&uadjT[p][lr][cc0]     = pkbf(ua0, ua1);
            *(unsigned int*)&uadjT[p][lr][cc0 + 2] = pkbf(ua2, ua3);
        }
        lds_barrier();   // (b) uadjT[p] visible

        short8 ub = *(const short8*)&uadjT[p][lr][lg * 8];

        // 6) waves 2,3: O = q@S + attn@uadj -> dout
        if (isQ) {
            short8 paR = *(const short8*)(sp + OA + opa);
            floatx4 Ot = __builtin_amdgcn_mfma_f32_16x16x32_bf16(paR, ub, P, 0,0,0);
#pragma unroll
            for (int r = 0; r < 4; ++r)
                db[(size_t)(l0 + half * 16 + lg * 4 + r) * DH + jcol + lr] = Ot[r];
        }

        // 7) S e-slice += kT @ uadj
#pragma unroll
        for (int mt = 0; mt < 4; ++mt) {
            short8 pkR = *(const short8*)(sp + OK2 + opk[mt]);
            Sacc[mt] = __builtin_amdgcn_mfma_f32_16x16x32_bf16(pkR, ub, Sacc[mt], 0,0,0);
        }
        // no trailing barrier: slot p / SbT[p] / uadjT[p] untouched until ci+2,
        // guarded by the vmcnt drain + barriers (a),(b) of ci+1
    }
    #undef OW
    #undef OQ
    #undef OK2
    #undef OA
    #undef OU
}

// ------------------------------------------------- per-head stats
__global__ __launch_bounds__(256) void stats_k(
    const float* __restrict__ ls, const float* __restrict__ llb,
    const float* __restrict__ dox, const float* __restrict__ v,
    float* __restrict__ stats)
{
    int bl = blockIdx.x;
    int b = bl >> 12, l = bl & (LL - 1);
    int wv = threadIdx.x >> 6, ln = threadIdx.x & 63;
    size_t ibase = (size_t)bl * DD + wv * DH;
    size_t dbase = (((size_t)(b * HH + wv)) * LL + l) * DH;
#pragma unroll
    for (int tn = 0; tn < 4; ++tn) {
        const float* p; size_t base;
        if (tn == 0)      { p = ls;  base = ibase; }
        else if (tn == 1) { p = llb; base = ibase; }
        else if (tn == 2) { p = dox; base = dbase; }
        else              { p = v;   base = ibase; }
        float4 x = *(const float4*)(p + base + ln * 4);
        float sm = x.x + x.y + x.z + x.w;
        float sq = x.x*x.x + x.y*x.y + x.z*x.z + x.w*x.w;
        float sa = fabsf(x.x) + fabsf(x.y) + fabsf(x.z) + fabsf(x.w);
#pragma unroll
        for (int off = 32; off > 0; off >>= 1) {
            sm += __shfl_down(sm, off);
            sq += __shfl_down(sq, off);
            sa += __shfl_down(sa, off);
        }
        if (ln == 0) {
            float mean = sm * (1.0f / DH);
            float var = sq * (1.0f / DH) - mean * mean;
            float am = sa * (1.0f / DH);
            float l2 = sqrtf(sq);
            *(float4*)(stats + (size_t)bl * 64 + wv * 16 + tn * 4) =
                make_float4(mean, var, am, l2);
        }
    }
}

// ------------------------------------------------- gate finish v2
__global__ __launch_bounds__(256) void gate_fin2_k(
    const float* __restrict__ hpart, const float* __restrict__ stats,
    const unsigned short* __restrict__ w1s,
    const float* __restrict__ w2, const float* __restrict__ b2,
    const float* __restrict__ ltemp, float* __restrict__ fw)
{
    const int bl = blockIdx.x;
    const int t = threadIdx.x;
    const float temp = log1pf(expf(ltemp[0])) + 1e-4f;
    __shared__ float st[HH][16];
    __shared__ float red[4][16];
    __shared__ float fin[16];
    if (t < 64) st[t >> 4][t & 15] = stats[(size_t)bl * 64 + t];

    const int e0 = t * 4;
    float4 hp4 = *(const float4*)(hpart + (size_t)bl * DD + e0);
    float hp[4] = {hp4.x, hp4.y, hp4.z, hp4.w};
    float w2a[4][4];
#pragma unroll
    for (int j = 0; j < 4; ++j) {
        float4 wv = *(const float4*)(w2 + (size_t)j * 1024 + e0);
        w2a[j][0] = wv.x; w2a[j][1] = wv.y; w2a[j][2] = wv.z; w2a[j][3] = wv.w;
    }
    uint4 wpk[8];
    const uint4* wp = (const uint4*)(w1s + (size_t)e0 * 16);
#pragma unroll
    for (int i = 0; i < 8; ++i) wpk[i] = wp[i];
    __syncthreads();

    float lg[4][4];
#pragma unroll
    for (int h = 0; h < 4; ++h)
#pragma unroll
        for (int j = 0; j < 4; ++j) lg[h][j] = 0.0f;

#pragma unroll
    for (int ii = 0; ii < 4; ++ii) {
        float xh[4] = {hp[ii], hp[ii], hp[ii], hp[ii]};
        unsigned arr[8] = {wpk[ii*2].x, wpk[ii*2].y, wpk[ii*2].z, wpk[ii*2].w,
                           wpk[ii*2+1].x, wpk[ii*2+1].y, wpk[ii*2+1].z, wpk[ii*2+1].w};
#pragma unroll
        for (int p = 0; p < 8; ++p) {
            float wlo = bflo(arr[p]), whi = bfhi(arr[p]);
            int s = p * 2;
#pragma unroll
            for (int h = 0; h < 4; ++h)
                xh[h] += st[h][s] * wlo + st[h][s + 1] * whi;
        }
#pragma unroll
        for (int h = 0; h < 4; ++h) {
            float x = xh[h];
            float gct = 0.5f * x * (1.0f + erff(x * 0.70710678118654752f));
            lg[h][0] += gct * w2a[0][ii];
            lg[h][1] += gct * w2a[1][ii];
            lg[h][2] += gct * w2a[2][ii];
            lg[h][3] += gct * w2a[3][ii];
        }
    }

#pragma unroll
    for (int h = 0; h < 4; ++h)
#pragma unroll
        for (int j = 0; j < 4; ++j)
#pragma unroll
            for (int off = 32; off > 0; off >>= 1)
                lg[h][j] += __shfl_down(lg[h][j], off);

    const int wv = t >> 6, ln = t & 63;
    if (ln == 0) {
#pragma unroll
        for (int h = 0; h < 4; ++h)
#pragma unroll
            for (int j = 0; j < 4; ++j) red[wv][h * 4 + j] = lg[h][j];
    }
    __syncthreads();
    if (t < 16) {
        float s = red[0][t] + red[1][t] + red[2][t] + red[3][t] + b2[t & 3];
        fin[t] = s / temp;
    }
    __syncthreads();
    if (t < 4) {
        float l0 = fin[t*4], l1 = fin[t*4+1], l2 = fin[t*4+2], l3 = fin[t*4+3];
        float m = fmaxf(fmaxf(l0, l1), fmaxf(l2, l3));
        float e0x = expf(l0-m), e1 = expf(l1-m), e2 = expf(l2-m), e3 = expf(l3-m);
        float inv = 1.0f / (e0x + e1 + e2 + e3);
        *(float4*)(fw + (size_t)bl * 16 + t * 4) = make_float4(e0x*inv, e1*inv, e2*inv, e3*inv);
    }
}

// ------------------------------------------------- combine + rms norm
__global__ __launch_bounds__(256) void combine_k(
    const float* __restrict__ ls, const float* __restrict__ llb,
    const float* __restrict__ dox, const float* __restrict__ v,
    const float* __restrict__ fw, const float* __restrict__ rss,
    const float* __restrict__ rsl, const float* __restrict__ onw,
    float* __restrict__ opre)
{
    int h = blockIdx.x & (HH - 1);
    int bl = blockIdx.x >> 2;
    int b = bl >> 12, l = bl & (LL - 1);
    int d = threadIdx.x;
    size_t i1 = (size_t)blockIdx.x * DH + d;
    size_t i2 = (((size_t)(b * HH + h)) * LL + l) * DH + d;
    const float* fwp = fw + (size_t)blockIdx.x * 4;
    float f0 = fwp[0], f1 = fwp[1], f2 = fwp[2], f3 = fwp[3];
    float aS = rss[0], aL = rsl[0];
    float vls = ls[i1], vll = llb[i1], vd = dox[i2], vv = v[i1];
    float o = f0*vls + f1*vll + f2*vd + f3*vv + aS*vls + aL*vll;
    float s = o * o;
#pragma unroll
    for (int off = 32; off > 0; off >>= 1) s += __shfl_down(s, off);
    __shared__ float red[4];
    int wv = threadIdx.x >> 6, ln = threadIdx.x & 63;
    if (ln == 0) red[wv] = s;
    __syncthreads();
    float ms = (red[0] + red[1] + red[2] + red[3]) * (1.0f / DH);
    opre[(size_t)bl * DD + h * DH + d] = o * rsqrtf(ms + 1e-5f) * onw[d];
}

// ================================================================ launch
extern "C" void kernel_launch(void* const* d_in, const int* in_sizes, int n_in,
                              void* d_out, int out_size, void* d_ws, size_t ws_size,
                              hipStream_t stream)
{
    const float* hs  = (const float*)d_in[0];
    const float* qw  = (const float*)d_in[1];
    const float* kw  = (const float*)d_in[2];
    const float* vw  = (const float*)d_in[3];
    const float* bw  = (const float*)d_in[4];
    const float* qcw = (const float*)d_in[5];
    const float* kcw = (const float*)d_in[6];
    const float* vcw = (const float*)d_in[7];
    const float* fsw = (const float*)d_in[8];
    const float* flw = (const float*)d_in[9];
    const float* w1  = (const float*)d_in[10];
    const float* b1  = (const float*)d_in[11];
    const float* w2  = (const float*)d_in[12];
    const float* b2  = (const float*)d_in[13];
    const float* lt  = (const float*)d_in[14];
    const float* rss = (const float*)d_in[15];
    const float* rsl = (const float*)d_in[16];
    const float* onw = (const float*)d_in[17];
    const float* opw = (const float*)d_in[18];
    float* out = (float*)d_out;

    float* wsf = (float*)d_ws;
    float* tmp   = wsf;
    unsigned short* ktbuf = (unsigned short*)tmp;
    unsigned short* uTbuf = (unsigned short*)(wsf + BLD/2);
    float* vbuf  = wsf + BLD;
    float* dbuf  = wsf + 2*BLD;
    // hsb shares the dbuf region -> DEAD once scan10 writes dbuf. Only used in phase 1.
    unsigned short* hsb = (unsigned short*)(wsf + 2*BLD);
    // bf16 QKV weights live in the dead second half of the dbuf region during phase 1
    unsigned short* qwb = (unsigned short*)(wsf + 2*BLD + BLD/2);
    unsigned short* kwb = qwb + (size_t)DD*DD;
    unsigned short* vwb = kwb + (size_t)DD*DD;
    unsigned short* qbuf = (unsigned short*)(wsf + 3*BLD);
    unsigned short* kbuf = qbuf + BLD;
    float* hpart = wsf + 3*BLD;
    float* opre  = wsf + 3*BLD;
    unsigned short* ubuf = (unsigned short*)(wsf + 4*BLD);
    unsigned short* wbuf = ubuf + BLD;
    float* llbuf = wsf + 4*BLD;
    float* lsbuf = tmp;
    unsigned short* attnb = (unsigned short*)(wsf + 5*BLD);
    float* statsb = wsf + 5*BLD + 524288;
    float* fwbuf  = statsb + (size_t)BL*HH*16;
    float* betab  = fwbuf + (size_t)BL*HH*4;
    unsigned short* w1sp = (unsigned short*)(betab + (size_t)BL*HH);

    dim3 gg(8, 64);   // N/128, M/128

    cvt_bf_k<<<(int)(BLD/1024), 256, 0, stream>>>(hs, hsb);
    cvt_bf_k<<<1024, 256, 0, stream>>>(qw, qwb);
    cvt_bf_k<<<1024, 256, 0, stream>>>(kw, kwb);
    cvt_bf_k<<<1024, 256, 0, stream>>>(vw, vwb);
    w1s_prep_k<<<64, 256, 0, stream>>>(w1, w1sp);

    gemm_bb<<<gg, 256, 0, stream>>>(hsb, DD, qwb, DD, tmp, DD, DD);
    convnorm_qk_k<<<BL*HH, 256, 0, stream>>>(tmp, qcw, qbuf);
    gemm_bb<<<gg, 256, 0, stream>>>(hsb, DD, kwb, DD, tmp, DD, DD);
    convnorm_qk_k<<<BL*HH, 256, 0, stream>>>(tmp, kcw, kbuf);
    gemm_bb<<<gg, 256, 0, stream>>>(hsb, DD, vwb, DD, tmp, DD, DD);
    conv_silu_k<<<(int)(BLD/256), 256, 0, stream>>>(tmp, vcw, vbuf);

    beta_k<<<BL, 256, 0, stream>>>(hs, bw, betab);

    tr_k<<<8*64*4, 256, 0, stream>>>(kbuf, ktbuf);
    // chunk_prep2 writes uT directly (tru_k eliminated)
    chunk_prep2_k<<<BB*HH*NC, 256, 0, stream>>>(qbuf, kbuf, ktbuf, vbuf, betab,
                                                uTbuf, wbuf, attnb);

    scan10_k<<<BB*HH*16, 256, 0, stream>>>(qbuf, ktbuf, uTbuf, wbuf, attnb, dbuf);

    fir2_k<5><<<BB*64*16, 256, 0, stream>>>(vbuf, fsw, lsbuf);
    fir2_k<64><<<BB*64*16, 256, 0, stream>>>(vbuf, flw, llbuf);

    stats_k<<<BL, 256, 0, stream>>>(lsbuf, llbuf, dbuf, vbuf, statsb);

    // hpart GEMM reads the pristine f32 input hs (hsb is dead: overwritten by dbuf)
    gemm_mfma<<<gg, 256, 0, stream>>>(hs, DD, w1, 1040, b1, hpart, DD, DD);
    gate_fin2_k<<<BL, 256, 0, stream>>>(hpart, statsb, w1sp, w2, b2, lt, fwbuf);

    combine_k<<<BL*HH, 256, 0, stream>>>(lsbuf, llbuf, dbuf, vbuf, fwbuf, rss, rsl, onw, opre);

    gemm_mfma<<<gg, 256, 0, stream>>>(opre, DD, opw, DD, nullptr, out, DD, DD);
}